// Round 9
// baseline (198.601 us; speedup 1.0000x reference)
//
#include <hip/hip_runtime.h>
#include <stdint.h>

// ============================================================================
// DSVABlockLarge — round 9: B operands global->register (no LDS round trip).
//  * Weights are L2-resident and have zero intra-block reuse -> load B
//    fragments straight to VGPRs (16B/lane, lane l15 = WT row = out col,
//    l4*8 = k), double-buffered, issue-early depth-1 prefetch.
//  * Wave layout 1(M)x8(N) for N=384 stages: B loaded once per block,
//    each A ds_read feeds 3 MFMAs. K-loops barrier-free.
//  * LDS only for A tiles (gload16, swizzled round-8 style) + row-local
//    intermediates (X1/Tb/X2/Hb, byte-XOR swizzled).
//  * attn/knn/prep/detect unchanged from passing round 8.
// ============================================================================

using u16 = unsigned short;
using u32 = unsigned int;
using u64 = unsigned long long;

typedef short short8 __attribute__((ext_vector_type(8)));
typedef float f32x4 __attribute__((ext_vector_type(4)));

#define DEV static __device__ __forceinline__

constexpr int cV = 4096, cD = 192;
constexpr int cE = 384;
constexpr int cKN = 16, cTK = 8;
constexpr int cM = 2 * cV;   // 8192 rows (B*V)
constexpr int c3E = 1152;

DEV float bf2f(u16 v) { return __uint_as_float(((u32)v) << 16); }
DEV float bflo(u32 v) { return __uint_as_float(v << 16); }
DEV float bfhi(u32 v) { return __uint_as_float(v & 0xFFFF0000u); }
DEV u16 f2bf(float f) {
  u32 u = __float_as_uint(f);
  u = (u + 0x7FFFu + ((u >> 16) & 1u)) >> 16;
  return (u16)u;
}
DEV int mget(const void* mp, int flag, int i) {
  if (flag == 0) return ((const int*)mp)[i] != 0;
  if (flag == 1) return ((const float*)mp)[i] != 0.0f;
  if (flag == 2) return ((const u16*)mp)[i] != 0;
  return ((const unsigned char*)mp)[i] != 0;
}
DEV float gelu_tanh(float x) {
  float t = tanhf(0.7978845608028654f * (x + 0.044715f * x * x * x));
  return 0.5f * x * (1.0f + t);
}
DEV u32 f2ord(float f) {
  u32 u = __float_as_uint(f);
  return (u & 0x80000000u) ? ~u : (u | 0x80000000u);
}
DEV float ord2f(u32 o) {
  u32 bits = (o & 0x80000000u) ? (o & 0x7FFFFFFFu) : ~o;
  return __uint_as_float(bits);
}
DEV int bf_plausible(u32 h) {
  if (h == 0u || h == 0x8000u) return 1;
  u32 e = (h >> 7) & 0xFFu;
  return (e >= 100u && e <= 140u) ? 1 : 0;
}

using as1p = const unsigned int __attribute__((address_space(1)))*;
using as3p = unsigned int __attribute__((address_space(3)))*;
DEV void gload16(const void* g, void* l) {
  __builtin_amdgcn_global_load_lds((as1p)g, (as3p)l, 16, 0, 0);
}
DEV f32x4 mfma16x16x32_bf16(short8 a, short8 b, f32x4 c) {
  asm volatile("v_mfma_f32_16x16x32_bf16 %0, %1, %2, %0" : "+v"(c) : "v"(a), "v"(b));
  return c;
}
DEV int swz(int row, int byteoff) { return byteoff ^ ((row & 7) << 4); }
DEV int ldswz(int r, int c) { return r * 64 + (c ^ ((r & 7) * 8)); }

// B-fragment register block: v[n][ks] covers cols n*16, k half ks*32.
template <int NF>
struct BF { short8 v[NF][2]; };

template <int NF>
DEV void loadB(BF<NF>& b, const u16* __restrict__ wbase, int Kst, int kt, int l15, int l4) {
  #pragma unroll
  for (int n = 0; n < NF; ++n)
    #pragma unroll
    for (int ks = 0; ks < 2; ++ks)
      b.v[n][ks] = *(const short8*)(wbase + (size_t)(n * 16 + l15) * Kst + kt + ks * 32 + l4 * 8);
}

// ---------------------------------------------------------------------------
__global__ void detect_all_kernel(const u32* __restrict__ tok,
                                  const u32* __restrict__ m,
                                  int* __restrict__ flag) {
  __shared__ int cnt, sa, sb, sc;
  if (threadIdx.x == 0) { cnt = 0; sa = 0; sb = 0; sc = 0; }
  __syncthreads();
  int c = 0;
  for (int i = threadIdx.x; i < 4096; i += 256) {
    u32 d = tok[i];
    c += bf_plausible(d & 0xFFFFu) & bf_plausible(d >> 16);
  }
  atomicAdd(&cnt, c);
  int a = 0, b = 0, cc = 0;
  for (int i = threadIdx.x; i < 2048; i += 256) {
    u32 d = m[i];
    if (!(d == 0u || d == 1u)) a = 1;
    if (!(d == 0u || d == 0x3F800000u)) b = 1;
    if (!(d == 0u || d == 0x00003F80u || d == 0x3F800000u || d == 0x3F803F80u)) cc = 1;
  }
  if (a) atomicOr(&sa, 1);
  if (b) atomicOr(&sb, 1);
  if (cc) atomicOr(&sc, 1);
  __syncthreads();
  if (threadIdx.x == 0) {
    flag[1] = (cnt > 3400) ? 1 : 0;
    flag[0] = (sa == 0) ? 0 : ((sb == 0) ? 1 : ((sc == 0) ? 2 : 3));
  }
}

// ---------------------------------------------------------------------------
struct PrepArgs {
  const void* csrc[11]; u16* cdst[11]; int cn[11];
  const void* tsrc[6]; u16* tdst[6]; int tK[6]; int tN[6];
  const void* mask; u64* bm;
};
__global__ __launch_bounds__(256) void prep_kernel(PrepArgs a, const int* __restrict__ flag) {
  const int job = blockIdx.y;
  const int dt = flag[1];
  if (job < 11) {
    const int n = a.cn[job];
    u16* d = a.cdst[job];
    if (dt) {
      const u16* s = (const u16*)a.csrc[job];
      for (int i = blockIdx.x * 256 + threadIdx.x; i < n; i += gridDim.x * 256) d[i] = s[i];
    } else {
      const float* s = (const float*)a.csrc[job];
      for (int i = blockIdx.x * 256 + threadIdx.x; i < n; i += gridDim.x * 256) d[i] = f2bf(s[i]);
    }
  } else if (job < 17) {
    const int t = job - 11;
    const int K = a.tK[t], N = a.tN[t];
    const int total = K * N;
    u16* d = a.tdst[t];
    for (int i = blockIdx.x * 256 + threadIdx.x; i < total; i += gridDim.x * 256) {
      int n = i / K, k = i - n * K;
      u16 vv;
      if (dt) vv = ((const u16*)a.tsrc[t])[(size_t)k * N + n];
      else vv = f2bf(((const float*)a.tsrc[t])[(size_t)k * N + n]);
      d[i] = vv;
    }
  } else {
    const int gw = (blockIdx.x * 256 + threadIdx.x) >> 6;
    const int lane = threadIdx.x & 63;
    if (gw < 128) {
      const int fl = flag[0];
      u64 bal = __ballot(mget(a.mask, fl, gw * 64 + lane) != 0);
      if (lane == 0) a.bm[gw] = bal;
    }
  }
}

// ---------------------------------------------------------------------------
// KNN v2 (unchanged).
__global__ __launch_bounds__(256) void knn_kernel(const u64* __restrict__ bitmask,
                                                  int* __restrict__ knn_out) {
  const int tid = threadIdx.x;
  const int wid = tid >> 6, lane = tid & 63;
  const int q0 = blockIdx.x * 4;
  const int b = q0 >> 12;
  const int q = q0 + wid;
  const int v = q & 4095;
  __shared__ u64 smask[64];
  __shared__ int hist4[4][64];
  __shared__ int listT[4][64];
  __shared__ int out16s[4][16];
  __shared__ int meta[4][3];
  __shared__ int cntA[4], cntT[4];
  if (tid < 64) smask[tid] = bitmask[b * 64 + tid];
  for (int i = tid; i < 4 * 64; i += 256) ((int*)hist4)[i] = 0;
  if (lane == 0) { cntA[wid] = 0; cntT[wid] = 0; }
  __syncthreads();
  const int iv = v >> 8, jv = (v >> 4) & 15, kv = v & 15;
  #pragma unroll
  for (int t = 0; t < 12; ++t) {
    int o = t * 64 + lane;
    if (o < 729) {
      int oi = o / 81, rm = o - oi * 81;
      int oj = rm / 9, ok = rm - oj * 9;
      int i = iv + oi - 4, j = jv + oj - 4, k = kv + ok - 4;
      if (((i | j | k) & ~15) == 0) {
        int u = (i << 8) | (j << 4) | k;
        if ((smask[u >> 6] >> (u & 63)) & 1ull) {
          int di = oi - 4, dj = oj - 4, dk = ok - 4;
          atomicAdd(&hist4[wid][di * di + dj * dj + dk * dk], 1);
        }
      }
    }
  }
  __syncthreads();
  if (lane == 0) {
    int cum = 0, T = -1, below = 0;
    for (int d = 0; d <= 48; ++d) {
      int h = hist4[wid][d];
      if (h > 0 && cum + h >= cKN) { T = d; below = cum; break; }
      cum += h;
    }
    if (T > 24) T = -1;
    meta[wid][0] = T; meta[wid][1] = below; meta[wid][2] = (T < 0) ? 1 : 0;
  }
  __syncthreads();
  const int T = meta[wid][0], below = meta[wid][1], fb = meta[wid][2];
  #pragma unroll
  for (int t = 0; t < 12; ++t) {
    int o = t * 64 + lane;
    if (o < 729) {
      int oi = o / 81, rm = o - oi * 81;
      int oj = rm / 9, ok = rm - oj * 9;
      int i = iv + oi - 4, j = jv + oj - 4, k = kv + ok - 4;
      if (((i | j | k) & ~15) == 0) {
        int u = (i << 8) | (j << 4) | k;
        if ((smask[u >> 6] >> (u & 63)) & 1ull) {
          int di = oi - 4, dj = oj - 4, dk = ok - 4;
          int d2 = di * di + dj * dj + dk * dk;
          if (d2 < T) { int p = atomicAdd(&cntA[wid], 1); out16s[wid][p] = u; }
          else if (d2 == T) { int p = atomicAdd(&cntT[wid], 1); if (p < 64) listT[wid][p] = u; }
        }
      }
    }
  }
  __syncthreads();
  if (!fb) {
    if (lane == 0) {
      int need = cKN - below;
      int nT = cntT[wid] < 64 ? cntT[wid] : 64;
      for (int r = 0; r < need; ++r) {
        int bi = 0, bu = 0x7FFFFFFF;
        for (int i2 = 0; i2 < nT; ++i2) { int x = listT[wid][i2]; if (x < bu) { bu = x; bi = i2; } }
        out16s[wid][below + r] = bu;
        listT[wid][bi] = 0x7FFFFFFF;
      }
    }
  } else {
    u64 rem = smask[lane];
    const int myi = lane >> 2;
    const int di2 = (iv - myi) * (iv - myi);
    for (int r = 0; r < cKN; ++r) {
      u64 tmp = rem;
      u32 best = 0xFFFFFFFFu;
      while (tmp) {
        int bp = __builtin_ctzll(tmp);
        tmp &= tmp - 1;
        int u = (lane << 6) | bp;
        int dj = jv - ((u >> 4) & 15), dk = kv - (u & 15);
        u32 key = (u32)(((di2 + dj * dj + dk * dk) << 12) | u);
        if (key < best) best = key;
      }
      u32 pk = (best == 0xFFFFFFFFu) ? 0xFFFFFFFFu : ((best << 6) | (u32)lane);
      #pragma unroll
      for (int off = 1; off < 64; off <<= 1) {
        u32 o2 = __shfl_xor(pk, off);
        if (o2 < pk) pk = o2;
      }
      int u = (int)((pk >> 6) & 4095u);
      int wl = (int)(pk & 63u);
      if (lane == wl) rem &= ~(1ull << (u & 63));
      if (lane == 0) out16s[wid][r] = u;
    }
  }
  __syncthreads();
  if (lane < cKN) knn_out[q * cKN + lane] = out16s[wid][lane];
}

// ---------------------------------------------------------------------------
// F_A: X1 = LN(tok@We+be; g1,bt1) ; QB = X1@Wqkv + bqkv.  1x8 waves.
__global__ __launch_bounds__(512) void fused_ln_qkv(
    const u16* __restrict__ tokc, const u16* __restrict__ WeT,
    const u16* __restrict__ be, const u16* __restrict__ g1, const u16* __restrict__ bt1,
    const u16* __restrict__ WqkvT, const u16* __restrict__ bqkv,
    u16* __restrict__ QB) {
  __shared__ alignas(16) u16 Afull[3 * 2048];   // 12KB tok tiles (swz)
  __shared__ alignas(16) char X1[32 * 768];     // 24KB swz
  __shared__ float st[32][8][2];
  const int tid = threadIdx.x;
  const int lane = tid & 63, wn = tid >> 6;
  const int l15 = lane & 15, l4 = lane >> 4;
  const int sr = lane >> 3;
  const int scs = (((lane & 7) ^ sr) << 3);
  const int row0 = blockIdx.x * 32;

  for (int g = wn; g < 12; g += 8)
    gload16(tokc + (size_t)(row0 + (g & 3) * 8 + sr) * 192 + (g >> 2) * 64 + scs,
            (char*)Afull + g * 1024);
  __syncthreads();

  // stage 1: tok @ WeT^T (K=192, T=3)
  const u16* w1base = WeT + (size_t)(wn * 48) * 192;
  BF<3> bp[2];
  loadB<3>(bp[0], w1base, 192, 0, l15, l4);
  f32x4 acc[2][3];
  #pragma unroll
  for (int m = 0; m < 2; ++m)
    #pragma unroll
    for (int n = 0; n < 3; ++n) acc[m][n] = f32x4{0.f, 0.f, 0.f, 0.f};
  #pragma unroll
  for (int t = 0; t < 3; ++t) {
    if (t + 1 < 3) loadB<3>(bp[(t + 1) & 1], w1base, 192, (t + 1) * 64, l15, l4);
    #pragma unroll
    for (int ks = 0; ks < 2; ++ks) {
      short8 a0 = *(const short8*)&Afull[t * 2048 + ldswz(l15, ks * 32 + l4 * 8)];
      short8 a1 = *(const short8*)&Afull[t * 2048 + ldswz(16 + l15, ks * 32 + l4 * 8)];
      #pragma unroll
      for (int n = 0; n < 3; ++n) {
        acc[0][n] = mfma16x16x32_bf16(a0, bp[t & 1].v[n][ks], acc[0][n]);
        acc[1][n] = mfma16x16x32_bf16(a1, bp[t & 1].v[n][ks], acc[1][n]);
      }
    }
  }
  // LN epilogue
  float s[2][4], sq[2][4];
  #pragma unroll
  for (int m = 0; m < 2; ++m)
    #pragma unroll
    for (int j = 0; j < 4; ++j) { s[m][j] = 0.f; sq[m][j] = 0.f; }
  #pragma unroll
  for (int n = 0; n < 3; ++n) {
    const float bi = bf2f(be[wn * 48 + n * 16 + l15]);
    #pragma unroll
    for (int m = 0; m < 2; ++m)
      #pragma unroll
      for (int j = 0; j < 4; ++j) {
        acc[m][n][j] += bi;
        s[m][j] += acc[m][n][j]; sq[m][j] += acc[m][n][j] * acc[m][n][j];
      }
  }
  #pragma unroll
  for (int off = 1; off < 16; off <<= 1)
    #pragma unroll
    for (int m = 0; m < 2; ++m)
      #pragma unroll
      for (int j = 0; j < 4; ++j) { s[m][j] += __shfl_xor(s[m][j], off); sq[m][j] += __shfl_xor(sq[m][j], off); }
  if (l15 == 0) {
    #pragma unroll
    for (int m = 0; m < 2; ++m)
      #pragma unroll
      for (int j = 0; j < 4; ++j) {
        const int rl = m * 16 + l4 * 4 + j;
        st[rl][wn][0] = s[m][j]; st[rl][wn][1] = sq[m][j];
      }
  }
  __syncthreads();
  #pragma unroll
  for (int m = 0; m < 2; ++m)
    #pragma unroll
    for (int j = 0; j < 4; ++j) {
      const int rl = m * 16 + l4 * 4 + j;
      float ts = 0.f, tq = 0.f;
      #pragma unroll
      for (int wv = 0; wv < 8; ++wv) { ts += st[rl][wv][0]; tq += st[rl][wv][1]; }
      const float mean = ts * (1.0f / 384.0f);
      const float var = tq * (1.0f / 384.0f) - mean * mean;
      const float rstd = rsqrtf(var + 1e-5f);
      #pragma unroll
      for (int n = 0; n < 3; ++n) {
        const int col = wn * 48 + n * 16 + l15;
        const float v = (acc[m][n][j] - mean) * rstd * bf2f(g1[col]) + bf2f(bt1[col]);
        *(u16*)(X1 + swz(rl, rl * 768 + col * 2)) = f2bf(v);
      }
    }
  __syncthreads();

  // stage 2: QB = X1 @ WqkvT^T + bqkv (3 chunks of 384, K=384, T=6)
  for (int chunk = 0; chunk < 3; ++chunk) {
    const u16* w2base = WqkvT + (size_t)(chunk * 384 + wn * 48) * 384;
    BF<3> bq[2];
    loadB<3>(bq[0], w2base, 384, 0, l15, l4);
    f32x4 a2[2][3];
    #pragma unroll
    for (int m = 0; m < 2; ++m)
      #pragma unroll
      for (int n = 0; n < 3; ++n) a2[m][n] = f32x4{0.f, 0.f, 0.f, 0.f};
    #pragma unroll
    for (int t = 0; t < 6; ++t) {
      if (t + 1 < 6) loadB<3>(bq[(t + 1) & 1], w2base, 384, (t + 1) * 64, l15, l4);
      #pragma unroll
      for (int ks = 0; ks < 2; ++ks) {
        const int kk = (t * 64 + ks * 32 + l4 * 8) * 2;
        short8 a0 = *(const short8*)(X1 + swz(l15, l15 * 768 + kk));
        short8 a1 = *(const short8*)(X1 + swz(16 + l15, (16 + l15) * 768 + kk));
        #pragma unroll
        for (int n = 0; n < 3; ++n) {
          a2[0][n] = mfma16x16x32_bf16(a0, bq[t & 1].v[n][ks], a2[0][n]);
          a2[1][n] = mfma16x16x32_bf16(a1, bq[t & 1].v[n][ks], a2[1][n]);
        }
      }
    }
    #pragma unroll
    for (int n = 0; n < 3; ++n) {
      const int col = chunk * 384 + wn * 48 + n * 16 + l15;
      const float bi = bf2f(bqkv[col]);
      #pragma unroll
      for (int m = 0; m < 2; ++m)
        #pragma unroll
        for (int j = 0; j < 4; ++j)
          QB[(size_t)(row0 + m * 16 + l4 * 4 + j) * c3E + col] = f2bf(a2[m][n][j] + bi);
    }
  }
}

// ---------------------------------------------------------------------------
// F_C: T=(S2@Wo+bo)*mask ; XM=(T@Wc+bc)*0.5+tok (f32) ; S1=LN(XM@We+be)
__global__ __launch_bounds__(512) void fused_mid(
    const u16* __restrict__ S2, const u16* __restrict__ WoT, const u16* __restrict__ bo,
    const void* __restrict__ mask, const int* __restrict__ flag,
    const u16* __restrict__ WcT, const u16* __restrict__ bc, const u16* __restrict__ tokc,
    float* __restrict__ XM,
    const u16* __restrict__ WeT, const u16* __restrict__ be,
    const u16* __restrict__ g2, const u16* __restrict__ bt2, u16* __restrict__ S1out) {
  __shared__ alignas(16) u16 Afull[6 * 2048];   // 24KB S2
  __shared__ alignas(16) char Tb[32 * 768];     // 24KB T swz; X2 overlays
  __shared__ float st[32][8][2];
  char* X2 = Tb;
  const int tid = threadIdx.x;
  const int lane = tid & 63, wn = tid >> 6;
  const int wr = wn >> 2, wc = wn & 3;
  const int l15 = lane & 15, l4 = lane >> 4;
  const int sr = lane >> 3;
  const int scs = (((lane & 7) ^ sr) << 3);
  const int row0 = blockIdx.x * 32;
  const int fl = flag[0];

  for (int g = wn; g < 24; g += 8)
    gload16(S2 + (size_t)(row0 + (g & 3) * 8 + sr) * cE + (g >> 2) * 64 + scs,
            (char*)Afull + g * 1024);
  __syncthreads();

  // stage 1: T = (S2 @ WoT^T + bo) * fmask (K=384, T=6, 1x8)
  {
    const u16* wbase = WoT + (size_t)(wn * 48) * 384;
    BF<3> bp[2];
    loadB<3>(bp[0], wbase, 384, 0, l15, l4);
    f32x4 acc[2][3];
    #pragma unroll
    for (int m = 0; m < 2; ++m)
      #pragma unroll
      for (int n = 0; n < 3; ++n) acc[m][n] = f32x4{0.f, 0.f, 0.f, 0.f};
    #pragma unroll
    for (int t = 0; t < 6; ++t) {
      if (t + 1 < 6) loadB<3>(bp[(t + 1) & 1], wbase, 384, (t + 1) * 64, l15, l4);
      #pragma unroll
      for (int ks = 0; ks < 2; ++ks) {
        short8 a0 = *(const short8*)&Afull[t * 2048 + ldswz(l15, ks * 32 + l4 * 8)];
        short8 a1 = *(const short8*)&Afull[t * 2048 + ldswz(16 + l15, ks * 32 + l4 * 8)];
        #pragma unroll
        for (int n = 0; n < 3; ++n) {
          acc[0][n] = mfma16x16x32_bf16(a0, bp[t & 1].v[n][ks], acc[0][n]);
          acc[1][n] = mfma16x16x32_bf16(a1, bp[t & 1].v[n][ks], acc[1][n]);
        }
      }
    }
    #pragma unroll
    for (int m = 0; m < 2; ++m)
      #pragma unroll
      for (int j = 0; j < 4; ++j) {
        const int rl = m * 16 + l4 * 4 + j;
        const float fm = mget(mask, fl, row0 + rl) ? 1.0f : 0.0f;
        #pragma unroll
        for (int n = 0; n < 3; ++n) {
          const int col = wn * 48 + n * 16 + l15;
          const float v = (acc[m][n][j] + bf2f(bo[col])) * fm;
          *(u16*)(Tb + swz(rl, rl * 768 + col * 2)) = f2bf(v);
        }
      }
  }
  __syncthreads();

  // stage 2: XM = (T @ WcT^T + bc)*0.5 + tok (K=384, T=6, N=192, 2x4)
  f32x4 a2[3];
  #pragma unroll
  for (int n = 0; n < 3; ++n) a2[n] = f32x4{0.f, 0.f, 0.f, 0.f};
  {
    const u16* wbase = WcT + (size_t)(wc * 48) * 384;
    BF<3> bp[2];
    loadB<3>(bp[0], wbase, 384, 0, l15, l4);
    #pragma unroll
    for (int t = 0; t < 6; ++t) {
      if (t + 1 < 6) loadB<3>(bp[(t + 1) & 1], wbase, 384, (t + 1) * 64, l15, l4);
      #pragma unroll
      for (int ks = 0; ks < 2; ++ks) {
        const int rl = wr * 16 + l15;
        short8 a = *(const short8*)(Tb + swz(rl, rl * 768 + (t * 64 + ks * 32 + l4 * 8) * 2));
        #pragma unroll
        for (int n = 0; n < 3; ++n)
          a2[n] = mfma16x16x32_bf16(a, bp[t & 1].v[n][ks], a2[n]);
      }
    }
  }
  __syncthreads();   // all reads of Tb done before X2 overlay
  #pragma unroll
  for (int n = 0; n < 3; ++n) {
    const int col = wc * 48 + n * 16 + l15;
    const float bi = bf2f(bc[col]);
    #pragma unroll
    for (int j = 0; j < 4; ++j) {
      const int rl = wr * 16 + l4 * 4 + j;
      const size_t oi = (size_t)(row0 + rl) * cD + col;
      const float r = (a2[n][j] + bi) * 0.5f + bf2f(tokc[oi]);
      XM[oi] = r;
      *(u16*)(X2 + swz(rl, rl * 384 + col * 2)) = f2bf(r);
    }
  }
  __syncthreads();

  // stage 3: S1 = LN(X2 @ WeT^T + be; g2, bt2) (K=192, T=3, 1x8)
  {
    const u16* wbase = WeT + (size_t)(wn * 48) * 192;
    BF<3> bp[2];
    loadB<3>(bp[0], wbase, 192, 0, l15, l4);
    f32x4 a3[2][3];
    #pragma unroll
    for (int m = 0; m < 2; ++m)
      #pragma unroll
      for (int n = 0; n < 3; ++n) a3[m][n] = f32x4{0.f, 0.f, 0.f, 0.f};
    #pragma unroll
    for (int t = 0; t < 3; ++t) {
      if (t + 1 < 3) loadB<3>(bp[(t + 1) & 1], wbase, 192, (t + 1) * 64, l15, l4);
      #pragma unroll
      for (int ks = 0; ks < 2; ++ks) {
        const int kk = (t * 64 + ks * 32 + l4 * 8) * 2;
        short8 a0 = *(const short8*)(X2 + swz(l15, l15 * 384 + kk));
        short8 a1 = *(const short8*)(X2 + swz(16 + l15, (16 + l15) * 384 + kk));
        #pragma unroll
        for (int n = 0; n < 3; ++n) {
          a3[0][n] = mfma16x16x32_bf16(a0, bp[t & 1].v[n][ks], a3[0][n]);
          a3[1][n] = mfma16x16x32_bf16(a1, bp[t & 1].v[n][ks], a3[1][n]);
        }
      }
    }
    float s[2][4], sq[2][4];
    #pragma unroll
    for (int m = 0; m < 2; ++m)
      #pragma unroll
      for (int j = 0; j < 4; ++j) { s[m][j] = 0.f; sq[m][j] = 0.f; }
    #pragma unroll
    for (int n = 0; n < 3; ++n) {
      const float bi = bf2f(be[wn * 48 + n * 16 + l15]);
      #pragma unroll
      for (int m = 0; m < 2; ++m)
        #pragma unroll
        for (int j = 0; j < 4; ++j) {
          a3[m][n][j] += bi;
          s[m][j] += a3[m][n][j]; sq[m][j] += a3[m][n][j] * a3[m][n][j];
        }
    }
    #pragma unroll
    for (int off = 1; off < 16; off <<= 1)
      #pragma unroll
      for (int m = 0; m < 2; ++m)
        #pragma unroll
        for (int j = 0; j < 4; ++j) { s[m][j] += __shfl_xor(s[m][j], off); sq[m][j] += __shfl_xor(sq[m][j], off); }
    if (l15 == 0) {
      #pragma unroll
      for (int m = 0; m < 2; ++m)
        #pragma unroll
        for (int j = 0; j < 4; ++j) {
          const int rl = m * 16 + l4 * 4 + j;
          st[rl][wn][0] = s[m][j]; st[rl][wn][1] = sq[m][j];
        }
    }
    __syncthreads();
    #pragma unroll
    for (int m = 0; m < 2; ++m)
      #pragma unroll
      for (int j = 0; j < 4; ++j) {
        const int rl = m * 16 + l4 * 4 + j;
        float ts = 0.f, tq = 0.f;
        #pragma unroll
        for (int wv = 0; wv < 8; ++wv) { ts += st[rl][wv][0]; tq += st[rl][wv][1]; }
        const float mean = ts * (1.0f / 384.0f);
        const float var = tq * (1.0f / 384.0f) - mean * mean;
        const float rstd = rsqrtf(var + 1e-5f);
        #pragma unroll
        for (int n = 0; n < 3; ++n) {
          const int col = wn * 48 + n * 16 + l15;
          S1out[(size_t)(row0 + rl) * cE + col] =
              f2bf((a3[m][n][j] - mean) * rstd * bf2f(g2[col]) + bf2f(bt2[col]));
        }
      }
  }
}

// ---------------------------------------------------------------------------
// F_D: H=gelu(S1@W1+b1) per K-half ; F=H@W2+b2 (reg acc) ; out=(F@Wc+bc)/2+XM
__global__ __launch_bounds__(512) void fused_ffn(
    const u16* __restrict__ S1, const u16* __restrict__ W1T, const u16* __restrict__ b1,
    const u16* __restrict__ W2T, const u16* __restrict__ b2,
    const u16* __restrict__ WcT, const u16* __restrict__ bc,
    const float* __restrict__ XM, void* __restrict__ outv, const int* __restrict__ flag) {
  __shared__ alignas(16) u16 Afull[6 * 2048];   // 24KB S1
  __shared__ alignas(16) char Hb[32 * 768];     // 24KB H-half swz; F overlays
  const int tid = threadIdx.x;
  const int lane = tid & 63, wn = tid >> 6;
  const int wr = wn >> 2, wc = wn & 3;
  const int l15 = lane & 15, l4 = lane >> 4;
  const int sr = lane >> 3;
  const int scs = (((lane & 7) ^ sr) << 3);
  const int row0 = blockIdx.x * 32;

  for (int g = wn; g < 24; g += 8)
    gload16(S1 + (size_t)(row0 + (g & 3) * 8 + sr) * cE + (g >> 2) * 64 + scs,
            (char*)Afull + g * 1024);
  __syncthreads();

  f32x4 accF[2][3];
  #pragma unroll
  for (int m = 0; m < 2; ++m)
    #pragma unroll
    for (int n = 0; n < 3; ++n) accF[m][n] = f32x4{0.f, 0.f, 0.f, 0.f};

  for (int half = 0; half < 2; ++half) {
    // s1: H = gelu(S1 @ W1T[half]^T + b1[half]) (K=384, T=6, 1x8)
    {
      const u16* wbase = W1T + (size_t)(half * 384 + wn * 48) * 384;
      BF<3> bp[2];
      loadB<3>(bp[0], wbase, 384, 0, l15, l4);
      f32x4 a1[2][3];
      #pragma unroll
      for (int m = 0; m < 2; ++m)
        #pragma unroll
        for (int n = 0; n < 3; ++n) a1[m][n] = f32x4{0.f, 0.f, 0.f, 0.f};
      #pragma unroll
      for (int t = 0; t < 6; ++t) {
        if (t + 1 < 6) loadB<3>(bp[(t + 1) & 1], wbase, 384, (t + 1) * 64, l15, l4);
        #pragma unroll
        for (int ks = 0; ks < 2; ++ks) {
          short8 a0 = *(const short8*)&Afull[t * 2048 + ldswz(l15, ks * 32 + l4 * 8)];
          short8 am = *(const short8*)&Afull[t * 2048 + ldswz(16 + l15, ks * 32 + l4 * 8)];
          #pragma unroll
          for (int n = 0; n < 3; ++n) {
            a1[0][n] = mfma16x16x32_bf16(a0, bp[t & 1].v[n][ks], a1[0][n]);
            a1[1][n] = mfma16x16x32_bf16(am, bp[t & 1].v[n][ks], a1[1][n]);
          }
        }
      }
      // Hb write: first half writes fresh; second half overwrites after the
      // s2-end barrier below has retired all readers.
      #pragma unroll
      for (int n = 0; n < 3; ++n) {
        const int col = wn * 48 + n * 16 + l15;
        const float bi = bf2f(b1[half * 384 + col]);
        #pragma unroll
        for (int m = 0; m < 2; ++m)
          #pragma unroll
          for (int j = 0; j < 4; ++j) {
            const int rl = m * 16 + l4 * 4 + j;
            *(u16*)(Hb + swz(rl, rl * 768 + col * 2)) = f2bf(gelu_tanh(a1[m][n][j] + bi));
          }
      }
    }
    __syncthreads();
    // s2: accF += H @ W2T[:, half]^T (K=384, T=6, 1x8)
    {
      const u16* wbase = W2T + (size_t)(wn * 48) * 768 + half * 384;
      BF<3> bp[2];
      loadB<3>(bp[0], wbase, 768, 0, l15, l4);
      #pragma unroll
      for (int t = 0; t < 6; ++t) {
        if (t + 1 < 6) loadB<3>(bp[(t + 1) & 1], wbase, 768, (t + 1) * 64, l15, l4);
        #pragma unroll
        for (int ks = 0; ks < 2; ++ks) {
          const int kk = (t * 64 + ks * 32 + l4 * 8) * 2;
          short8 a0 = *(const short8*)(Hb + swz(l15, l15 * 768 + kk));
          short8 am = *(const short8*)(Hb + swz(16 + l15, (16 + l15) * 768 + kk));
          #pragma unroll
          for (int n = 0; n < 3; ++n) {
            accF[0][n] = mfma16x16x32_bf16(a0, bp[t & 1].v[n][ks], accF[0][n]);
            accF[1][n] = mfma16x16x32_bf16(am, bp[t & 1].v[n][ks], accF[1][n]);
          }
        }
      }
    }
    __syncthreads();
  }
  // F = accF + b2 -> Hb (readers retired by the last s2 barrier)
  #pragma unroll
  for (int n = 0; n < 3; ++n) {
    const int col = wn * 48 + n * 16 + l15;
    const float bi = bf2f(b2[col]);
    #pragma unroll
    for (int m = 0; m < 2; ++m)
      #pragma unroll
      for (int j = 0; j < 4; ++j) {
        const int rl = m * 16 + l4 * 4 + j;
        *(u16*)(Hb + swz(rl, rl * 768 + col * 2)) = f2bf(accF[m][n][j] + bi);
      }
  }
  __syncthreads();
  // s3: out = (F @ WcT^T + bc)*0.5 + XM (K=384, T=6, N=192, 2x4)
  f32x4 a3[3];
  #pragma unroll
  for (int n = 0; n < 3; ++n) a3[n] = f32x4{0.f, 0.f, 0.f, 0.f};
  {
    const u16* wbase = WcT + (size_t)(wc * 48) * 384;
    BF<3> bp[2];
    loadB<3>(bp[0], wbase, 384, 0, l15, l4);
    #pragma unroll
    for (int t = 0; t < 6; ++t) {
      if (t + 1 < 6) loadB<3>(bp[(t + 1) & 1], wbase, 384, (t + 1) * 64, l15, l4);
      #pragma unroll
      for (int ks = 0; ks < 2; ++ks) {
        const int rl = wr * 16 + l15;
        short8 a = *(const short8*)(Hb + swz(rl, rl * 768 + (t * 64 + ks * 32 + l4 * 8) * 2));
        #pragma unroll
        for (int n = 0; n < 3; ++n)
          a3[n] = mfma16x16x32_bf16(a, bp[t & 1].v[n][ks], a3[n]);
      }
    }
  }
  u16* o16 = (u16*)outv;
  float* o32 = (float*)outv;
  const int dtf = flag[1];
  #pragma unroll
  for (int n = 0; n < 3; ++n) {
    const int col = wc * 48 + n * 16 + l15;
    const float bi = bf2f(bc[col]);
    #pragma unroll
    for (int j = 0; j < 4; ++j) {
      const int rl = wr * 16 + l4 * 4 + j;
      const size_t oi = (size_t)(row0 + rl) * cD + col;
      const float r = (a3[n][j] + bi) * 0.5f + XM[oi];
      if (dtf) o16[oi] = f2bf(r);
      else o32[oi] = r;
    }
  }
}

// ---------------------------------------------------------------------------
// attn v3 (unchanged).
__global__ __launch_bounds__(256) void attn_kernel(const u16* __restrict__ qkv,
                                                   const int* __restrict__ knn,
                                                   u16* __restrict__ o_out) {
  const int wid = threadIdx.x >> 6;
  const int lane = threadIdx.x & 63;
  const int bq = blockIdx.x * 4 + wid;
  const int b = bq >> 12;
  __shared__ float w4[4][8][8];
  __shared__ int vid4[4][8][8];
  __shared__ int nb4[4][16];
  float (*w)[8] = w4[wid];
  int (*vid)[8] = vid4[wid];
  int* nb = nb4[wid];
  if (lane < 16) nb[lane] = knn[bq * cKN + lane];
  const int h = lane >> 3;
  const int j = lane & 7;
  const uint2* qp = (const uint2*)(qkv + (size_t)bq * c3E + h * 48);
  const int r0 = nb[j], r1 = nb[j + 8];
  const uint2* k0p = (const uint2*)(qkv + ((size_t)(b * cV + r0)) * c3E + cE + h * 48);
  const uint2* k1p = (const uint2*)(qkv + ((size_t)(b * cV + r1)) * c3E + cE + h * 48);
  float s0 = 0.f, s1 = 0.f;
  #pragma unroll
  for (int t = 0; t < 12; ++t) {
    uint2 qv = qp[t];
    uint2 k0 = k0p[t];
    uint2 k1 = k1p[t];
    s0 += bflo(qv.x) * bflo(k0.x) + bfhi(qv.x) * bfhi(k0.x)
        + bflo(qv.y) * bflo(k0.y) + bfhi(qv.y) * bfhi(k0.y);
    s1 += bflo(qv.x) * bflo(k1.x) + bfhi(qv.x) * bfhi(k1.x)
        + bflo(qv.y) * bflo(k1.y) + bfhi(qv.y) * bfhi(k1.y);
  }
  const float inv = 0.14433756729740643f;  // 1/sqrt(48)
  u64 key0 = (((u64)f2ord(s0 * inv)) << 4) | (u64)(15 - j);
  u64 key1 = (((u64)f2ord(s1 * inv)) << 4) | (u64)(15 - (j + 8));
  float m0 = 0.f, Z = 0.f, myw = 0.f;
  int myv = 0;
  #pragma unroll
  for (int r = 0; r < cTK; ++r) {
    u64 best = key0 > key1 ? key0 : key1;
    u64 o1 = __shfl_xor(best, 1); if (o1 > best) best = o1;
    u64 o2 = __shfl_xor(best, 2); if (o2 > best) best = o2;
    u64 o4 = __shfl_xor(best, 4); if (o4 > best) best = o4;
    if (key0 == best) key0 = 0;
    if (key1 == best) key1 = 0;
    float sv = ord2f((u32)(best >> 4));
    int nsel = 15 - (int)(best & 15ull);
    if (r == 0) m0 = sv;
    float e = expf(sv - m0);
    Z += e;
    if (j == r) { myw = e; myv = nsel; }
  }
  w[h][j] = myw / Z;
  vid[h][j] = nb[myv];
  const u16* vbase = qkv + (size_t)(b * cV) * c3E + 2 * cE;
  #pragma unroll
  for (int rep = 0; rep < 6; ++rep) {
    int e = rep * 64 + lane;
    int h2 = e / 48;
    float acc = 0.f;
    #pragma unroll
    for (int t = 0; t < cTK; ++t)
      acc += w[h2][t] * bf2f(vbase[(size_t)vid[h2][t] * c3E + e]);
    o_out[(size_t)bq * cE + e] = f2bf(acc);
  }
}

// ---------------------------------------------------------------------------
extern "C" void kernel_launch(void* const* d_in, const int* in_sizes, int n_in,
                              void* d_out, int out_size, void* d_ws, size_t ws_size,
                              hipStream_t stream) {
  if (n_in < 18) return;
  const void* mask = d_in[1];

  char* ws = (char*)d_ws;
  size_t off = 0;
  auto alloc = [&](size_t bytes) { size_t o = off; off += (bytes + 255) & ~(size_t)255; return o; };
  int* flag  = (int*)(ws + alloc(256));
  u64* bmask = (u64*)(ws + alloc(128 * 8));
  int* knn   = (int*)(ws + alloc((size_t)cM * cKN * 4));
  float* XM  = (float*)(ws + alloc((size_t)cM * cD * 4));
  u16* S1    = (u16*)(ws + alloc((size_t)cM * cE * 2));
  u16* S2    = (u16*)(ws + alloc((size_t)cM * cE * 2));
  u16* QB    = (u16*)(ws + alloc((size_t)cM * c3E * 2));
  u16* tokc  = (u16*)(ws + alloc((size_t)cM * cD * 2));
  u16* be    = (u16*)(ws + alloc(cE * 2));
  u16* g1    = (u16*)(ws + alloc(cE * 2));
  u16* bt1   = (u16*)(ws + alloc(cE * 2));
  u16* bqkv  = (u16*)(ws + alloc(c3E * 2));
  u16* bo    = (u16*)(ws + alloc(cE * 2));
  u16* bc    = (u16*)(ws + alloc(cD * 2));
  u16* g2    = (u16*)(ws + alloc(cE * 2));
  u16* bt2   = (u16*)(ws + alloc(cE * 2));
  u16* b1    = (u16*)(ws + alloc(2 * cE * 2));
  u16* b2    = (u16*)(ws + alloc(cE * 2));
  u16* WeT   = (u16*)(ws + alloc((size_t)384 * 192 * 2));
  u16* WqkvT = (u16*)(ws + alloc((size_t)1152 * 384 * 2));
  u16* WoT   = (u16*)(ws + alloc((size_t)384 * 384 * 2));
  u16* WcT   = (u16*)(ws + alloc((size_t)256 * 384 * 2));   // rows padded 192->256
  u16* W1T   = (u16*)(ws + alloc((size_t)768 * 384 * 2));
  u16* W2T   = (u16*)(ws + alloc((size_t)384 * 768 * 2));
  (void)ws_size; (void)in_sizes; (void)out_size;

  detect_all_kernel<<<1, 256, 0, stream>>>((const u32*)d_in[0], (const u32*)mask, flag);

  {
    PrepArgs pa;
    const int csrci[11] = {0, 3, 4, 5, 7, 9, 11, 12, 13, 15, 17};
    u16* cdsts[11] = {tokc, be, g1, bt1, bqkv, bo, bc, g2, bt2, b1, b2};
    const int cns[11] = {cM * cD, cE, cE, cE, c3E, cE, cD, cE, cE, 2 * cE, cE};
    for (int i = 0; i < 11; ++i) { pa.csrc[i] = d_in[csrci[i]]; pa.cdst[i] = cdsts[i]; pa.cn[i] = cns[i]; }
    const int tsrci[6] = {2, 6, 8, 10, 14, 16};
    u16* tdsts[6] = {WeT, WqkvT, WoT, WcT, W1T, W2T};
    const int tKs[6] = {192, 384, 384, 384, 384, 768};
    const int tNs[6] = {384, 1152, 384, 192, 768, 384};
    for (int i = 0; i < 6; ++i) { pa.tsrc[i] = d_in[tsrci[i]]; pa.tdst[i] = tdsts[i]; pa.tK[i] = tKs[i]; pa.tN[i] = tNs[i]; }
    pa.mask = mask; pa.bm = bmask;
    prep_kernel<<<dim3(96, 18), 256, 0, stream>>>(pa, flag);
  }

  knn_kernel<<<cM / 4, 256, 0, stream>>>(bmask, knn);

  const int GB = cM / 32;  // 256 blocks
  fused_ln_qkv<<<GB, 512, 0, stream>>>(tokc, WeT, be, g1, bt1, WqkvT, bqkv, QB);
  attn_kernel<<<cM / 4, 256, 0, stream>>>(QB, knn, S2);
  fused_mid<<<GB, 512, 0, stream>>>(S2, WoT, bo, mask, flag, WcT, bc, tokc, XM,
                                    WeT, be, g2, bt2, S1);
  fused_ffn<<<GB, 512, 0, stream>>>(S1, W1T, b1, W2T, b2, WcT, bc, XM, d_out, flag);
}

// Round 11
// 178.940 us; speedup vs baseline: 1.1099x; 1.1099x over previous
//
#include <hip/hip_runtime.h>
#include <stdint.h>

// ============================================================================
// DSVABlockLarge — round 11: round-8 base (last PASS) + m201-style counted
// vmcnt K-loops with raw barriers (no implicit vmcnt(0) drain per step).
//  * Per K-step: issue next cluster -> sched_barrier -> vmcnt(L) -> s_barrier
//    -> compute -> s_barrier. L = loads/wave/step (6 or 3). Clusters pinned
//    with sched_barrier(0) (round-10 failure was unpinned cluster reorder).
//  * Staged tiles swizzled (round 8); intermediates swizzled; epilogues,
//    detect/prep/knn/attn byte-identical to round 8.
// ============================================================================

using u16 = unsigned short;
using u32 = unsigned int;
using u64 = unsigned long long;

typedef short short8 __attribute__((ext_vector_type(8)));
typedef float f32x4 __attribute__((ext_vector_type(4)));

#define DEV static __device__ __forceinline__

constexpr int cV = 4096, cD = 192;
constexpr int cE = 384;
constexpr int cKN = 16, cTK = 8;
constexpr int cM = 2 * cV;   // 8192 rows (B*V)
constexpr int c3E = 1152;

DEV float bf2f(u16 v) { return __uint_as_float(((u32)v) << 16); }
DEV float bflo(u32 v) { return __uint_as_float(v << 16); }
DEV float bfhi(u32 v) { return __uint_as_float(v & 0xFFFF0000u); }
DEV u16 f2bf(float f) {
  u32 u = __float_as_uint(f);
  u = (u + 0x7FFFu + ((u >> 16) & 1u)) >> 16;
  return (u16)u;
}
DEV int mget(const void* mp, int flag, int i) {
  if (flag == 0) return ((const int*)mp)[i] != 0;
  if (flag == 1) return ((const float*)mp)[i] != 0.0f;
  if (flag == 2) return ((const u16*)mp)[i] != 0;
  return ((const unsigned char*)mp)[i] != 0;
}
DEV float gelu_tanh(float x) {
  float t = tanhf(0.7978845608028654f * (x + 0.044715f * x * x * x));
  return 0.5f * x * (1.0f + t);
}
DEV u32 f2ord(float f) {
  u32 u = __float_as_uint(f);
  return (u & 0x80000000u) ? ~u : (u | 0x80000000u);
}
DEV float ord2f(u32 o) {
  u32 bits = (o & 0x80000000u) ? (o & 0x7FFFFFFFu) : ~o;
  return __uint_as_float(bits);
}
DEV int bf_plausible(u32 h) {
  if (h == 0u || h == 0x8000u) return 1;
  u32 e = (h >> 7) & 0xFFu;
  return (e >= 100u && e <= 140u) ? 1 : 0;
}

using as1p = const unsigned int __attribute__((address_space(1)))*;
using as3p = unsigned int __attribute__((address_space(3)))*;
DEV void gload16(const void* g, void* l) {
  __builtin_amdgcn_global_load_lds((as1p)g, (as3p)l, 16, 0, 0);
}
DEV f32x4 mfma16x16x32_bf16(short8 a, short8 b, f32x4 c) {
  asm volatile("v_mfma_f32_16x16x32_bf16 %0, %1, %2, %0" : "+v"(c) : "v"(a), "v"(b));
  return c;
}
DEV int swz(int row, int byteoff) { return byteoff ^ ((row & 7) << 4); }
DEV int ldswz(int r, int c) { return r * 64 + (c ^ ((r & 7) * 8)); }

// Pin cluster order, counted wait, raw barrier (no implicit drain).
#define SBPIN() __builtin_amdgcn_sched_barrier(0)
#define VMW(N) do { \
  __builtin_amdgcn_sched_barrier(0); \
  asm volatile("s_waitcnt vmcnt(" #N ")" ::: "memory"); \
  __builtin_amdgcn_sched_barrier(0); \
} while (0)
DEV void sbar() {
  __builtin_amdgcn_s_barrier();
  __builtin_amdgcn_sched_barrier(0);
}

// ---------------------------------------------------------------------------
__global__ void detect_all_kernel(const u32* __restrict__ tok,
                                  const u32* __restrict__ m,
                                  int* __restrict__ flag) {
  __shared__ int cnt, sa, sb, sc;
  if (threadIdx.x == 0) { cnt = 0; sa = 0; sb = 0; sc = 0; }
  __syncthreads();
  int c = 0;
  for (int i = threadIdx.x; i < 4096; i += 256) {
    u32 d = tok[i];
    c += bf_plausible(d & 0xFFFFu) & bf_plausible(d >> 16);
  }
  atomicAdd(&cnt, c);
  int a = 0, b = 0, cc = 0;
  for (int i = threadIdx.x; i < 2048; i += 256) {
    u32 d = m[i];
    if (!(d == 0u || d == 1u)) a = 1;
    if (!(d == 0u || d == 0x3F800000u)) b = 1;
    if (!(d == 0u || d == 0x00003F80u || d == 0x3F800000u || d == 0x3F803F80u)) cc = 1;
  }
  if (a) atomicOr(&sa, 1);
  if (b) atomicOr(&sb, 1);
  if (cc) atomicOr(&sc, 1);
  __syncthreads();
  if (threadIdx.x == 0) {
    flag[1] = (cnt > 3400) ? 1 : 0;
    flag[0] = (sa == 0) ? 0 : ((sb == 0) ? 1 : ((sc == 0) ? 2 : 3));
  }
}

// ---------------------------------------------------------------------------
struct PrepArgs {
  const void* csrc[11]; u16* cdst[11]; int cn[11];
  const void* tsrc[6]; u16* tdst[6]; int tK[6]; int tN[6];
  const void* mask; u64* bm;
};
__global__ __launch_bounds__(256) void prep_kernel(PrepArgs a, const int* __restrict__ flag) {
  const int job = blockIdx.y;
  const int dt = flag[1];
  if (job < 11) {
    const int n = a.cn[job];
    u16* d = a.cdst[job];
    if (dt) {
      const u16* s = (const u16*)a.csrc[job];
      for (int i = blockIdx.x * 256 + threadIdx.x; i < n; i += gridDim.x * 256) d[i] = s[i];
    } else {
      const float* s = (const float*)a.csrc[job];
      for (int i = blockIdx.x * 256 + threadIdx.x; i < n; i += gridDim.x * 256) d[i] = f2bf(s[i]);
    }
  } else if (job < 17) {
    const int t = job - 11;
    const int K = a.tK[t], N = a.tN[t];
    const int total = K * N;
    u16* d = a.tdst[t];
    for (int i = blockIdx.x * 256 + threadIdx.x; i < total; i += gridDim.x * 256) {
      int n = i / K, k = i - n * K;
      u16 vv;
      if (dt) vv = ((const u16*)a.tsrc[t])[(size_t)k * N + n];
      else vv = f2bf(((const float*)a.tsrc[t])[(size_t)k * N + n]);
      d[i] = vv;
    }
  } else {
    const int gw = (blockIdx.x * 256 + threadIdx.x) >> 6;
    const int lane = threadIdx.x & 63;
    if (gw < 128) {
      const int fl = flag[0];
      u64 bal = __ballot(mget(a.mask, fl, gw * 64 + lane) != 0);
      if (lane == 0) a.bm[gw] = bal;
    }
  }
}

// ---------------------------------------------------------------------------
// KNN v2 (unchanged).
__global__ __launch_bounds__(256) void knn_kernel(const u64* __restrict__ bitmask,
                                                  int* __restrict__ knn_out) {
  const int tid = threadIdx.x;
  const int wid = tid >> 6, lane = tid & 63;
  const int q0 = blockIdx.x * 4;
  const int b = q0 >> 12;
  const int q = q0 + wid;
  const int v = q & 4095;
  __shared__ u64 smask[64];
  __shared__ int hist4[4][64];
  __shared__ int listT[4][64];
  __shared__ int out16s[4][16];
  __shared__ int meta[4][3];
  __shared__ int cntA[4], cntT[4];
  if (tid < 64) smask[tid] = bitmask[b * 64 + tid];
  for (int i = tid; i < 4 * 64; i += 256) ((int*)hist4)[i] = 0;
  if (lane == 0) { cntA[wid] = 0; cntT[wid] = 0; }
  __syncthreads();
  const int iv = v >> 8, jv = (v >> 4) & 15, kv = v & 15;
  #pragma unroll
  for (int t = 0; t < 12; ++t) {
    int o = t * 64 + lane;
    if (o < 729) {
      int oi = o / 81, rm = o - oi * 81;
      int oj = rm / 9, ok = rm - oj * 9;
      int i = iv + oi - 4, j = jv + oj - 4, k = kv + ok - 4;
      if (((i | j | k) & ~15) == 0) {
        int u = (i << 8) | (j << 4) | k;
        if ((smask[u >> 6] >> (u & 63)) & 1ull) {
          int di = oi - 4, dj = oj - 4, dk = ok - 4;
          atomicAdd(&hist4[wid][di * di + dj * dj + dk * dk], 1);
        }
      }
    }
  }
  __syncthreads();
  if (lane == 0) {
    int cum = 0, T = -1, below = 0;
    for (int d = 0; d <= 48; ++d) {
      int h = hist4[wid][d];
      if (h > 0 && cum + h >= cKN) { T = d; below = cum; break; }
      cum += h;
    }
    if (T > 24) T = -1;
    meta[wid][0] = T; meta[wid][1] = below; meta[wid][2] = (T < 0) ? 1 : 0;
  }
  __syncthreads();
  const int T = meta[wid][0], below = meta[wid][1], fb = meta[wid][2];
  #pragma unroll
  for (int t = 0; t < 12; ++t) {
    int o = t * 64 + lane;
    if (o < 729) {
      int oi = o / 81, rm = o - oi * 81;
      int oj = rm / 9, ok = rm - oj * 9;
      int i = iv + oi - 4, j = jv + oj - 4, k = kv + ok - 4;
      if (((i | j | k) & ~15) == 0) {
        int u = (i << 8) | (j << 4) | k;
        if ((smask[u >> 6] >> (u & 63)) & 1ull) {
          int di = oi - 4, dj = oj - 4, dk = ok - 4;
          int d2 = di * di + dj * dj + dk * dk;
          if (d2 < T) { int p = atomicAdd(&cntA[wid], 1); out16s[wid][p] = u; }
          else if (d2 == T) { int p = atomicAdd(&cntT[wid], 1); if (p < 64) listT[wid][p] = u; }
        }
      }
    }
  }
  __syncthreads();
  if (!fb) {
    if (lane == 0) {
      int need = cKN - below;
      int nT = cntT[wid] < 64 ? cntT[wid] : 64;
      for (int r = 0; r < need; ++r) {
        int bi = 0, bu = 0x7FFFFFFF;
        for (int i2 = 0; i2 < nT; ++i2) { int x = listT[wid][i2]; if (x < bu) { bu = x; bi = i2; } }
        out16s[wid][below + r] = bu;
        listT[wid][bi] = 0x7FFFFFFF;
      }
    }
  } else {
    u64 rem = smask[lane];
    const int myi = lane >> 2;
    const int di2 = (iv - myi) * (iv - myi);
    for (int r = 0; r < cKN; ++r) {
      u64 tmp = rem;
      u32 best = 0xFFFFFFFFu;
      while (tmp) {
        int bp = __builtin_ctzll(tmp);
        tmp &= tmp - 1;
        int u = (lane << 6) | bp;
        int dj = jv - ((u >> 4) & 15), dk = kv - (u & 15);
        u32 key = (u32)(((di2 + dj * dj + dk * dk) << 12) | u);
        if (key < best) best = key;
      }
      u32 pk = (best == 0xFFFFFFFFu) ? 0xFFFFFFFFu : ((best << 6) | (u32)lane);
      #pragma unroll
      for (int off = 1; off < 64; off <<= 1) {
        u32 o2 = __shfl_xor(pk, off);
        if (o2 < pk) pk = o2;
      }
      int u = (int)((pk >> 6) & 4095u);
      int wl = (int)(pk & 63u);
      if (lane == wl) rem &= ~(1ull << (u & 63));
      if (lane == 0) out16s[wid][r] = u;
    }
  }
  __syncthreads();
  if (lane < cKN) knn_out[q * cKN + lane] = out16s[wid][lane];
}

// ---------------------------------------------------------------------------
// F_A: X1 = LN(tok@We+be; g1,bt1) (LDS) ; QB = X1@Wqkv + bqkv.
__global__ __launch_bounds__(512) void fused_ln_qkv(
    const u16* __restrict__ tokc, const u16* __restrict__ WeT,
    const u16* __restrict__ be, const u16* __restrict__ g1, const u16* __restrict__ bt1,
    const u16* __restrict__ WqkvT, const u16* __restrict__ bqkv,
    u16* __restrict__ QB) {
  __shared__ alignas(16) u16 Afull[3 * 2048];    // 12KB tok K=192 (swz)
  __shared__ alignas(16) u16 Bst[2][384 * 64];   // 96KB dbuf
  __shared__ alignas(16) char X1[32 * 768];      // 24KB swz
  __shared__ float st[32][4][2];
  const int tid = threadIdx.x;
  const int lane = tid & 63, wave = tid >> 6;
  const int wr = wave >> 2, wc = wave & 3;
  const int l15 = lane & 15, l4 = lane >> 4;
  const int sr = lane >> 3;
  const int scs = (((lane & 7) ^ sr) << 3);
  const int row0 = blockIdx.x * 32;

  // A staging + stage-1 B step 0
  for (int g = wave; g < 12; g += 8)
    gload16(tokc + (size_t)(row0 + (g & 3) * 8 + sr) * 192 + (g >> 2) * 64 + scs,
            (char*)Afull + g * 1024);
  #pragma unroll
  for (int i = 0; i < 6; ++i) {
    const int g = wave * 6 + i;
    gload16(WeT + (size_t)(g * 8 + sr) * 192 + scs, (char*)&Bst[0][0] + g * 1024);
  }
  SBPIN();
  __syncthreads();   // full drain once (A + B0 landed for all waves)

  // stage 1: tok @ WeT^T (3 K-steps)
  f32x4 acc[6];
  #pragma unroll
  for (int n = 0; n < 6; ++n) acc[n] = f32x4{0.f, 0.f, 0.f, 0.f};
  int cur = 0;
  #pragma unroll
  for (int t = 0; t < 3; ++t) {
    if (t + 1 < 3) {
      #pragma unroll
      for (int i = 0; i < 6; ++i) {
        const int g = wave * 6 + i;
        gload16(WeT + (size_t)(g * 8 + sr) * 192 + (t + 1) * 64 + scs,
                (char*)&Bst[cur ^ 1][0] + g * 1024);
      }
      VMW(6);
    } else {
      VMW(0);
    }
    sbar();
    #pragma unroll
    for (int ks = 0; ks < 2; ++ks) {
      short8 a = *(const short8*)&Afull[t * 2048 + ldswz(wr * 16 + l15, ks * 32 + l4 * 8)];
      #pragma unroll
      for (int n = 0; n < 6; ++n) {
        short8 b = *(const short8*)&Bst[cur][ldswz(wc * 96 + n * 16 + l15, ks * 32 + l4 * 8)];
        acc[n] = mfma16x16x32_bf16(a, b, acc[n]);
      }
    }
    sbar();
    cur ^= 1;
  }
  // LN epilogue -> X1
  float s[4] = {0, 0, 0, 0}, sq[4] = {0, 0, 0, 0};
  #pragma unroll
  for (int n = 0; n < 6; ++n) {
    const float bi = bf2f(be[wc * 96 + n * 16 + l15]);
    #pragma unroll
    for (int j = 0; j < 4; ++j) {
      acc[n][j] += bi;
      s[j] += acc[n][j]; sq[j] += acc[n][j] * acc[n][j];
    }
  }
  #pragma unroll
  for (int off = 1; off < 16; off <<= 1) {
    #pragma unroll
    for (int j = 0; j < 4; ++j) { s[j] += __shfl_xor(s[j], off); sq[j] += __shfl_xor(sq[j], off); }
  }
  if (l15 == 0) {
    #pragma unroll
    for (int j = 0; j < 4; ++j) {
      const int rl = wr * 16 + l4 * 4 + j;
      st[rl][wc][0] = s[j]; st[rl][wc][1] = sq[j];
    }
  }
  __syncthreads();
  #pragma unroll
  for (int j = 0; j < 4; ++j) {
    const int rl = wr * 16 + l4 * 4 + j;
    const float mean = (st[rl][0][0] + st[rl][1][0] + st[rl][2][0] + st[rl][3][0]) * (1.0f / 384.0f);
    const float var = (st[rl][0][1] + st[rl][1][1] + st[rl][2][1] + st[rl][3][1]) * (1.0f / 384.0f) - mean * mean;
    const float rstd = rsqrtf(var + 1e-5f);
    #pragma unroll
    for (int n = 0; n < 6; ++n) {
      const int col = wc * 96 + n * 16 + l15;
      const float v = (acc[n][j] - mean) * rstd * bf2f(g1[col]) + bf2f(bt1[col]);
      *(u16*)(X1 + swz(rl, rl * 768 + col * 2)) = f2bf(v);
    }
  }
  __syncthreads();

  // stage 2: QB = X1 @ WqkvT^T + bqkv (3 chunks, 6 K-steps each)
  for (int chunk = 0; chunk < 3; ++chunk) {
    #pragma unroll
    for (int i = 0; i < 6; ++i) {
      const int g = wave * 6 + i;
      gload16(WqkvT + (size_t)(chunk * 384 + g * 8 + sr) * 384 + scs,
              (char*)&Bst[0][0] + g * 1024);
    }
    SBPIN();
    f32x4 a2[6];
    #pragma unroll
    for (int n = 0; n < 6; ++n) a2[n] = f32x4{0.f, 0.f, 0.f, 0.f};
    cur = 0;
    #pragma unroll
    for (int t = 0; t < 6; ++t) {
      if (t + 1 < 6) {
        #pragma unroll
        for (int i = 0; i < 6; ++i) {
          const int g = wave * 6 + i;
          gload16(WqkvT + (size_t)(chunk * 384 + g * 8 + sr) * 384 + (t + 1) * 64 + scs,
                  (char*)&Bst[cur ^ 1][0] + g * 1024);
        }
        VMW(6);
      } else {
        VMW(0);
      }
      sbar();
      #pragma unroll
      for (int ks = 0; ks < 2; ++ks) {
        const int rl = wr * 16 + l15;
        short8 a = *(const short8*)(X1 + swz(rl, rl * 768 + (t * 64 + ks * 32 + l4 * 8) * 2));
        #pragma unroll
        for (int n = 0; n < 6; ++n) {
          short8 b = *(const short8*)&Bst[cur][ldswz(wc * 96 + n * 16 + l15, ks * 32 + l4 * 8)];
          a2[n] = mfma16x16x32_bf16(a, b, a2[n]);
        }
      }
      sbar();
      cur ^= 1;
    }
    #pragma unroll
    for (int n = 0; n < 6; ++n) {
      const int col = chunk * 384 + wc * 96 + n * 16 + l15;
      const float bi = bf2f(bqkv[col]);
      #pragma unroll
      for (int j = 0; j < 4; ++j)
        QB[(size_t)(row0 + wr * 16 + l4 * 4 + j) * c3E + col] = f2bf(a2[n][j] + bi);
    }
  }
}

// ---------------------------------------------------------------------------
// F_C: T=(S2@Wo+bo)*mask ; XM=(T@Wc+bc)*0.5+tok (f32) ; S1=LN(XM@We+be)
__global__ __launch_bounds__(512) void fused_mid(
    const u16* __restrict__ S2, const u16* __restrict__ WoT, const u16* __restrict__ bo,
    const void* __restrict__ mask, const int* __restrict__ flag,
    const u16* __restrict__ WcT, const u16* __restrict__ bc, const u16* __restrict__ tokc,
    float* __restrict__ XM,
    const u16* __restrict__ WeT, const u16* __restrict__ be,
    const u16* __restrict__ g2, const u16* __restrict__ bt2, u16* __restrict__ S1out) {
  __shared__ alignas(16) u16 Afull[6 * 2048];    // 24KB S2
  __shared__ alignas(16) u16 Bst[2][384 * 64];   // 96KB dbuf
  __shared__ alignas(16) char Tb[32 * 768];      // 24KB T swz; X2 overlays
  __shared__ float st[32][4][2];
  char* X2 = Tb;
  const int tid = threadIdx.x;
  const int lane = tid & 63, wave = tid >> 6;
  const int wr = wave >> 2, wc = wave & 3;
  const int l15 = lane & 15, l4 = lane >> 4;
  const int sr = lane >> 3;
  const int scs = (((lane & 7) ^ sr) << 3);
  const int row0 = blockIdx.x * 32;
  const int fl = flag[0];

  for (int g = wave; g < 24; g += 8)
    gload16(S2 + (size_t)(row0 + (g & 3) * 8 + sr) * cE + (g >> 2) * 64 + scs,
            (char*)Afull + g * 1024);
  #pragma unroll
  for (int i = 0; i < 6; ++i) {
    const int g = wave * 6 + i;
    gload16(WoT + (size_t)(g * 8 + sr) * 384 + scs, (char*)&Bst[0][0] + g * 1024);
  }
  SBPIN();
  __syncthreads();

  // stage 1: T = (S2 @ WoT^T + bo) * fmask (6 K-steps)
  f32x4 acc[6];
  #pragma unroll
  for (int n = 0; n < 6; ++n) acc[n] = f32x4{0.f, 0.f, 0.f, 0.f};
  int cur = 0;
  #pragma unroll
  for (int t = 0; t < 6; ++t) {
    if (t + 1 < 6) {
      #pragma unroll
      for (int i = 0; i < 6; ++i) {
        const int g = wave * 6 + i;
        gload16(WoT + (size_t)(g * 8 + sr) * 384 + (t + 1) * 64 + scs,
                (char*)&Bst[cur ^ 1][0] + g * 1024);
      }
      VMW(6);
    } else {
      VMW(0);
    }
    sbar();
    #pragma unroll
    for (int ks = 0; ks < 2; ++ks) {
      short8 a = *(const short8*)&Afull[t * 2048 + ldswz(wr * 16 + l15, ks * 32 + l4 * 8)];
      #pragma unroll
      for (int n = 0; n < 6; ++n) {
        short8 b = *(const short8*)&Bst[cur][ldswz(wc * 96 + n * 16 + l15, ks * 32 + l4 * 8)];
        acc[n] = mfma16x16x32_bf16(a, b, acc[n]);
      }
    }
    sbar();
    cur ^= 1;
  }
  #pragma unroll
  for (int j = 0; j < 4; ++j) {
    const int rl = wr * 16 + l4 * 4 + j;
    const float fm = mget(mask, fl, row0 + rl) ? 1.0f : 0.0f;
    #pragma unroll
    for (int n = 0; n < 6; ++n) {
      const int col = wc * 96 + n * 16 + l15;
      const float v = (acc[n][j] + bf2f(bo[col])) * fm;
      *(u16*)(Tb + swz(rl, rl * 768 + col * 2)) = f2bf(v);
    }
  }
  __syncthreads();

  // stage 2: XM = (T @ WcT^T + bc)*0.5 + tok (6 K-steps, N=192, 3 loads/wave)
  {
    #pragma unroll
    for (int i = 0; i < 3; ++i) {
      const int g = wave * 3 + i;
      gload16(WcT + (size_t)(g * 8 + sr) * 384 + scs, (char*)&Bst[0][0] + g * 1024);
    }
    SBPIN();
    f32x4 a2[3];
    #pragma unroll
    for (int n = 0; n < 3; ++n) a2[n] = f32x4{0.f, 0.f, 0.f, 0.f};
    cur = 0;
    #pragma unroll
    for (int t = 0; t < 6; ++t) {
      if (t + 1 < 6) {
        #pragma unroll
        for (int i = 0; i < 3; ++i) {
          const int g = wave * 3 + i;
          gload16(WcT + (size_t)(g * 8 + sr) * 384 + (t + 1) * 64 + scs,
                  (char*)&Bst[cur ^ 1][0] + g * 1024);
        }
        VMW(3);
      } else {
        VMW(0);
      }
      sbar();
      #pragma unroll
      for (int ks = 0; ks < 2; ++ks) {
        const int rl = wr * 16 + l15;
        short8 a = *(const short8*)(Tb + swz(rl, rl * 768 + (t * 64 + ks * 32 + l4 * 8) * 2));
        #pragma unroll
        for (int n = 0; n < 3; ++n) {
          short8 b = *(const short8*)&Bst[cur][ldswz(wc * 48 + n * 16 + l15, ks * 32 + l4 * 8)];
          a2[n] = mfma16x16x32_bf16(a, b, a2[n]);
        }
      }
      sbar();
      cur ^= 1;
    }
    __syncthreads();   // all reads of Tb done before X2 overlay
    #pragma unroll
    for (int n = 0; n < 3; ++n) {
      const int col = wc * 48 + n * 16 + l15;
      const float bi = bf2f(bc[col]);
      #pragma unroll
      for (int j = 0; j < 4; ++j) {
        const int rl = wr * 16 + l4 * 4 + j;
        const size_t oi = (size_t)(row0 + rl) * cD + col;
        const float r = (a2[n][j] + bi) * 0.5f + bf2f(tokc[oi]);
        XM[oi] = r;
        *(u16*)(X2 + swz(rl, rl * 384 + col * 2)) = f2bf(r);
      }
    }
  }
  __syncthreads();

  // stage 3: S1 = LN(X2 @ WeT^T + be; g2, bt2) (3 K-steps)
  {
    #pragma unroll
    for (int i = 0; i < 6; ++i) {
      const int g = wave * 6 + i;
      gload16(WeT + (size_t)(g * 8 + sr) * 192 + scs, (char*)&Bst[0][0] + g * 1024);
    }
    SBPIN();
    f32x4 a3[6];
    #pragma unroll
    for (int n = 0; n < 6; ++n) a3[n] = f32x4{0.f, 0.f, 0.f, 0.f};
    cur = 0;
    #pragma unroll
    for (int t = 0; t < 3; ++t) {
      if (t + 1 < 3) {
        #pragma unroll
        for (int i = 0; i < 6; ++i) {
          const int g = wave * 6 + i;
          gload16(WeT + (size_t)(g * 8 + sr) * 192 + (t + 1) * 64 + scs,
                  (char*)&Bst[cur ^ 1][0] + g * 1024);
        }
        VMW(6);
      } else {
        VMW(0);
      }
      sbar();
      #pragma unroll
      for (int ks = 0; ks < 2; ++ks) {
        const int rl = wr * 16 + l15;
        short8 a = *(const short8*)(X2 + swz(rl, rl * 384 + (t * 64 + ks * 32 + l4 * 8) * 2));
        #pragma unroll
        for (int n = 0; n < 6; ++n) {
          short8 b = *(const short8*)&Bst[cur][ldswz(wc * 96 + n * 16 + l15, ks * 32 + l4 * 8)];
          a3[n] = mfma16x16x32_bf16(a, b, a3[n]);
        }
      }
      sbar();
      cur ^= 1;
    }
    float s[4] = {0, 0, 0, 0}, sq[4] = {0, 0, 0, 0};
    #pragma unroll
    for (int n = 0; n < 6; ++n) {
      const float bi = bf2f(be[wc * 96 + n * 16 + l15]);
      #pragma unroll
      for (int j = 0; j < 4; ++j) {
        a3[n][j] += bi;
        s[j] += a3[n][j]; sq[j] += a3[n][j] * a3[n][j];
      }
    }
    #pragma unroll
    for (int off = 1; off < 16; off <<= 1) {
      #pragma unroll
      for (int j = 0; j < 4; ++j) { s[j] += __shfl_xor(s[j], off); sq[j] += __shfl_xor(sq[j], off); }
    }
    if (l15 == 0) {
      #pragma unroll
      for (int j = 0; j < 4; ++j) {
        const int rl = wr * 16 + l4 * 4 + j;
        st[rl][wc][0] = s[j]; st[rl][wc][1] = sq[j];
      }
    }
    __syncthreads();
    #pragma unroll
    for (int j = 0; j < 4; ++j) {
      const int rl = wr * 16 + l4 * 4 + j;
      const float mean = (st[rl][0][0] + st[rl][1][0] + st[rl][2][0] + st[rl][3][0]) * (1.0f / 384.0f);
      const float var = (st[rl][0][1] + st[rl][1][1] + st[rl][2][1] + st[rl][3][1]) * (1.0f / 384.0f) - mean * mean;
      const float rstd = rsqrtf(var + 1e-5f);
      #pragma unroll
      for (int n = 0; n < 6; ++n) {
        const int col = wc * 96 + n * 16 + l15;
        S1out[(size_t)(row0 + rl) * cE + col] =
            f2bf((a3[n][j] - mean) * rstd * bf2f(g2[col]) + bf2f(bt2[col]));
      }
    }
  }
}

// ---------------------------------------------------------------------------
// F_D: H=gelu(S1@W1+b1) per K-half ; F=H@W2+b2 (reg acc) ; out=(F@Wc+bc)/2+XM
__global__ __launch_bounds__(512) void fused_ffn(
    const u16* __restrict__ S1, const u16* __restrict__ W1T, const u16* __restrict__ b1,
    const u16* __restrict__ W2T, const u16* __restrict__ b2,
    const u16* __restrict__ WcT, const u16* __restrict__ bc,
    const float* __restrict__ XM, void* __restrict__ outv, const int* __restrict__ flag) {
  __shared__ alignas(16) u16 Afull[6 * 2048];    // 24KB S1
  __shared__ alignas(16) u16 Bst[2][384 * 64];   // 96KB dbuf
  __shared__ alignas(16) char Hb[32 * 768];      // 24KB H-half swz; F overlays
  const int tid = threadIdx.x;
  const int lane = tid & 63, wave = tid >> 6;
  const int wr = wave >> 2, wc = wave & 3;
  const int l15 = lane & 15, l4 = lane >> 4;
  const int sr = lane >> 3;
  const int scs = (((lane & 7) ^ sr) << 3);
  const int row0 = blockIdx.x * 32;

  for (int g = wave; g < 24; g += 8)
    gload16(S1 + (size_t)(row0 + (g & 3) * 8 + sr) * cE + (g >> 2) * 64 + scs,
            (char*)Afull + g * 1024);
  SBPIN();
  __syncthreads();

  f32x4 accF[6];
  #pragma unroll
  for (int n = 0; n < 6; ++n) accF[n] = f32x4{0.f, 0.f, 0.f, 0.f};

  for (int half = 0; half < 2; ++half) {
    // s1: H = gelu(S1 @ W1T[half]^T + b1[half]) (6 K-steps)
    {
      #pragma unroll
      for (int i = 0; i < 6; ++i) {
        const int g = wave * 6 + i;
        gload16(W1T + (size_t)(half * 384 + g * 8 + sr) * 384 + scs,
                (char*)&Bst[0][0] + g * 1024);
      }
      SBPIN();
      f32x4 a1[6];
      #pragma unroll
      for (int n = 0; n < 6; ++n) a1[n] = f32x4{0.f, 0.f, 0.f, 0.f};
      int cur = 0;
      #pragma unroll
      for (int t = 0; t < 6; ++t) {
        if (t + 1 < 6) {
          #pragma unroll
          for (int i = 0; i < 6; ++i) {
            const int g = wave * 6 + i;
            gload16(W1T + (size_t)(half * 384 + g * 8 + sr) * 384 + (t + 1) * 64 + scs,
                    (char*)&Bst[cur ^ 1][0] + g * 1024);
          }
          VMW(6);
        } else {
          VMW(0);
        }
        sbar();
        #pragma unroll
        for (int ks = 0; ks < 2; ++ks) {
          short8 a = *(const short8*)&Afull[t * 2048 + ldswz(wr * 16 + l15, ks * 32 + l4 * 8)];
          #pragma unroll
          for (int n = 0; n < 6; ++n) {
            short8 b = *(const short8*)&Bst[cur][ldswz(wc * 96 + n * 16 + l15, ks * 32 + l4 * 8)];
            a1[n] = mfma16x16x32_bf16(a, b, a1[n]);
          }
        }
        sbar();
        cur ^= 1;
      }
      #pragma unroll
      for (int n = 0; n < 6; ++n) {
        const int col = wc * 96 + n * 16 + l15;
        const float bi = bf2f(b1[half * 384 + col]);
        #pragma unroll
        for (int j = 0; j < 4; ++j) {
          const int rl = wr * 16 + l4 * 4 + j;
          *(u16*)(Hb + swz(rl, rl * 768 + col * 2)) = f2bf(gelu_tanh(a1[n][j] + bi));
        }
      }
    }
    __syncthreads();
    // s2: accF += H @ W2T[:, half]^T (6 K-steps)
    {
      #pragma unroll
      for (int i = 0; i < 6; ++i) {
        const int g = wave * 6 + i;
        gload16(W2T + (size_t)(g * 8 + sr) * 768 + half * 384 + scs,
                (char*)&Bst[0][0] + g * 1024);
      }
      SBPIN();
      int cur = 0;
      #pragma unroll
      for (int t = 0; t < 6; ++t) {
        if (t + 1 < 6) {
          #pragma unroll
          for (int i = 0; i < 6; ++i) {
            const int g = wave * 6 + i;
            gload16(W2T + (size_t)(g * 8 + sr) * 768 + half * 384 + (t + 1) * 64 + scs,
                    (char*)&Bst[cur ^ 1][0] + g * 1024);
          }
          VMW(6);
        } else {
          VMW(0);
        }
        sbar();
        #pragma unroll
        for (int ks = 0; ks < 2; ++ks) {
          const int rl = wr * 16 + l15;
          short8 a = *(const short8*)(Hb + swz(rl, rl * 768 + (t * 64 + ks * 32 + l4 * 8) * 2));
          #pragma unroll
          for (int n = 0; n < 6; ++n) {
            short8 b = *(const short8*)&Bst[cur][ldswz(wc * 96 + n * 16 + l15, ks * 32 + l4 * 8)];
            accF[n] = mfma16x16x32_bf16(a, b, accF[n]);
          }
        }
        sbar();
        cur ^= 1;
      }
    }
    __syncthreads();   // retire Hb readers before next half overwrites
  }
  // F = accF + b2 -> Hb
  #pragma unroll
  for (int n = 0; n < 6; ++n) {
    const int col = wc * 96 + n * 16 + l15;
    const float bi = bf2f(b2[col]);
    #pragma unroll
    for (int j = 0; j < 4; ++j) {
      const int rl = wr * 16 + l4 * 4 + j;
      *(u16*)(Hb + swz(rl, rl * 768 + col * 2)) = f2bf(accF[n][j] + bi);
    }
  }
  __syncthreads();
  // s3: out = (F @ WcT^T + bc)*0.5 + XM (6 K-steps, N=192, 3 loads/wave)
  f32x4 a3[3];
  #pragma unroll
  for (int n = 0; n < 3; ++n) a3[n] = f32x4{0.f, 0.f, 0.f, 0.f};
  {
    #pragma unroll
    for (int i = 0; i < 3; ++i) {
      const int g = wave * 3 + i;
      gload16(WcT + (size_t)(g * 8 + sr) * 384 + scs, (char*)&Bst[0][0] + g * 1024);
    }
    SBPIN();
    int cur = 0;
    #pragma unroll
    for (int t = 0; t < 6; ++t) {
      if (t + 1 < 6) {
        #pragma unroll
        for (int i = 0; i < 3; ++i) {
          const int g = wave * 3 + i;
          gload16(WcT + (size_t)(g * 8 + sr) * 384 + (t + 1) * 64 + scs,
                  (char*)&Bst[cur ^ 1][0] + g * 1024);
        }
        VMW(3);
      } else {
        VMW(0);
      }
      sbar();
      #pragma unroll
      for (int ks = 0; ks < 2; ++ks) {
        const int rl = wr * 16 + l15;
        short8 a = *(const short8*)(Hb + swz(rl, rl * 768 + (t * 64 + ks * 32 + l4 * 8) * 2));
        #pragma unroll
        for (int n = 0; n < 3; ++n) {
          short8 b = *(const short8*)&Bst[cur][ldswz(wc * 48 + n * 16 + l15, ks * 32 + l4 * 8)];
          a3[n] = mfma16x16x32_bf16(a, b, a3[n]);
        }
      }
      sbar();
      cur ^= 1;
    }
  }
  u16* o16 = (u16*)outv;
  float* o32 = (float*)outv;
  const int dtf = flag[1];
  #pragma unroll
  for (int n = 0; n < 3; ++n) {
    const int col = wc * 48 + n * 16 + l15;
    const float bi = bf2f(bc[col]);
    #pragma unroll
    for (int j = 0; j < 4; ++j) {
      const int rl = wr * 16 + l4 * 4 + j;
      const size_t oi = (size_t)(row0 + rl) * cD + col;
      const float r = (a3[n][j] + bi) * 0.5f + XM[oi];
      if (dtf) o16[oi] = f2bf(r);
      else o32[oi] = r;
    }
  }
}

// ---------------------------------------------------------------------------
// attn v3 (unchanged).
__global__ __launch_bounds__(256) void attn_kernel(const u16* __restrict__ qkv,
                                                   const int* __restrict__ knn,
                                                   u16* __restrict__ o_out) {
  const int wid = threadIdx.x >> 6;
  const int lane = threadIdx.x & 63;
  const int bq = blockIdx.x * 4 + wid;
  const int b = bq >> 12;
  __shared__ float w4[4][8][8];
  __shared__ int vid4[4][8][8];
  __shared__ int nb4[4][16];
  float (*w)[8] = w4[wid];
  int (*vid)[8] = vid4[wid];
  int* nb = nb4[wid];
  if (lane < 16) nb[lane] = knn[bq * cKN + lane];
  const int h = lane >> 3;
  const int j = lane & 7;
  const uint2* qp = (const uint2*)(qkv + (size_t)bq * c3E + h * 48);
  const int r0 = nb[j], r1 = nb[j + 8];
  const uint2* k0p = (const uint2*)(qkv + ((size_t)(b * cV + r0)) * c3E + cE + h * 48);
  const uint2* k1p = (const uint2*)(qkv + ((size_t)(b * cV + r1)) * c3E + cE + h * 48);
  float s0 = 0.f, s1 = 0.f;
  #pragma unroll
  for (int t = 0; t < 12; ++t) {
    uint2 qv = qp[t];
    uint2 k0 = k0p[t];
    uint2 k1 = k1p[t];
    s0 += bflo(qv.x) * bflo(k0.x) + bfhi(qv.x) * bfhi(k0.x)
        + bflo(qv.y) * bflo(k0.y) + bfhi(qv.y) * bfhi(k0.y);
    s1 += bflo(qv.x) * bflo(k1.x) + bfhi(qv.x) * bfhi(k1.x)
        + bflo(qv.y) * bflo(k1.y) + bfhi(qv.y) * bfhi(k1.y);
  }
  const float inv = 0.14433756729740643f;  // 1/sqrt(48)
  u64 key0 = (((u64)f2ord(s0 * inv)) << 4) | (u64)(15 - j);
  u64 key1 = (((u64)f2ord(s1 * inv)) << 4) | (u64)(15 - (j + 8));
  float m0 = 0.f, Z = 0.f, myw = 0.f;
  int myv = 0;
  #pragma unroll
  for (int r = 0; r < cTK; ++r) {
    u64 best = key0 > key1 ? key0 : key1;
    u64 o1 = __shfl_xor(best, 1); if (o1 > best) best = o1;
    u64 o2 = __shfl_xor(best, 2); if (o2 > best) best = o2;
    u64 o4 = __shfl_xor(best, 4); if (o4 > best) best = o4;
    if (key0 == best) key0 = 0;
    if (key1 == best) key1 = 0;
    float sv = ord2f((u32)(best >> 4));
    int nsel = 15 - (int)(best & 15ull);
    if (r == 0) m0 = sv;
    float e = expf(sv - m0);
    Z += e;
    if (j == r) { myw = e; myv = nsel; }
  }
  w[h][j] = myw / Z;
  vid[h][j] = nb[myv];
  const u16* vbase = qkv + (size_t)(b * cV) * c3E + 2 * cE;
  #pragma unroll
  for (int rep = 0; rep < 6; ++rep) {
    int e = rep * 64 + lane;
    int h2 = e / 48;
    float acc = 0.f;
    #pragma unroll
    for (int t = 0; t < cTK; ++t)
      acc += w[h2][t] * bf2f(vbase[(size_t)vid[h2][t] * c3E + e]);
    o_out[(size_t)bq * cE + e] = f2bf(acc);
  }
}

// ---------------------------------------------------------------------------
extern "C" void kernel_launch(void* const* d_in, const int* in_sizes, int n_in,
                              void* d_out, int out_size, void* d_ws, size_t ws_size,
                              hipStream_t stream) {
  if (n_in < 18) return;
  const void* mask = d_in[1];

  char* ws = (char*)d_ws;
  size_t off = 0;
  auto alloc = [&](size_t bytes) { size_t o = off; off += (bytes + 255) & ~(size_t)255; return o; };
  int* flag  = (int*)(ws + alloc(256));
  u64* bmask = (u64*)(ws + alloc(128 * 8));
  int* knn   = (int*)(ws + alloc((size_t)cM * cKN * 4));
  float* XM  = (float*)(ws + alloc((size_t)cM * cD * 4));
  u16* S1    = (u16*)(ws + alloc((size_t)cM * cE * 2));
  u16* S2    = (u16*)(ws + alloc((size_t)cM * cE * 2));
  u16* QB    = (u16*)(ws + alloc((size_t)cM * c3E * 2));
  u16* tokc  = (u16*)(ws + alloc((size_t)cM * cD * 2));
  u16* be    = (u16*)(ws + alloc(cE * 2));
  u16* g1    = (u16*)(ws + alloc(cE * 2));
  u16* bt1   = (u16*)(ws + alloc(cE * 2));
  u16* bqkv  = (u16*)(ws + alloc(c3E * 2));
  u16* bo    = (u16*)(ws + alloc(cE * 2));
  u16* bc    = (u16*)(ws + alloc(cD * 2));
  u16* g2    = (u16*)(ws + alloc(cE * 2));
  u16* bt2   = (u16*)(ws + alloc(cE * 2));
  u16* b1    = (u16*)(ws + alloc(2 * cE * 2));
  u16* b2    = (u16*)(ws + alloc(cE * 2));
  u16* WeT   = (u16*)(ws + alloc((size_t)384 * 192 * 2));
  u16* WqkvT = (u16*)(ws + alloc((size_t)1152 * 384 * 2));
  u16* WoT   = (u16*)(ws + alloc((size_t)384 * 384 * 2));
  u16* WcT   = (u16*)(ws + alloc((size_t)256 * 384 * 2));   // rows padded 192->256
  u16* W1T   = (u16*)(ws + alloc((size_t)768 * 384 * 2));
  u16* W2T   = (u16*)(ws + alloc((size_t)384 * 768 * 2));
  (void)ws_size; (void)in_sizes; (void)out_size;

  detect_all_kernel<<<1, 256, 0, stream>>>((const u32*)d_in[0], (const u32*)mask, flag);

  {
    PrepArgs pa;
    const int csrci[11] = {0, 3, 4, 5, 7, 9, 11, 12, 13, 15, 17};
    u16* cdsts[11] = {tokc, be, g1, bt1, bqkv, bo, bc, g2, bt2, b1, b2};
    const int cns[11] = {cM * cD, cE, cE, cE, c3E, cE, cD, cE, cE, 2 * cE, cE};
    for (int i = 0; i < 11; ++i) { pa.csrc[i] = d_in[csrci[i]]; pa.cdst[i] = cdsts[i]; pa.cn[i] = cns[i]; }
    const int tsrci[6] = {2, 6, 8, 10, 14, 16};
    u16* tdsts[6] = {WeT, WqkvT, WoT, WcT, W1T, W2T};
    const int tKs[6] = {192, 384, 384, 384, 384, 768};
    const int tNs[6] = {384, 1152, 384, 192, 768, 384};
    for (int i = 0; i < 6; ++i) { pa.tsrc[i] = d_in[tsrci[i]]; pa.tdst[i] = tdsts[i]; pa.tK[i] = tKs[i]; pa.tN[i] = tNs[i]; }
    pa.mask = mask; pa.bm = bmask;
    prep_kernel<<<dim3(96, 18), 256, 0, stream>>>(pa, flag);
  }

  knn_kernel<<<cM / 4, 256, 0, stream>>>(bmask, knn);

  const int GB = cM / 32;  // 256 blocks
  fused_ln_qkv<<<GB, 512, 0, stream>>>(tokc, WeT, be, g1, bt1, WqkvT, bqkv, QB);
  attn_kernel<<<cM / 4, 256, 0, stream>>>(QB, knn, S2);
  fused_mid<<<GB, 512, 0, stream>>>(S2, WoT, bo, mask, flag, WcT, bc, tokc, XM,
                                    WeT, be, g2, bt2, S1);
  fused_ffn<<<GB, 512, 0, stream>>>(S1, W1T, b1, W2T, b2, WcT, bc, XM, d_out, flag);
}

// Round 12
// 154.979 us; speedup vs baseline: 1.2815x; 1.1546x over previous
//
#include <hip/hip_runtime.h>
#include <stdint.h>

// ============================================================================
// DSVABlockLarge — round 12: wave-private barrier-free K-loops (round-10
// design, staging bug fixed: 2x4 stages ALL 48 local rows, not 24).
//  * Each wave stages its own 48x64 B panel (6 gload16/step, swizzled src)
//    into a private [2][48x64] LDS dbuf; counted VMW(6); NO K-loop barriers.
//  * N=192 stages: 2(M)x4(N) layout, wr-pairs stage duplicate panels.
//  * Stage-boundary __syncthreads around shared intermediates (X1/Tb/X2/Hb)
//    kept from round 11. Epilogues/detect/prep/knn/attn unchanged.
// ============================================================================

using u16 = unsigned short;
using u32 = unsigned int;
using u64 = unsigned long long;

typedef short short8 __attribute__((ext_vector_type(8)));
typedef float f32x4 __attribute__((ext_vector_type(4)));

#define DEV static __device__ __forceinline__

constexpr int cV = 4096, cD = 192;
constexpr int cE = 384;
constexpr int cKN = 16, cTK = 8;
constexpr int cM = 2 * cV;   // 8192 rows (B*V)
constexpr int c3E = 1152;

DEV float bf2f(u16 v) { return __uint_as_float(((u32)v) << 16); }
DEV float bflo(u32 v) { return __uint_as_float(v << 16); }
DEV float bfhi(u32 v) { return __uint_as_float(v & 0xFFFF0000u); }
DEV u16 f2bf(float f) {
  u32 u = __float_as_uint(f);
  u = (u + 0x7FFFu + ((u >> 16) & 1u)) >> 16;
  return (u16)u;
}
DEV int mget(const void* mp, int flag, int i) {
  if (flag == 0) return ((const int*)mp)[i] != 0;
  if (flag == 1) return ((const float*)mp)[i] != 0.0f;
  if (flag == 2) return ((const u16*)mp)[i] != 0;
  return ((const unsigned char*)mp)[i] != 0;
}
DEV float gelu_tanh(float x) {
  float t = tanhf(0.7978845608028654f * (x + 0.044715f * x * x * x));
  return 0.5f * x * (1.0f + t);
}
DEV u32 f2ord(float f) {
  u32 u = __float_as_uint(f);
  return (u & 0x80000000u) ? ~u : (u | 0x80000000u);
}
DEV float ord2f(u32 o) {
  u32 bits = (o & 0x80000000u) ? (o & 0x7FFFFFFFu) : ~o;
  return __uint_as_float(bits);
}
DEV int bf_plausible(u32 h) {
  if (h == 0u || h == 0x8000u) return 1;
  u32 e = (h >> 7) & 0xFFu;
  return (e >= 100u && e <= 140u) ? 1 : 0;
}

using as1p = const unsigned int __attribute__((address_space(1)))*;
using as3p = unsigned int __attribute__((address_space(3)))*;
DEV void gload16(const void* g, void* l) {
  __builtin_amdgcn_global_load_lds((as1p)g, (as3p)l, 16, 0, 0);
}
DEV f32x4 mfma16x16x32_bf16(short8 a, short8 b, f32x4 c) {
  asm volatile("v_mfma_f32_16x16x32_bf16 %0, %1, %2, %0" : "+v"(c) : "v"(a), "v"(b));
  return c;
}
DEV int swz(int row, int byteoff) { return byteoff ^ ((row & 7) << 4); }
DEV int ldswz(int r, int c) { return r * 64 + (c ^ ((r & 7) * 8)); }

#define SBPIN() __builtin_amdgcn_sched_barrier(0)
#define VMW(N) do { \
  __builtin_amdgcn_sched_barrier(0); \
  asm volatile("s_waitcnt vmcnt(" #N ")" ::: "memory"); \
  __builtin_amdgcn_sched_barrier(0); \
} while (0)

// Wave-private barrier-free K-loop, 1(M:32 rows)x8(N:48 cols/wave).
// bpriv: this wave's [2][48*64] u16 dbuf. 6 loads/step.
template <int T, typename AF>
DEV void stage_1x8(const u16* __restrict__ wbase, int Kst, u16* bpriv,
                   int l15, int l4, int sr, int scs,
                   f32x4 (&acc)[2][3], AF&& aread) {
  #pragma unroll
  for (int i = 0; i < 6; ++i)
    gload16(wbase + (size_t)(i * 8 + sr) * Kst + scs, (char*)bpriv + i * 1024);
  SBPIN();
  #pragma unroll
  for (int t = 0; t < T; ++t) {
    if (t + 1 < T) {
      #pragma unroll
      for (int i = 0; i < 6; ++i)
        gload16(wbase + (size_t)(i * 8 + sr) * Kst + (t + 1) * 64 + scs,
                (char*)bpriv + ((t + 1) & 1) * 6144 + i * 1024);
      VMW(6);
    } else {
      VMW(0);
    }
    const u16* bb = bpriv + (t & 1) * 3072;
    #pragma unroll
    for (int ks = 0; ks < 2; ++ks) {
      short8 a0 = aread(0, t, ks);
      short8 a1 = aread(1, t, ks);
      #pragma unroll
      for (int n = 0; n < 3; ++n) {
        short8 b = *(const short8*)&bb[ldswz(n * 16 + l15, ks * 32 + l4 * 8)];
        acc[0][n] = mfma16x16x32_bf16(a0, b, acc[0][n]);
        acc[1][n] = mfma16x16x32_bf16(a1, b, acc[1][n]);
      }
    }
    SBPIN();
  }
}

// Wave-private barrier-free, 2(M)x4(N): wave owns cols wc*48..+48 (rows via
// wr). Stages ALL 48 local rows (6 groups) — the round-10 fix. 6 loads/step.
template <int T, typename AF>
DEV void stage_2x4(const u16* __restrict__ wbase, int Kst, u16* bpriv,
                   int l15, int l4, int sr, int scs,
                   f32x4 (&acc)[3], AF&& aread) {
  #pragma unroll
  for (int i = 0; i < 6; ++i)
    gload16(wbase + (size_t)(i * 8 + sr) * Kst + scs, (char*)bpriv + i * 1024);
  SBPIN();
  #pragma unroll
  for (int t = 0; t < T; ++t) {
    if (t + 1 < T) {
      #pragma unroll
      for (int i = 0; i < 6; ++i)
        gload16(wbase + (size_t)(i * 8 + sr) * Kst + (t + 1) * 64 + scs,
                (char*)bpriv + ((t + 1) & 1) * 6144 + i * 1024);
      VMW(6);
    } else {
      VMW(0);
    }
    const u16* bb = bpriv + (t & 1) * 3072;
    #pragma unroll
    for (int ks = 0; ks < 2; ++ks) {
      short8 a = aread(t, ks);
      #pragma unroll
      for (int n = 0; n < 3; ++n) {
        short8 b = *(const short8*)&bb[ldswz(n * 16 + l15, ks * 32 + l4 * 8)];
        acc[n] = mfma16x16x32_bf16(a, b, acc[n]);
      }
    }
    SBPIN();
  }
}

// ---------------------------------------------------------------------------
__global__ void detect_all_kernel(const u32* __restrict__ tok,
                                  const u32* __restrict__ m,
                                  int* __restrict__ flag) {
  __shared__ int cnt, sa, sb, sc;
  if (threadIdx.x == 0) { cnt = 0; sa = 0; sb = 0; sc = 0; }
  __syncthreads();
  int c = 0;
  for (int i = threadIdx.x; i < 4096; i += 256) {
    u32 d = tok[i];
    c += bf_plausible(d & 0xFFFFu) & bf_plausible(d >> 16);
  }
  atomicAdd(&cnt, c);
  int a = 0, b = 0, cc = 0;
  for (int i = threadIdx.x; i < 2048; i += 256) {
    u32 d = m[i];
    if (!(d == 0u || d == 1u)) a = 1;
    if (!(d == 0u || d == 0x3F800000u)) b = 1;
    if (!(d == 0u || d == 0x00003F80u || d == 0x3F800000u || d == 0x3F803F80u)) cc = 1;
  }
  if (a) atomicOr(&sa, 1);
  if (b) atomicOr(&sb, 1);
  if (cc) atomicOr(&sc, 1);
  __syncthreads();
  if (threadIdx.x == 0) {
    flag[1] = (cnt > 3400) ? 1 : 0;
    flag[0] = (sa == 0) ? 0 : ((sb == 0) ? 1 : ((sc == 0) ? 2 : 3));
  }
}

// ---------------------------------------------------------------------------
struct PrepArgs {
  const void* csrc[11]; u16* cdst[11]; int cn[11];
  const void* tsrc[6]; u16* tdst[6]; int tK[6]; int tN[6];
  const void* mask; u64* bm;
};
__global__ __launch_bounds__(256) void prep_kernel(PrepArgs a, const int* __restrict__ flag) {
  const int job = blockIdx.y;
  const int dt = flag[1];
  if (job < 11) {
    const int n = a.cn[job];
    u16* d = a.cdst[job];
    if (dt) {
      const u16* s = (const u16*)a.csrc[job];
      for (int i = blockIdx.x * 256 + threadIdx.x; i < n; i += gridDim.x * 256) d[i] = s[i];
    } else {
      const float* s = (const float*)a.csrc[job];
      for (int i = blockIdx.x * 256 + threadIdx.x; i < n; i += gridDim.x * 256) d[i] = f2bf(s[i]);
    }
  } else if (job < 17) {
    const int t = job - 11;
    const int K = a.tK[t], N = a.tN[t];
    const int total = K * N;
    u16* d = a.tdst[t];
    for (int i = blockIdx.x * 256 + threadIdx.x; i < total; i += gridDim.x * 256) {
      int n = i / K, k = i - n * K;
      u16 vv;
      if (dt) vv = ((const u16*)a.tsrc[t])[(size_t)k * N + n];
      else vv = f2bf(((const float*)a.tsrc[t])[(size_t)k * N + n]);
      d[i] = vv;
    }
  } else {
    const int gw = (blockIdx.x * 256 + threadIdx.x) >> 6;
    const int lane = threadIdx.x & 63;
    if (gw < 128) {
      const int fl = flag[0];
      u64 bal = __ballot(mget(a.mask, fl, gw * 64 + lane) != 0);
      if (lane == 0) a.bm[gw] = bal;
    }
  }
}

// ---------------------------------------------------------------------------
// KNN v2 (unchanged).
__global__ __launch_bounds__(256) void knn_kernel(const u64* __restrict__ bitmask,
                                                  int* __restrict__ knn_out) {
  const int tid = threadIdx.x;
  const int wid = tid >> 6, lane = tid & 63;
  const int q0 = blockIdx.x * 4;
  const int b = q0 >> 12;
  const int q = q0 + wid;
  const int v = q & 4095;
  __shared__ u64 smask[64];
  __shared__ int hist4[4][64];
  __shared__ int listT[4][64];
  __shared__ int out16s[4][16];
  __shared__ int meta[4][3];
  __shared__ int cntA[4], cntT[4];
  if (tid < 64) smask[tid] = bitmask[b * 64 + tid];
  for (int i = tid; i < 4 * 64; i += 256) ((int*)hist4)[i] = 0;
  if (lane == 0) { cntA[wid] = 0; cntT[wid] = 0; }
  __syncthreads();
  const int iv = v >> 8, jv = (v >> 4) & 15, kv = v & 15;
  #pragma unroll
  for (int t = 0; t < 12; ++t) {
    int o = t * 64 + lane;
    if (o < 729) {
      int oi = o / 81, rm = o - oi * 81;
      int oj = rm / 9, ok = rm - oj * 9;
      int i = iv + oi - 4, j = jv + oj - 4, k = kv + ok - 4;
      if (((i | j | k) & ~15) == 0) {
        int u = (i << 8) | (j << 4) | k;
        if ((smask[u >> 6] >> (u & 63)) & 1ull) {
          int di = oi - 4, dj = oj - 4, dk = ok - 4;
          atomicAdd(&hist4[wid][di * di + dj * dj + dk * dk], 1);
        }
      }
    }
  }
  __syncthreads();
  if (lane == 0) {
    int cum = 0, T = -1, below = 0;
    for (int d = 0; d <= 48; ++d) {
      int h = hist4[wid][d];
      if (h > 0 && cum + h >= cKN) { T = d; below = cum; break; }
      cum += h;
    }
    if (T > 24) T = -1;
    meta[wid][0] = T; meta[wid][1] = below; meta[wid][2] = (T < 0) ? 1 : 0;
  }
  __syncthreads();
  const int T = meta[wid][0], below = meta[wid][1], fb = meta[wid][2];
  #pragma unroll
  for (int t = 0; t < 12; ++t) {
    int o = t * 64 + lane;
    if (o < 729) {
      int oi = o / 81, rm = o - oi * 81;
      int oj = rm / 9, ok = rm - oj * 9;
      int i = iv + oi - 4, j = jv + oj - 4, k = kv + ok - 4;
      if (((i | j | k) & ~15) == 0) {
        int u = (i << 8) | (j << 4) | k;
        if ((smask[u >> 6] >> (u & 63)) & 1ull) {
          int di = oi - 4, dj = oj - 4, dk = ok - 4;
          int d2 = di * di + dj * dj + dk * dk;
          if (d2 < T) { int p = atomicAdd(&cntA[wid], 1); out16s[wid][p] = u; }
          else if (d2 == T) { int p = atomicAdd(&cntT[wid], 1); if (p < 64) listT[wid][p] = u; }
        }
      }
    }
  }
  __syncthreads();
  if (!fb) {
    if (lane == 0) {
      int need = cKN - below;
      int nT = cntT[wid] < 64 ? cntT[wid] : 64;
      for (int r = 0; r < need; ++r) {
        int bi = 0, bu = 0x7FFFFFFF;
        for (int i2 = 0; i2 < nT; ++i2) { int x = listT[wid][i2]; if (x < bu) { bu = x; bi = i2; } }
        out16s[wid][below + r] = bu;
        listT[wid][bi] = 0x7FFFFFFF;
      }
    }
  } else {
    u64 rem = smask[lane];
    const int myi = lane >> 2;
    const int di2 = (iv - myi) * (iv - myi);
    for (int r = 0; r < cKN; ++r) {
      u64 tmp = rem;
      u32 best = 0xFFFFFFFFu;
      while (tmp) {
        int bp = __builtin_ctzll(tmp);
        tmp &= tmp - 1;
        int u = (lane << 6) | bp;
        int dj = jv - ((u >> 4) & 15), dk = kv - (u & 15);
        u32 key = (u32)(((di2 + dj * dj + dk * dk) << 12) | u);
        if (key < best) best = key;
      }
      u32 pk = (best == 0xFFFFFFFFu) ? 0xFFFFFFFFu : ((best << 6) | (u32)lane);
      #pragma unroll
      for (int off = 1; off < 64; off <<= 1) {
        u32 o2 = __shfl_xor(pk, off);
        if (o2 < pk) pk = o2;
      }
      int u = (int)((pk >> 6) & 4095u);
      int wl = (int)(pk & 63u);
      if (lane == wl) rem &= ~(1ull << (u & 63));
      if (lane == 0) out16s[wid][r] = u;
    }
  }
  __syncthreads();
  if (lane < cKN) knn_out[q * cKN + lane] = out16s[wid][lane];
}

// ---------------------------------------------------------------------------
// F_A: X1 = LN(tok@We+be; g1,bt1) ; QB = X1@Wqkv + bqkv.
__global__ __launch_bounds__(512) void fused_ln_qkv(
    const u16* __restrict__ tokc, const u16* __restrict__ WeT,
    const u16* __restrict__ be, const u16* __restrict__ g1, const u16* __restrict__ bt1,
    const u16* __restrict__ WqkvT, const u16* __restrict__ bqkv,
    u16* __restrict__ QB) {
  __shared__ alignas(16) u16 Afull[3 * 2048];   // 12KB tok (swz)
  __shared__ alignas(16) u16 Bst[8][2][3072];   // 96KB wave-private dbuf
  __shared__ alignas(16) char X1[32 * 768];     // 24KB swz
  __shared__ float st[32][8][2];
  const int tid = threadIdx.x;
  const int lane = tid & 63, wn = tid >> 6;
  const int l15 = lane & 15, l4 = lane >> 4;
  const int sr = lane >> 3;
  const int scs = (((lane & 7) ^ sr) << 3);
  const int row0 = blockIdx.x * 32;
  u16* bpriv = &Bst[wn][0][0];

  for (int g = wn; g < 12; g += 8)
    gload16(tokc + (size_t)(row0 + (g & 3) * 8 + sr) * 192 + (g >> 2) * 64 + scs,
            (char*)Afull + g * 1024);
  SBPIN();
  __syncthreads();

  // stage 1: tok @ WeT^T (K=192, T=3), barrier-free
  f32x4 acc[2][3];
  #pragma unroll
  for (int m = 0; m < 2; ++m)
    #pragma unroll
    for (int n = 0; n < 3; ++n) acc[m][n] = f32x4{0.f, 0.f, 0.f, 0.f};
  stage_1x8<3>(WeT + (size_t)(wn * 48) * 192, 192, bpriv, l15, l4, sr, scs, acc,
               [&](int m, int t, int ks) {
                 return *(const short8*)&Afull[t * 2048 + ldswz(m * 16 + l15, ks * 32 + l4 * 8)];
               });
  // LN epilogue
  float s[2][4], sq[2][4];
  #pragma unroll
  for (int m = 0; m < 2; ++m)
    #pragma unroll
    for (int j = 0; j < 4; ++j) { s[m][j] = 0.f; sq[m][j] = 0.f; }
  #pragma unroll
  for (int n = 0; n < 3; ++n) {
    const float bi = bf2f(be[wn * 48 + n * 16 + l15]);
    #pragma unroll
    for (int m = 0; m < 2; ++m)
      #pragma unroll
      for (int j = 0; j < 4; ++j) {
        acc[m][n][j] += bi;
        s[m][j] += acc[m][n][j]; sq[m][j] += acc[m][n][j] * acc[m][n][j];
      }
  }
  #pragma unroll
  for (int off = 1; off < 16; off <<= 1)
    #pragma unroll
    for (int m = 0; m < 2; ++m)
      #pragma unroll
      for (int j = 0; j < 4; ++j) { s[m][j] += __shfl_xor(s[m][j], off); sq[m][j] += __shfl_xor(sq[m][j], off); }
  if (l15 == 0) {
    #pragma unroll
    for (int m = 0; m < 2; ++m)
      #pragma unroll
      for (int j = 0; j < 4; ++j) {
        const int rl = m * 16 + l4 * 4 + j;
        st[rl][wn][0] = s[m][j]; st[rl][wn][1] = sq[m][j];
      }
  }
  __syncthreads();
  #pragma unroll
  for (int m = 0; m < 2; ++m)
    #pragma unroll
    for (int j = 0; j < 4; ++j) {
      const int rl = m * 16 + l4 * 4 + j;
      float ts = 0.f, tq = 0.f;
      #pragma unroll
      for (int wv = 0; wv < 8; ++wv) { ts += st[rl][wv][0]; tq += st[rl][wv][1]; }
      const float mean = ts * (1.0f / 384.0f);
      const float var = tq * (1.0f / 384.0f) - mean * mean;
      const float rstd = rsqrtf(var + 1e-5f);
      #pragma unroll
      for (int n = 0; n < 3; ++n) {
        const int col = wn * 48 + n * 16 + l15;
        const float v = (acc[m][n][j] - mean) * rstd * bf2f(g1[col]) + bf2f(bt1[col]);
        *(u16*)(X1 + swz(rl, rl * 768 + col * 2)) = f2bf(v);
      }
    }
  __syncthreads();

  // stage 2: QB = X1 @ WqkvT^T + bqkv (3 chunks, K=384, T=6), barrier-free
  for (int chunk = 0; chunk < 3; ++chunk) {
    f32x4 a2[2][3];
    #pragma unroll
    for (int m = 0; m < 2; ++m)
      #pragma unroll
      for (int n = 0; n < 3; ++n) a2[m][n] = f32x4{0.f, 0.f, 0.f, 0.f};
    stage_1x8<6>(WqkvT + (size_t)(chunk * 384 + wn * 48) * 384, 384, bpriv,
                 l15, l4, sr, scs, a2,
                 [&](int m, int t, int ks) {
                   const int rl = m * 16 + l15;
                   return *(const short8*)(X1 + swz(rl, rl * 768 + (t * 64 + ks * 32 + l4 * 8) * 2));
                 });
    #pragma unroll
    for (int n = 0; n < 3; ++n) {
      const int col = chunk * 384 + wn * 48 + n * 16 + l15;
      const float bi = bf2f(bqkv[col]);
      #pragma unroll
      for (int m = 0; m < 2; ++m)
        #pragma unroll
        for (int j = 0; j < 4; ++j)
          QB[(size_t)(row0 + m * 16 + l4 * 4 + j) * c3E + col] = f2bf(a2[m][n][j] + bi);
    }
  }
}

// ---------------------------------------------------------------------------
// F_C: T=(S2@Wo+bo)*mask ; XM=(T@Wc+bc)*0.5+tok (f32) ; S1=LN(XM@We+be)
__global__ __launch_bounds__(512) void fused_mid(
    const u16* __restrict__ S2, const u16* __restrict__ WoT, const u16* __restrict__ bo,
    const void* __restrict__ mask, const int* __restrict__ flag,
    const u16* __restrict__ WcT, const u16* __restrict__ bc, const u16* __restrict__ tokc,
    float* __restrict__ XM,
    const u16* __restrict__ WeT, const u16* __restrict__ be,
    const u16* __restrict__ g2, const u16* __restrict__ bt2, u16* __restrict__ S1out) {
  __shared__ alignas(16) u16 Afull[6 * 2048];   // 24KB S2
  __shared__ alignas(16) u16 Bst[8][2][3072];   // 96KB wave-private dbuf
  __shared__ alignas(16) char Tb[32 * 768];     // 24KB T swz; X2 overlays
  __shared__ float st[32][8][2];
  char* X2 = Tb;
  const int tid = threadIdx.x;
  const int lane = tid & 63, wn = tid >> 6;
  const int wr = wn >> 2, wc = wn & 3;
  const int l15 = lane & 15, l4 = lane >> 4;
  const int sr = lane >> 3;
  const int scs = (((lane & 7) ^ sr) << 3);
  const int row0 = blockIdx.x * 32;
  const int fl = flag[0];
  u16* bpriv = &Bst[wn][0][0];

  for (int g = wn; g < 24; g += 8)
    gload16(S2 + (size_t)(row0 + (g & 3) * 8 + sr) * cE + (g >> 2) * 64 + scs,
            (char*)Afull + g * 1024);
  SBPIN();
  __syncthreads();

  // stage 1: T = (S2 @ WoT^T + bo) * fmask (K=384, T=6, 1x8)
  {
    f32x4 acc[2][3];
    #pragma unroll
    for (int m = 0; m < 2; ++m)
      #pragma unroll
      for (int n = 0; n < 3; ++n) acc[m][n] = f32x4{0.f, 0.f, 0.f, 0.f};
    stage_1x8<6>(WoT + (size_t)(wn * 48) * 384, 384, bpriv, l15, l4, sr, scs, acc,
                 [&](int m, int t, int ks) {
                   return *(const short8*)&Afull[t * 2048 + ldswz(m * 16 + l15, ks * 32 + l4 * 8)];
                 });
    #pragma unroll
    for (int m = 0; m < 2; ++m)
      #pragma unroll
      for (int j = 0; j < 4; ++j) {
        const int rl = m * 16 + l4 * 4 + j;
        const float fm = mget(mask, fl, row0 + rl) ? 1.0f : 0.0f;
        #pragma unroll
        for (int n = 0; n < 3; ++n) {
          const int col = wn * 48 + n * 16 + l15;
          const float v = (acc[m][n][j] + bf2f(bo[col])) * fm;
          *(u16*)(Tb + swz(rl, rl * 768 + col * 2)) = f2bf(v);
        }
      }
  }
  __syncthreads();

  // stage 2: XM = (T @ WcT^T + bc)*0.5 + tok (K=384, T=6, N=192, 2x4, full 48-row panels)
  f32x4 a2[3];
  #pragma unroll
  for (int n = 0; n < 3; ++n) a2[n] = f32x4{0.f, 0.f, 0.f, 0.f};
  stage_2x4<6>(WcT + (size_t)(wc * 48) * 384, 384, bpriv, l15, l4, sr, scs, a2,
               [&](int t, int ks) {
                 const int rl = wr * 16 + l15;
                 return *(const short8*)(Tb + swz(rl, rl * 768 + (t * 64 + ks * 32 + l4 * 8) * 2));
               });
  __syncthreads();   // all reads of Tb done before X2 overlay
  #pragma unroll
  for (int n = 0; n < 3; ++n) {
    const int col = wc * 48 + n * 16 + l15;
    const float bi = bf2f(bc[col]);
    #pragma unroll
    for (int j = 0; j < 4; ++j) {
      const int rl = wr * 16 + l4 * 4 + j;
      const size_t oi = (size_t)(row0 + rl) * cD + col;
      const float r = (a2[n][j] + bi) * 0.5f + bf2f(tokc[oi]);
      XM[oi] = r;
      *(u16*)(X2 + swz(rl, rl * 384 + col * 2)) = f2bf(r);
    }
  }
  __syncthreads();

  // stage 3: S1 = LN(X2 @ WeT^T + be; g2, bt2) (K=192, T=3, 1x8)
  {
    f32x4 a3[2][3];
    #pragma unroll
    for (int m = 0; m < 2; ++m)
      #pragma unroll
      for (int n = 0; n < 3; ++n) a3[m][n] = f32x4{0.f, 0.f, 0.f, 0.f};
    stage_1x8<3>(WeT + (size_t)(wn * 48) * 192, 192, bpriv, l15, l4, sr, scs, a3,
                 [&](int m, int t, int ks) {
                   const int rl = m * 16 + l15;
                   return *(const short8*)(X2 + swz(rl, rl * 384 + (t * 64 + ks * 32 + l4 * 8) * 2));
                 });
    float s[2][4], sq[2][4];
    #pragma unroll
    for (int m = 0; m < 2; ++m)
      #pragma unroll
      for (int j = 0; j < 4; ++j) { s[m][j] = 0.f; sq[m][j] = 0.f; }
    #pragma unroll
    for (int n = 0; n < 3; ++n) {
      const float bi = bf2f(be[wn * 48 + n * 16 + l15]);
      #pragma unroll
      for (int m = 0; m < 2; ++m)
        #pragma unroll
        for (int j = 0; j < 4; ++j) {
          a3[m][n][j] += bi;
          s[m][j] += a3[m][n][j]; sq[m][j] += a3[m][n][j] * a3[m][n][j];
        }
    }
    #pragma unroll
    for (int off = 1; off < 16; off <<= 1)
      #pragma unroll
      for (int m = 0; m < 2; ++m)
        #pragma unroll
        for (int j = 0; j < 4; ++j) { s[m][j] += __shfl_xor(s[m][j], off); sq[m][j] += __shfl_xor(sq[m][j], off); }
    if (l15 == 0) {
      #pragma unroll
      for (int m = 0; m < 2; ++m)
        #pragma unroll
        for (int j = 0; j < 4; ++j) {
          const int rl = m * 16 + l4 * 4 + j;
          st[rl][wn][0] = s[m][j]; st[rl][wn][1] = sq[m][j];
        }
    }
    __syncthreads();
    #pragma unroll
    for (int m = 0; m < 2; ++m)
      #pragma unroll
      for (int j = 0; j < 4; ++j) {
        const int rl = m * 16 + l4 * 4 + j;
        float ts = 0.f, tq = 0.f;
        #pragma unroll
        for (int wv = 0; wv < 8; ++wv) { ts += st[rl][wv][0]; tq += st[rl][wv][1]; }
        const float mean = ts * (1.0f / 384.0f);
        const float var = tq * (1.0f / 384.0f) - mean * mean;
        const float rstd = rsqrtf(var + 1e-5f);
        #pragma unroll
        for (int n = 0; n < 3; ++n) {
          const int col = wn * 48 + n * 16 + l15;
          S1out[(size_t)(row0 + rl) * cE + col] =
              f2bf((a3[m][n][j] - mean) * rstd * bf2f(g2[col]) + bf2f(bt2[col]));
        }
      }
  }
}

// ---------------------------------------------------------------------------
// F_D: H=gelu(S1@W1+b1) per K-half ; F=H@W2+b2 (reg acc) ; out=(F@Wc+bc)/2+XM
__global__ __launch_bounds__(512) void fused_ffn(
    const u16* __restrict__ S1, const u16* __restrict__ W1T, const u16* __restrict__ b1,
    const u16* __restrict__ W2T, const u16* __restrict__ b2,
    const u16* __restrict__ WcT, const u16* __restrict__ bc,
    const float* __restrict__ XM, void* __restrict__ outv, const int* __restrict__ flag) {
  __shared__ alignas(16) u16 Afull[6 * 2048];   // 24KB S1
  __shared__ alignas(16) u16 Bst[8][2][3072];   // 96KB wave-private dbuf
  __shared__ alignas(16) char Hb[32 * 768];     // 24KB H-half swz; F overlays
  const int tid = threadIdx.x;
  const int lane = tid & 63, wn = tid >> 6;
  const int wr = wn >> 2, wc = wn & 3;
  const int l15 = lane & 15, l4 = lane >> 4;
  const int sr = lane >> 3;
  const int scs = (((lane & 7) ^ sr) << 3);
  const int row0 = blockIdx.x * 32;
  u16* bpriv = &Bst[wn][0][0];

  for (int g = wn; g < 24; g += 8)
    gload16(S1 + (size_t)(row0 + (g & 3) * 8 + sr) * cE + (g >> 2) * 64 + scs,
            (char*)Afull + g * 1024);
  SBPIN();
  __syncthreads();

  f32x4 accF[2][3];
  #pragma unroll
  for (int m = 0; m < 2; ++m)
    #pragma unroll
    for (int n = 0; n < 3; ++n) accF[m][n] = f32x4{0.f, 0.f, 0.f, 0.f};

  for (int half = 0; half < 2; ++half) {
    // s1: H = gelu(S1 @ W1T[half]^T + b1[half]) (K=384, T=6, 1x8)
    {
      f32x4 a1[2][3];
      #pragma unroll
      for (int m = 0; m < 2; ++m)
        #pragma unroll
        for (int n = 0; n < 3; ++n) a1[m][n] = f32x4{0.f, 0.f, 0.f, 0.f};
      stage_1x8<6>(W1T + (size_t)(half * 384 + wn * 48) * 384, 384, bpriv,
                   l15, l4, sr, scs, a1,
                   [&](int m, int t, int ks) {
                     return *(const short8*)&Afull[t * 2048 + ldswz(m * 16 + l15, ks * 32 + l4 * 8)];
                   });
      #pragma unroll
      for (int n = 0; n < 3; ++n) {
        const int col = wn * 48 + n * 16 + l15;
        const float bi = bf2f(b1[half * 384 + col]);
        #pragma unroll
        for (int m = 0; m < 2; ++m)
          #pragma unroll
          for (int j = 0; j < 4; ++j) {
            const int rl = m * 16 + l4 * 4 + j;
            *(u16*)(Hb + swz(rl, rl * 768 + col * 2)) = f2bf(gelu_tanh(a1[m][n][j] + bi));
          }
      }
    }
    __syncthreads();
    // s2: accF += H @ W2T[:, half]^T (K=384, T=6, 1x8)
    stage_1x8<6>(W2T + (size_t)(wn * 48) * 768 + half * 384, 768, bpriv,
                 l15, l4, sr, scs, accF,
                 [&](int m, int t, int ks) {
                   const int rl = m * 16 + l15;
                   return *(const short8*)(Hb + swz(rl, rl * 768 + (t * 64 + ks * 32 + l4 * 8) * 2));
                 });
    __syncthreads();   // retire Hb readers before next half overwrites
  }
  // F = accF + b2 -> Hb
  #pragma unroll
  for (int n = 0; n < 3; ++n) {
    const int col = wn * 48 + n * 16 + l15;
    const float bi = bf2f(b2[col]);
    #pragma unroll
    for (int m = 0; m < 2; ++m)
      #pragma unroll
      for (int j = 0; j < 4; ++j) {
        const int rl = m * 16 + l4 * 4 + j;
        *(u16*)(Hb + swz(rl, rl * 768 + col * 2)) = f2bf(accF[m][n][j] + bi);
      }
  }
  __syncthreads();
  // s3: out = (F @ WcT^T + bc)*0.5 + XM (K=384, T=6, N=192, 2x4 full panels)
  f32x4 a3[3];
  #pragma unroll
  for (int n = 0; n < 3; ++n) a3[n] = f32x4{0.f, 0.f, 0.f, 0.f};
  stage_2x4<6>(WcT + (size_t)(wc * 48) * 384, 384, bpriv, l15, l4, sr, scs, a3,
               [&](int t, int ks) {
                 const int rl = wr * 16 + l15;
                 return *(const short8*)(Hb + swz(rl, rl * 768 + (t * 64 + ks * 32 + l4 * 8) * 2));
               });
  u16* o16 = (u16*)outv;
  float* o32 = (float*)outv;
  const int dtf = flag[1];
  #pragma unroll
  for (int n = 0; n < 3; ++n) {
    const int col = wc * 48 + n * 16 + l15;
    const float bi = bf2f(bc[col]);
    #pragma unroll
    for (int j = 0; j < 4; ++j) {
      const int rl = wr * 16 + l4 * 4 + j;
      const size_t oi = (size_t)(row0 + rl) * cD + col;
      const float r = (a3[n][j] + bi) * 0.5f + XM[oi];
      if (dtf) o16[oi] = f2bf(r);
      else o32[oi] = r;
    }
  }
}

// ---------------------------------------------------------------------------
// attn v3 (unchanged).
__global__ __launch_bounds__(256) void attn_kernel(const u16* __restrict__ qkv,
                                                   const int* __restrict__ knn,
                                                   u16* __restrict__ o_out) {
  const int wid = threadIdx.x >> 6;
  const int lane = threadIdx.x & 63;
  const int bq = blockIdx.x * 4 + wid;
  const int b = bq >> 12;
  __shared__ float w4[4][8][8];
  __shared__ int vid4[4][8][8];
  __shared__ int nb4[4][16];
  float (*w)[8] = w4[wid];
  int (*vid)[8] = vid4[wid];
  int* nb = nb4[wid];
  if (lane < 16) nb[lane] = knn[bq * cKN + lane];
  const int h = lane >> 3;
  const int j = lane & 7;
  const uint2* qp = (const uint2*)(qkv + (size_t)bq * c3E + h * 48);
  const int r0 = nb[j], r1 = nb[j + 8];
  const uint2* k0p = (const uint2*)(qkv + ((size_t)(b * cV + r0)) * c3E + cE + h * 48);
  const uint2* k1p = (const uint2*)(qkv + ((size_t)(b * cV + r1)) * c3E + cE + h * 48);
  float s0 = 0.f, s1 = 0.f;
  #pragma unroll
  for (int t = 0; t < 12; ++t) {
    uint2 qv = qp[t];
    uint2 k0 = k0p[t];
    uint2 k1 = k1p[t];
    s0 += bflo(qv.x) * bflo(k0.x) + bfhi(qv.x) * bfhi(k0.x)
        + bflo(qv.y) * bflo(k0.y) + bfhi(qv.y) * bfhi(k0.y);
    s1 += bflo(qv.x) * bflo(k1.x) + bfhi(qv.x) * bfhi(k1.x)
        + bflo(qv.y) * bflo(k1.y) + bfhi(qv.y) * bfhi(k1.y);
  }
  const float inv = 0.14433756729740643f;  // 1/sqrt(48)
  u64 key0 = (((u64)f2ord(s0 * inv)) << 4) | (u64)(15 - j);
  u64 key1 = (((u64)f2ord(s1 * inv)) << 4) | (u64)(15 - (j + 8));
  float m0 = 0.f, Z = 0.f, myw = 0.f;
  int myv = 0;
  #pragma unroll
  for (int r = 0; r < cTK; ++r) {
    u64 best = key0 > key1 ? key0 : key1;
    u64 o1 = __shfl_xor(best, 1); if (o1 > best) best = o1;
    u64 o2 = __shfl_xor(best, 2); if (o2 > best) best = o2;
    u64 o4 = __shfl_xor(best, 4); if (o4 > best) best = o4;
    if (key0 == best) key0 = 0;
    if (key1 == best) key1 = 0;
    float sv = ord2f((u32)(best >> 4));
    int nsel = 15 - (int)(best & 15ull);
    if (r == 0) m0 = sv;
    float e = expf(sv - m0);
    Z += e;
    if (j == r) { myw = e; myv = nsel; }
  }
  w[h][j] = myw / Z;
  vid[h][j] = nb[myv];
  const u16* vbase = qkv + (size_t)(b * cV) * c3E + 2 * cE;
  #pragma unroll
  for (int rep = 0; rep < 6; ++rep) {
    int e = rep * 64 + lane;
    int h2 = e / 48;
    float acc = 0.f;
    #pragma unroll
    for (int t = 0; t < cTK; ++t)
      acc += w[h2][t] * bf2f(vbase[(size_t)vid[h2][t] * c3E + e]);
    o_out[(size_t)bq * cE + e] = f2bf(acc);
  }
}

// ---------------------------------------------------------------------------
extern "C" void kernel_launch(void* const* d_in, const int* in_sizes, int n_in,
                              void* d_out, int out_size, void* d_ws, size_t ws_size,
                              hipStream_t stream) {
  if (n_in < 18) return;
  const void* mask = d_in[1];

  char* ws = (char*)d_ws;
  size_t off = 0;
  auto alloc = [&](size_t bytes) { size_t o = off; off += (bytes + 255) & ~(size_t)255; return o; };
  int* flag  = (int*)(ws + alloc(256));
  u64* bmask = (u64*)(ws + alloc(128 * 8));
  int* knn   = (int*)(ws + alloc((size_t)cM * cKN * 4));
  float* XM  = (float*)(ws + alloc((size_t)cM * cD * 4));
  u16* S1    = (u16*)(ws + alloc((size_t)cM * cE * 2));
  u16* S2    = (u16*)(ws + alloc((size_t)cM * cE * 2));
  u16* QB    = (u16*)(ws + alloc((size_t)cM * c3E * 2));
  u16* tokc  = (u16*)(ws + alloc((size_t)cM * cD * 2));
  u16* be    = (u16*)(ws + alloc(cE * 2));
  u16* g1    = (u16*)(ws + alloc(cE * 2));
  u16* bt1   = (u16*)(ws + alloc(cE * 2));
  u16* bqkv  = (u16*)(ws + alloc(c3E * 2));
  u16* bo    = (u16*)(ws + alloc(cE * 2));
  u16* bc    = (u16*)(ws + alloc(cD * 2));
  u16* g2    = (u16*)(ws + alloc(cE * 2));
  u16* bt2   = (u16*)(ws + alloc(cE * 2));
  u16* b1    = (u16*)(ws + alloc(2 * cE * 2));
  u16* b2    = (u16*)(ws + alloc(cE * 2));
  u16* WeT   = (u16*)(ws + alloc((size_t)384 * 192 * 2));
  u16* WqkvT = (u16*)(ws + alloc((size_t)1152 * 384 * 2));
  u16* WoT   = (u16*)(ws + alloc((size_t)384 * 384 * 2));
  u16* WcT   = (u16*)(ws + alloc((size_t)256 * 384 * 2));   // rows padded 192->256
  u16* W1T   = (u16*)(ws + alloc((size_t)768 * 384 * 2));
  u16* W2T   = (u16*)(ws + alloc((size_t)384 * 768 * 2));
  (void)ws_size; (void)in_sizes; (void)out_size;

  detect_all_kernel<<<1, 256, 0, stream>>>((const u32*)d_in[0], (const u32*)mask, flag);

  {
    PrepArgs pa;
    const int csrci[11] = {0, 3, 4, 5, 7, 9, 11, 12, 13, 15, 17};
    u16* cdsts[11] = {tokc, be, g1, bt1, bqkv, bo, bc, g2, bt2, b1, b2};
    const int cns[11] = {cM * cD, cE, cE, cE, c3E, cE, cD, cE, cE, 2 * cE, cE};
    for (int i = 0; i < 11; ++i) { pa.csrc[i] = d_in[csrci[i]]; pa.cdst[i] = cdsts[i]; pa.cn[i] = cns[i]; }
    const int tsrci[6] = {2, 6, 8, 10, 14, 16};
    u16* tdsts[6] = {WeT, WqkvT, WoT, WcT, W1T, W2T};
    const int tKs[6] = {192, 384, 384, 384, 384, 768};
    const int tNs[6] = {384, 1152, 384, 192, 768, 384};
    for (int i = 0; i < 6; ++i) { pa.tsrc[i] = d_in[tsrci[i]]; pa.tdst[i] = tdsts[i]; pa.tK[i] = tKs[i]; pa.tN[i] = tNs[i]; }
    pa.mask = mask; pa.bm = bmask;
    prep_kernel<<<dim3(96, 18), 256, 0, stream>>>(pa, flag);
  }

  knn_kernel<<<cM / 4, 256, 0, stream>>>(bmask, knn);

  const int GB = cM / 32;  // 256 blocks
  fused_ln_qkv<<<GB, 512, 0, stream>>>(tokc, WeT, be, g1, bt1, WqkvT, bqkv, QB);
  attn_kernel<<<cM / 4, 256, 0, stream>>>(QB, knn, S2);
  fused_mid<<<GB, 512, 0, stream>>>(S2, WoT, bo, mask, flag, WcT, bc, tokc, XM,
                                    WeT, be, g2, bt2, S1);
  fused_ffn<<<GB, 512, 0, stream>>>(S1, W1T, b1, W2T, b2, WcT, bc, XM, d_out, flag);
}

// Round 13
// 150.896 us; speedup vs baseline: 1.3161x; 1.0271x over previous
//
#include <hip/hip_runtime.h>
#include <stdint.h>

// ============================================================================
// DSVABlockLarge — round 13: merge F_C+F_D into one row-local kernel (F_CD).
//  * XM residual lives in registers (stage-2 and final s3 share the same
//    2x4 (wr,wc) ownership) — no XM global buffer at all.
//  * S1 stays in LDS (Tb: T -> X2 -> S1); Afull reused as H buffer.
//  * Wave-private barrier-free K-loops (round-12 stage_1x8/stage_2x4) kept.
//  * F_A / attn / knn / prep / detect byte-identical to round 12.
// ============================================================================

using u16 = unsigned short;
using u32 = unsigned int;
using u64 = unsigned long long;

typedef short short8 __attribute__((ext_vector_type(8)));
typedef float f32x4 __attribute__((ext_vector_type(4)));

#define DEV static __device__ __forceinline__

constexpr int cV = 4096, cD = 192;
constexpr int cE = 384;
constexpr int cKN = 16, cTK = 8;
constexpr int cM = 2 * cV;   // 8192 rows (B*V)
constexpr int c3E = 1152;

DEV float bf2f(u16 v) { return __uint_as_float(((u32)v) << 16); }
DEV float bflo(u32 v) { return __uint_as_float(v << 16); }
DEV float bfhi(u32 v) { return __uint_as_float(v & 0xFFFF0000u); }
DEV u16 f2bf(float f) {
  u32 u = __float_as_uint(f);
  u = (u + 0x7FFFu + ((u >> 16) & 1u)) >> 16;
  return (u16)u;
}
DEV int mget(const void* mp, int flag, int i) {
  if (flag == 0) return ((const int*)mp)[i] != 0;
  if (flag == 1) return ((const float*)mp)[i] != 0.0f;
  if (flag == 2) return ((const u16*)mp)[i] != 0;
  return ((const unsigned char*)mp)[i] != 0;
}
DEV float gelu_tanh(float x) {
  float t = tanhf(0.7978845608028654f * (x + 0.044715f * x * x * x));
  return 0.5f * x * (1.0f + t);
}
DEV u32 f2ord(float f) {
  u32 u = __float_as_uint(f);
  return (u & 0x80000000u) ? ~u : (u | 0x80000000u);
}
DEV float ord2f(u32 o) {
  u32 bits = (o & 0x80000000u) ? (o & 0x7FFFFFFFu) : ~o;
  return __uint_as_float(bits);
}
DEV int bf_plausible(u32 h) {
  if (h == 0u || h == 0x8000u) return 1;
  u32 e = (h >> 7) & 0xFFu;
  return (e >= 100u && e <= 140u) ? 1 : 0;
}

using as1p = const unsigned int __attribute__((address_space(1)))*;
using as3p = unsigned int __attribute__((address_space(3)))*;
DEV void gload16(const void* g, void* l) {
  __builtin_amdgcn_global_load_lds((as1p)g, (as3p)l, 16, 0, 0);
}
DEV f32x4 mfma16x16x32_bf16(short8 a, short8 b, f32x4 c) {
  asm volatile("v_mfma_f32_16x16x32_bf16 %0, %1, %2, %0" : "+v"(c) : "v"(a), "v"(b));
  return c;
}
DEV int swz(int row, int byteoff) { return byteoff ^ ((row & 7) << 4); }
DEV int ldswz(int r, int c) { return r * 64 + (c ^ ((r & 7) * 8)); }

#define SBPIN() __builtin_amdgcn_sched_barrier(0)
#define VMW(N) do { \
  __builtin_amdgcn_sched_barrier(0); \
  asm volatile("s_waitcnt vmcnt(" #N ")" ::: "memory"); \
  __builtin_amdgcn_sched_barrier(0); \
} while (0)

// Wave-private barrier-free K-loop, 1(M:32 rows)x8(N:48 cols/wave).
template <int T, typename AF>
DEV void stage_1x8(const u16* __restrict__ wbase, int Kst, u16* bpriv,
                   int l15, int l4, int sr, int scs,
                   f32x4 (&acc)[2][3], AF&& aread) {
  #pragma unroll
  for (int i = 0; i < 6; ++i)
    gload16(wbase + (size_t)(i * 8 + sr) * Kst + scs, (char*)bpriv + i * 1024);
  SBPIN();
  #pragma unroll
  for (int t = 0; t < T; ++t) {
    if (t + 1 < T) {
      #pragma unroll
      for (int i = 0; i < 6; ++i)
        gload16(wbase + (size_t)(i * 8 + sr) * Kst + (t + 1) * 64 + scs,
                (char*)bpriv + ((t + 1) & 1) * 6144 + i * 1024);
      VMW(6);
    } else {
      VMW(0);
    }
    const u16* bb = bpriv + (t & 1) * 3072;
    #pragma unroll
    for (int ks = 0; ks < 2; ++ks) {
      short8 a0 = aread(0, t, ks);
      short8 a1 = aread(1, t, ks);
      #pragma unroll
      for (int n = 0; n < 3; ++n) {
        short8 b = *(const short8*)&bb[ldswz(n * 16 + l15, ks * 32 + l4 * 8)];
        acc[0][n] = mfma16x16x32_bf16(a0, b, acc[0][n]);
        acc[1][n] = mfma16x16x32_bf16(a1, b, acc[1][n]);
      }
    }
    SBPIN();
  }
}

// Wave-private barrier-free, 2(M)x4(N); full 48-row panels per wave.
template <int T, typename AF>
DEV void stage_2x4(const u16* __restrict__ wbase, int Kst, u16* bpriv,
                   int l15, int l4, int sr, int scs,
                   f32x4 (&acc)[3], AF&& aread) {
  #pragma unroll
  for (int i = 0; i < 6; ++i)
    gload16(wbase + (size_t)(i * 8 + sr) * Kst + scs, (char*)bpriv + i * 1024);
  SBPIN();
  #pragma unroll
  for (int t = 0; t < T; ++t) {
    if (t + 1 < T) {
      #pragma unroll
      for (int i = 0; i < 6; ++i)
        gload16(wbase + (size_t)(i * 8 + sr) * Kst + (t + 1) * 64 + scs,
                (char*)bpriv + ((t + 1) & 1) * 6144 + i * 1024);
      VMW(6);
    } else {
      VMW(0);
    }
    const u16* bb = bpriv + (t & 1) * 3072;
    #pragma unroll
    for (int ks = 0; ks < 2; ++ks) {
      short8 a = aread(t, ks);
      #pragma unroll
      for (int n = 0; n < 3; ++n) {
        short8 b = *(const short8*)&bb[ldswz(n * 16 + l15, ks * 32 + l4 * 8)];
        acc[n] = mfma16x16x32_bf16(a, b, acc[n]);
      }
    }
    SBPIN();
  }
}

// ---------------------------------------------------------------------------
__global__ void detect_all_kernel(const u32* __restrict__ tok,
                                  const u32* __restrict__ m,
                                  int* __restrict__ flag) {
  __shared__ int cnt, sa, sb, sc;
  if (threadIdx.x == 0) { cnt = 0; sa = 0; sb = 0; sc = 0; }
  __syncthreads();
  int c = 0;
  for (int i = threadIdx.x; i < 4096; i += 256) {
    u32 d = tok[i];
    c += bf_plausible(d & 0xFFFFu) & bf_plausible(d >> 16);
  }
  atomicAdd(&cnt, c);
  int a = 0, b = 0, cc = 0;
  for (int i = threadIdx.x; i < 2048; i += 256) {
    u32 d = m[i];
    if (!(d == 0u || d == 1u)) a = 1;
    if (!(d == 0u || d == 0x3F800000u)) b = 1;
    if (!(d == 0u || d == 0x00003F80u || d == 0x3F800000u || d == 0x3F803F80u)) cc = 1;
  }
  if (a) atomicOr(&sa, 1);
  if (b) atomicOr(&sb, 1);
  if (cc) atomicOr(&sc, 1);
  __syncthreads();
  if (threadIdx.x == 0) {
    flag[1] = (cnt > 3400) ? 1 : 0;
    flag[0] = (sa == 0) ? 0 : ((sb == 0) ? 1 : ((sc == 0) ? 2 : 3));
  }
}

// ---------------------------------------------------------------------------
struct PrepArgs {
  const void* csrc[11]; u16* cdst[11]; int cn[11];
  const void* tsrc[6]; u16* tdst[6]; int tK[6]; int tN[6];
  const void* mask; u64* bm;
};
__global__ __launch_bounds__(256) void prep_kernel(PrepArgs a, const int* __restrict__ flag) {
  const int job = blockIdx.y;
  const int dt = flag[1];
  if (job < 11) {
    const int n = a.cn[job];
    u16* d = a.cdst[job];
    if (dt) {
      const u16* s = (const u16*)a.csrc[job];
      for (int i = blockIdx.x * 256 + threadIdx.x; i < n; i += gridDim.x * 256) d[i] = s[i];
    } else {
      const float* s = (const float*)a.csrc[job];
      for (int i = blockIdx.x * 256 + threadIdx.x; i < n; i += gridDim.x * 256) d[i] = f2bf(s[i]);
    }
  } else if (job < 17) {
    const int t = job - 11;
    const int K = a.tK[t], N = a.tN[t];
    const int total = K * N;
    u16* d = a.tdst[t];
    for (int i = blockIdx.x * 256 + threadIdx.x; i < total; i += gridDim.x * 256) {
      int n = i / K, k = i - n * K;
      u16 vv;
      if (dt) vv = ((const u16*)a.tsrc[t])[(size_t)k * N + n];
      else vv = f2bf(((const float*)a.tsrc[t])[(size_t)k * N + n]);
      d[i] = vv;
    }
  } else {
    const int gw = (blockIdx.x * 256 + threadIdx.x) >> 6;
    const int lane = threadIdx.x & 63;
    if (gw < 128) {
      const int fl = flag[0];
      u64 bal = __ballot(mget(a.mask, fl, gw * 64 + lane) != 0);
      if (lane == 0) a.bm[gw] = bal;
    }
  }
}

// ---------------------------------------------------------------------------
// KNN v2 (unchanged).
__global__ __launch_bounds__(256) void knn_kernel(const u64* __restrict__ bitmask,
                                                  int* __restrict__ knn_out) {
  const int tid = threadIdx.x;
  const int wid = tid >> 6, lane = tid & 63;
  const int q0 = blockIdx.x * 4;
  const int b = q0 >> 12;
  const int q = q0 + wid;
  const int v = q & 4095;
  __shared__ u64 smask[64];
  __shared__ int hist4[4][64];
  __shared__ int listT[4][64];
  __shared__ int out16s[4][16];
  __shared__ int meta[4][3];
  __shared__ int cntA[4], cntT[4];
  if (tid < 64) smask[tid] = bitmask[b * 64 + tid];
  for (int i = tid; i < 4 * 64; i += 256) ((int*)hist4)[i] = 0;
  if (lane == 0) { cntA[wid] = 0; cntT[wid] = 0; }
  __syncthreads();
  const int iv = v >> 8, jv = (v >> 4) & 15, kv = v & 15;
  #pragma unroll
  for (int t = 0; t < 12; ++t) {
    int o = t * 64 + lane;
    if (o < 729) {
      int oi = o / 81, rm = o - oi * 81;
      int oj = rm / 9, ok = rm - oj * 9;
      int i = iv + oi - 4, j = jv + oj - 4, k = kv + ok - 4;
      if (((i | j | k) & ~15) == 0) {
        int u = (i << 8) | (j << 4) | k;
        if ((smask[u >> 6] >> (u & 63)) & 1ull) {
          int di = oi - 4, dj = oj - 4, dk = ok - 4;
          atomicAdd(&hist4[wid][di * di + dj * dj + dk * dk], 1);
        }
      }
    }
  }
  __syncthreads();
  if (lane == 0) {
    int cum = 0, T = -1, below = 0;
    for (int d = 0; d <= 48; ++d) {
      int h = hist4[wid][d];
      if (h > 0 && cum + h >= cKN) { T = d; below = cum; break; }
      cum += h;
    }
    if (T > 24) T = -1;
    meta[wid][0] = T; meta[wid][1] = below; meta[wid][2] = (T < 0) ? 1 : 0;
  }
  __syncthreads();
  const int T = meta[wid][0], below = meta[wid][1], fb = meta[wid][2];
  #pragma unroll
  for (int t = 0; t < 12; ++t) {
    int o = t * 64 + lane;
    if (o < 729) {
      int oi = o / 81, rm = o - oi * 81;
      int oj = rm / 9, ok = rm - oj * 9;
      int i = iv + oi - 4, j = jv + oj - 4, k = kv + ok - 4;
      if (((i | j | k) & ~15) == 0) {
        int u = (i << 8) | (j << 4) | k;
        if ((smask[u >> 6] >> (u & 63)) & 1ull) {
          int di = oi - 4, dj = oj - 4, dk = ok - 4;
          int d2 = di * di + dj * dj + dk * dk;
          if (d2 < T) { int p = atomicAdd(&cntA[wid], 1); out16s[wid][p] = u; }
          else if (d2 == T) { int p = atomicAdd(&cntT[wid], 1); if (p < 64) listT[wid][p] = u; }
        }
      }
    }
  }
  __syncthreads();
  if (!fb) {
    if (lane == 0) {
      int need = cKN - below;
      int nT = cntT[wid] < 64 ? cntT[wid] : 64;
      for (int r = 0; r < need; ++r) {
        int bi = 0, bu = 0x7FFFFFFF;
        for (int i2 = 0; i2 < nT; ++i2) { int x = listT[wid][i2]; if (x < bu) { bu = x; bi = i2; } }
        out16s[wid][below + r] = bu;
        listT[wid][bi] = 0x7FFFFFFF;
      }
    }
  } else {
    u64 rem = smask[lane];
    const int myi = lane >> 2;
    const int di2 = (iv - myi) * (iv - myi);
    for (int r = 0; r < cKN; ++r) {
      u64 tmp = rem;
      u32 best = 0xFFFFFFFFu;
      while (tmp) {
        int bp = __builtin_ctzll(tmp);
        tmp &= tmp - 1;
        int u = (lane << 6) | bp;
        int dj = jv - ((u >> 4) & 15), dk = kv - (u & 15);
        u32 key = (u32)(((di2 + dj * dj + dk * dk) << 12) | u);
        if (key < best) best = key;
      }
      u32 pk = (best == 0xFFFFFFFFu) ? 0xFFFFFFFFu : ((best << 6) | (u32)lane);
      #pragma unroll
      for (int off = 1; off < 64; off <<= 1) {
        u32 o2 = __shfl_xor(pk, off);
        if (o2 < pk) pk = o2;
      }
      int u = (int)((pk >> 6) & 4095u);
      int wl = (int)(pk & 63u);
      if (lane == wl) rem &= ~(1ull << (u & 63));
      if (lane == 0) out16s[wid][r] = u;
    }
  }
  __syncthreads();
  if (lane < cKN) knn_out[q * cKN + lane] = out16s[wid][lane];
}

// ---------------------------------------------------------------------------
// F_A: X1 = LN(tok@We+be; g1,bt1) ; QB = X1@Wqkv + bqkv.  (round 12)
__global__ __launch_bounds__(512) void fused_ln_qkv(
    const u16* __restrict__ tokc, const u16* __restrict__ WeT,
    const u16* __restrict__ be, const u16* __restrict__ g1, const u16* __restrict__ bt1,
    const u16* __restrict__ WqkvT, const u16* __restrict__ bqkv,
    u16* __restrict__ QB) {
  __shared__ alignas(16) u16 Afull[3 * 2048];
  __shared__ alignas(16) u16 Bst[8][2][3072];
  __shared__ alignas(16) char X1[32 * 768];
  __shared__ float st[32][8][2];
  const int tid = threadIdx.x;
  const int lane = tid & 63, wn = tid >> 6;
  const int l15 = lane & 15, l4 = lane >> 4;
  const int sr = lane >> 3;
  const int scs = (((lane & 7) ^ sr) << 3);
  const int row0 = blockIdx.x * 32;
  u16* bpriv = &Bst[wn][0][0];

  for (int g = wn; g < 12; g += 8)
    gload16(tokc + (size_t)(row0 + (g & 3) * 8 + sr) * 192 + (g >> 2) * 64 + scs,
            (char*)Afull + g * 1024);
  SBPIN();
  __syncthreads();

  f32x4 acc[2][3];
  #pragma unroll
  for (int m = 0; m < 2; ++m)
    #pragma unroll
    for (int n = 0; n < 3; ++n) acc[m][n] = f32x4{0.f, 0.f, 0.f, 0.f};
  stage_1x8<3>(WeT + (size_t)(wn * 48) * 192, 192, bpriv, l15, l4, sr, scs, acc,
               [&](int m, int t, int ks) {
                 return *(const short8*)&Afull[t * 2048 + ldswz(m * 16 + l15, ks * 32 + l4 * 8)];
               });
  float s[2][4], sq[2][4];
  #pragma unroll
  for (int m = 0; m < 2; ++m)
    #pragma unroll
    for (int j = 0; j < 4; ++j) { s[m][j] = 0.f; sq[m][j] = 0.f; }
  #pragma unroll
  for (int n = 0; n < 3; ++n) {
    const float bi = bf2f(be[wn * 48 + n * 16 + l15]);
    #pragma unroll
    for (int m = 0; m < 2; ++m)
      #pragma unroll
      for (int j = 0; j < 4; ++j) {
        acc[m][n][j] += bi;
        s[m][j] += acc[m][n][j]; sq[m][j] += acc[m][n][j] * acc[m][n][j];
      }
  }
  #pragma unroll
  for (int off = 1; off < 16; off <<= 1)
    #pragma unroll
    for (int m = 0; m < 2; ++m)
      #pragma unroll
      for (int j = 0; j < 4; ++j) { s[m][j] += __shfl_xor(s[m][j], off); sq[m][j] += __shfl_xor(sq[m][j], off); }
  if (l15 == 0) {
    #pragma unroll
    for (int m = 0; m < 2; ++m)
      #pragma unroll
      for (int j = 0; j < 4; ++j) {
        const int rl = m * 16 + l4 * 4 + j;
        st[rl][wn][0] = s[m][j]; st[rl][wn][1] = sq[m][j];
      }
  }
  __syncthreads();
  #pragma unroll
  for (int m = 0; m < 2; ++m)
    #pragma unroll
    for (int j = 0; j < 4; ++j) {
      const int rl = m * 16 + l4 * 4 + j;
      float ts = 0.f, tq = 0.f;
      #pragma unroll
      for (int wv = 0; wv < 8; ++wv) { ts += st[rl][wv][0]; tq += st[rl][wv][1]; }
      const float mean = ts * (1.0f / 384.0f);
      const float var = tq * (1.0f / 384.0f) - mean * mean;
      const float rstd = rsqrtf(var + 1e-5f);
      #pragma unroll
      for (int n = 0; n < 3; ++n) {
        const int col = wn * 48 + n * 16 + l15;
        const float v = (acc[m][n][j] - mean) * rstd * bf2f(g1[col]) + bf2f(bt1[col]);
        *(u16*)(X1 + swz(rl, rl * 768 + col * 2)) = f2bf(v);
      }
    }
  __syncthreads();

  for (int chunk = 0; chunk < 3; ++chunk) {
    f32x4 a2[2][3];
    #pragma unroll
    for (int m = 0; m < 2; ++m)
      #pragma unroll
      for (int n = 0; n < 3; ++n) a2[m][n] = f32x4{0.f, 0.f, 0.f, 0.f};
    stage_1x8<6>(WqkvT + (size_t)(chunk * 384 + wn * 48) * 384, 384, bpriv,
                 l15, l4, sr, scs, a2,
                 [&](int m, int t, int ks) {
                   const int rl = m * 16 + l15;
                   return *(const short8*)(X1 + swz(rl, rl * 768 + (t * 64 + ks * 32 + l4 * 8) * 2));
                 });
    #pragma unroll
    for (int n = 0; n < 3; ++n) {
      const int col = chunk * 384 + wn * 48 + n * 16 + l15;
      const float bi = bf2f(bqkv[col]);
      #pragma unroll
      for (int m = 0; m < 2; ++m)
        #pragma unroll
        for (int j = 0; j < 4; ++j)
          QB[(size_t)(row0 + m * 16 + l4 * 4 + j) * c3E + col] = f2bf(a2[m][n][j] + bi);
    }
  }
}

// ---------------------------------------------------------------------------
// F_CD: T=(S2@Wo+bo)*mask ; xm=(T@Wc+bc)/2+tok (REGS) ; S1=LN(xm@We+be) (LDS);
//       H=gelu(S1@W1+b1) ; F=H@W2+b2 ; out=(F@Wc+bc)/2+xm.
__global__ __launch_bounds__(512) void fused_cd(
    const u16* __restrict__ S2, const u16* __restrict__ WoT, const u16* __restrict__ bo,
    const void* __restrict__ mask, const int* __restrict__ flag,
    const u16* __restrict__ WcT, const u16* __restrict__ bc, const u16* __restrict__ tokc,
    const u16* __restrict__ WeT, const u16* __restrict__ be,
    const u16* __restrict__ g2, const u16* __restrict__ bt2,
    const u16* __restrict__ W1T, const u16* __restrict__ b1,
    const u16* __restrict__ W2T, const u16* __restrict__ b2,
    void* __restrict__ outv) {
  __shared__ alignas(16) u16 Afull[6 * 2048];   // 24KB: S2 tiles; later H (byte-swz)
  __shared__ alignas(16) u16 Bst[8][2][3072];   // 96KB wave-private dbuf
  __shared__ alignas(16) char Tb[32 * 768];     // 24KB: T -> X2 -> S1 (byte-swz)
  __shared__ float st[32][8][2];
  char* HbA = (char*)Afull;
  const int tid = threadIdx.x;
  const int lane = tid & 63, wn = tid >> 6;
  const int wr = wn >> 2, wc = wn & 3;
  const int l15 = lane & 15, l4 = lane >> 4;
  const int sr = lane >> 3;
  const int scs = (((lane & 7) ^ sr) << 3);
  const int row0 = blockIdx.x * 32;
  const int fl = flag[0];
  u16* bpriv = &Bst[wn][0][0];

  for (int g = wn; g < 24; g += 8)
    gload16(S2 + (size_t)(row0 + (g & 3) * 8 + sr) * cE + (g >> 2) * 64 + scs,
            (char*)Afull + g * 1024);
  SBPIN();
  __syncthreads();

  // stage 1: T = (S2 @ WoT^T + bo) * fmask  (1x8)
  {
    f32x4 acc[2][3];
    #pragma unroll
    for (int m = 0; m < 2; ++m)
      #pragma unroll
      for (int n = 0; n < 3; ++n) acc[m][n] = f32x4{0.f, 0.f, 0.f, 0.f};
    stage_1x8<6>(WoT + (size_t)(wn * 48) * 384, 384, bpriv, l15, l4, sr, scs, acc,
                 [&](int m, int t, int ks) {
                   return *(const short8*)&Afull[t * 2048 + ldswz(m * 16 + l15, ks * 32 + l4 * 8)];
                 });
    #pragma unroll
    for (int m = 0; m < 2; ++m)
      #pragma unroll
      for (int j = 0; j < 4; ++j) {
        const int rl = m * 16 + l4 * 4 + j;
        const float fm = mget(mask, fl, row0 + rl) ? 1.0f : 0.0f;
        #pragma unroll
        for (int n = 0; n < 3; ++n) {
          const int col = wn * 48 + n * 16 + l15;
          const float v = (acc[m][n][j] + bf2f(bo[col])) * fm;
          *(u16*)(Tb + swz(rl, rl * 768 + col * 2)) = f2bf(v);
        }
      }
  }
  __syncthreads();

  // stage 2: xm = (T @ WcT^T + bc)*0.5 + tok  — REGISTERS (2x4)
  f32x4 xm[3];
  #pragma unroll
  for (int n = 0; n < 3; ++n) xm[n] = f32x4{0.f, 0.f, 0.f, 0.f};
  stage_2x4<6>(WcT + (size_t)(wc * 48) * 384, 384, bpriv, l15, l4, sr, scs, xm,
               [&](int t, int ks) {
                 const int rl = wr * 16 + l15;
                 return *(const short8*)(Tb + swz(rl, rl * 768 + (t * 64 + ks * 32 + l4 * 8) * 2));
               });
  __syncthreads();   // all Tb(T) readers done
  #pragma unroll
  for (int n = 0; n < 3; ++n) {
    const int col = wc * 48 + n * 16 + l15;
    const float bi = bf2f(bc[col]);
    #pragma unroll
    for (int j = 0; j < 4; ++j) {
      const int rl = wr * 16 + l4 * 4 + j;
      xm[n][j] = (xm[n][j] + bi) * 0.5f + bf2f(tokc[(size_t)(row0 + rl) * cD + col]);
      *(u16*)(Tb + swz(rl, rl * 384 + col * 2)) = f2bf(xm[n][j]);   // X2
    }
  }
  __syncthreads();

  // stage 3: S1 = LN(X2 @ WeT^T + be; g2, bt2) -> Tb (1x8, K=192)
  {
    f32x4 a3[2][3];
    #pragma unroll
    for (int m = 0; m < 2; ++m)
      #pragma unroll
      for (int n = 0; n < 3; ++n) a3[m][n] = f32x4{0.f, 0.f, 0.f, 0.f};
    stage_1x8<3>(WeT + (size_t)(wn * 48) * 192, 192, bpriv, l15, l4, sr, scs, a3,
                 [&](int m, int t, int ks) {
                   const int rl = m * 16 + l15;
                   return *(const short8*)(Tb + swz(rl, rl * 384 + (t * 64 + ks * 32 + l4 * 8) * 2));
                 });
    float s[2][4], sq[2][4];
    #pragma unroll
    for (int m = 0; m < 2; ++m)
      #pragma unroll
      for (int j = 0; j < 4; ++j) { s[m][j] = 0.f; sq[m][j] = 0.f; }
    #pragma unroll
    for (int n = 0; n < 3; ++n) {
      const float bi = bf2f(be[wn * 48 + n * 16 + l15]);
      #pragma unroll
      for (int m = 0; m < 2; ++m)
        #pragma unroll
        for (int j = 0; j < 4; ++j) {
          a3[m][n][j] += bi;
          s[m][j] += a3[m][n][j]; sq[m][j] += a3[m][n][j] * a3[m][n][j];
        }
    }
    #pragma unroll
    for (int off = 1; off < 16; off <<= 1)
      #pragma unroll
      for (int m = 0; m < 2; ++m)
        #pragma unroll
        for (int j = 0; j < 4; ++j) { s[m][j] += __shfl_xor(s[m][j], off); sq[m][j] += __shfl_xor(sq[m][j], off); }
    if (l15 == 0) {
      #pragma unroll
      for (int m = 0; m < 2; ++m)
        #pragma unroll
        for (int j = 0; j < 4; ++j) {
          const int rl = m * 16 + l4 * 4 + j;
          st[rl][wn][0] = s[m][j]; st[rl][wn][1] = sq[m][j];
        }
    }
    __syncthreads();   // X2 reads done + st visible
    #pragma unroll
    for (int m = 0; m < 2; ++m)
      #pragma unroll
      for (int j = 0; j < 4; ++j) {
        const int rl = m * 16 + l4 * 4 + j;
        float ts = 0.f, tq = 0.f;
        #pragma unroll
        for (int wv = 0; wv < 8; ++wv) { ts += st[rl][wv][0]; tq += st[rl][wv][1]; }
        const float mean = ts * (1.0f / 384.0f);
        const float var = tq * (1.0f / 384.0f) - mean * mean;
        const float rstd = rsqrtf(var + 1e-5f);
        #pragma unroll
        for (int n = 0; n < 3; ++n) {
          const int col = wn * 48 + n * 16 + l15;
          const float v = (a3[m][n][j] - mean) * rstd * bf2f(g2[col]) + bf2f(bt2[col]);
          *(u16*)(Tb + swz(rl, rl * 768 + col * 2)) = f2bf(v);   // S1 (overwrites X2)
        }
      }
  }
  __syncthreads();

  // ---- FFN (from round-12 fused_ffn; A = S1 in Tb, H buffer = Afull) ----
  f32x4 accF[2][3];
  #pragma unroll
  for (int m = 0; m < 2; ++m)
    #pragma unroll
    for (int n = 0; n < 3; ++n) accF[m][n] = f32x4{0.f, 0.f, 0.f, 0.f};

  for (int half = 0; half < 2; ++half) {
    // s1: H = gelu(S1 @ W1T[half]^T + b1[half]) (1x8)
    {
      f32x4 a1[2][3];
      #pragma unroll
      for (int m = 0; m < 2; ++m)
        #pragma unroll
        for (int n = 0; n < 3; ++n) a1[m][n] = f32x4{0.f, 0.f, 0.f, 0.f};
      stage_1x8<6>(W1T + (size_t)(half * 384 + wn * 48) * 384, 384, bpriv,
                   l15, l4, sr, scs, a1,
                   [&](int m, int t, int ks) {
                     const int rl = m * 16 + l15;
                     return *(const short8*)(Tb + swz(rl, rl * 768 + (t * 64 + ks * 32 + l4 * 8) * 2));
                   });
      // half=0: Afull's S2 long dead. half=1: previous H readers retired by
      // the post-s2 __syncthreads below.
      #pragma unroll
      for (int n = 0; n < 3; ++n) {
        const int col = wn * 48 + n * 16 + l15;
        const float bi = bf2f(b1[half * 384 + col]);
        #pragma unroll
        for (int m = 0; m < 2; ++m)
          #pragma unroll
          for (int j = 0; j < 4; ++j) {
            const int rl = m * 16 + l4 * 4 + j;
            *(u16*)(HbA + swz(rl, rl * 768 + col * 2)) = f2bf(gelu_tanh(a1[m][n][j] + bi));
          }
      }
    }
    __syncthreads();
    // s2: accF += H @ W2T[:, half]^T (1x8)
    stage_1x8<6>(W2T + (size_t)(wn * 48) * 768 + half * 384, 768, bpriv,
                 l15, l4, sr, scs, accF,
                 [&](int m, int t, int ks) {
                   const int rl = m * 16 + l15;
                   return *(const short8*)(HbA + swz(rl, rl * 768 + (t * 64 + ks * 32 + l4 * 8) * 2));
                 });
    __syncthreads();
  }
  // F = accF + b2 -> HbA
  #pragma unroll
  for (int n = 0; n < 3; ++n) {
    const int col = wn * 48 + n * 16 + l15;
    const float bi = bf2f(b2[col]);
    #pragma unroll
    for (int m = 0; m < 2; ++m)
      #pragma unroll
      for (int j = 0; j < 4; ++j) {
        const int rl = m * 16 + l4 * 4 + j;
        *(u16*)(HbA + swz(rl, rl * 768 + col * 2)) = f2bf(accF[m][n][j] + bi);
      }
  }
  __syncthreads();
  // s3: out = (F @ WcT^T + bc)*0.5 + xm  (2x4; xm in regs, same ownership)
  f32x4 a3[3];
  #pragma unroll
  for (int n = 0; n < 3; ++n) a3[n] = f32x4{0.f, 0.f, 0.f, 0.f};
  stage_2x4<6>(WcT + (size_t)(wc * 48) * 384, 384, bpriv, l15, l4, sr, scs, a3,
               [&](int t, int ks) {
                 const int rl = wr * 16 + l15;
                 return *(const short8*)(HbA + swz(rl, rl * 768 + (t * 64 + ks * 32 + l4 * 8) * 2));
               });
  u16* o16 = (u16*)outv;
  float* o32 = (float*)outv;
  const int dtf = flag[1];
  #pragma unroll
  for (int n = 0; n < 3; ++n) {
    const int col = wc * 48 + n * 16 + l15;
    const float bi = bf2f(bc[col]);
    #pragma unroll
    for (int j = 0; j < 4; ++j) {
      const int rl = wr * 16 + l4 * 4 + j;
      const size_t oi = (size_t)(row0 + rl) * cD + col;
      const float r = (a3[n][j] + bi) * 0.5f + xm[n][j];
      if (dtf) o16[oi] = f2bf(r);
      else o32[oi] = r;
    }
  }
}

// ---------------------------------------------------------------------------
// attn v3 (unchanged).
__global__ __launch_bounds__(256) void attn_kernel(const u16* __restrict__ qkv,
                                                   const int* __restrict__ knn,
                                                   u16* __restrict__ o_out) {
  const int wid = threadIdx.x >> 6;
  const int lane = threadIdx.x & 63;
  const int bq = blockIdx.x * 4 + wid;
  const int b = bq >> 12;
  __shared__ float w4[4][8][8];
  __shared__ int vid4[4][8][8];
  __shared__ int nb4[4][16];
  float (*w)[8] = w4[wid];
  int (*vid)[8] = vid4[wid];
  int* nb = nb4[wid];
  if (lane < 16) nb[lane] = knn[bq * cKN + lane];
  const int h = lane >> 3;
  const int j = lane & 7;
  const uint2* qp = (const uint2*)(qkv + (size_t)bq * c3E + h * 48);
  const int r0 = nb[j], r1 = nb[j + 8];
  const uint2* k0p = (const uint2*)(qkv + ((size_t)(b * cV + r0)) * c3E + cE + h * 48);
  const uint2* k1p = (const uint2*)(qkv + ((size_t)(b * cV + r1)) * c3E + cE + h * 48);
  float s0 = 0.f, s1 = 0.f;
  #pragma unroll
  for (int t = 0; t < 12; ++t) {
    uint2 qv = qp[t];
    uint2 k0 = k0p[t];
    uint2 k1 = k1p[t];
    s0 += bflo(qv.x) * bflo(k0.x) + bfhi(qv.x) * bfhi(k0.x)
        + bflo(qv.y) * bflo(k0.y) + bfhi(qv.y) * bfhi(k0.y);
    s1 += bflo(qv.x) * bflo(k1.x) + bfhi(qv.x) * bfhi(k1.x)
        + bflo(qv.y) * bflo(k1.y) + bfhi(qv.y) * bfhi(k1.y);
  }
  const float inv = 0.14433756729740643f;  // 1/sqrt(48)
  u64 key0 = (((u64)f2ord(s0 * inv)) << 4) | (u64)(15 - j);
  u64 key1 = (((u64)f2ord(s1 * inv)) << 4) | (u64)(15 - (j + 8));
  float m0 = 0.f, Z = 0.f, myw = 0.f;
  int myv = 0;
  #pragma unroll
  for (int r = 0; r < cTK; ++r) {
    u64 best = key0 > key1 ? key0 : key1;
    u64 o1 = __shfl_xor(best, 1); if (o1 > best) best = o1;
    u64 o2 = __shfl_xor(best, 2); if (o2 > best) best = o2;
    u64 o4 = __shfl_xor(best, 4); if (o4 > best) best = o4;
    if (key0 == best) key0 = 0;
    if (key1 == best) key1 = 0;
    float sv = ord2f((u32)(best >> 4));
    int nsel = 15 - (int)(best & 15ull);
    if (r == 0) m0 = sv;
    float e = expf(sv - m0);
    Z += e;
    if (j == r) { myw = e; myv = nsel; }
  }
  w[h][j] = myw / Z;
  vid[h][j] = nb[myv];
  const u16* vbase = qkv + (size_t)(b * cV) * c3E + 2 * cE;
  #pragma unroll
  for (int rep = 0; rep < 6; ++rep) {
    int e = rep * 64 + lane;
    int h2 = e / 48;
    float acc = 0.f;
    #pragma unroll
    for (int t = 0; t < cTK; ++t)
      acc += w[h2][t] * bf2f(vbase[(size_t)vid[h2][t] * c3E + e]);
    o_out[(size_t)bq * cE + e] = f2bf(acc);
  }
}

// ---------------------------------------------------------------------------
extern "C" void kernel_launch(void* const* d_in, const int* in_sizes, int n_in,
                              void* d_out, int out_size, void* d_ws, size_t ws_size,
                              hipStream_t stream) {
  if (n_in < 18) return;
  const void* mask = d_in[1];

  char* ws = (char*)d_ws;
  size_t off = 0;
  auto alloc = [&](size_t bytes) { size_t o = off; off += (bytes + 255) & ~(size_t)255; return o; };
  int* flag  = (int*)(ws + alloc(256));
  u64* bmask = (u64*)(ws + alloc(128 * 8));
  int* knn   = (int*)(ws + alloc((size_t)cM * cKN * 4));
  u16* S2    = (u16*)(ws + alloc((size_t)cM * cE * 2));
  u16* QB    = (u16*)(ws + alloc((size_t)cM * c3E * 2));
  u16* tokc  = (u16*)(ws + alloc((size_t)cM * cD * 2));
  u16* be    = (u16*)(ws + alloc(cE * 2));
  u16* g1    = (u16*)(ws + alloc(cE * 2));
  u16* bt1   = (u16*)(ws + alloc(cE * 2));
  u16* bqkv  = (u16*)(ws + alloc(c3E * 2));
  u16* bo    = (u16*)(ws + alloc(cE * 2));
  u16* bc    = (u16*)(ws + alloc(cD * 2));
  u16* g2    = (u16*)(ws + alloc(cE * 2));
  u16* bt2   = (u16*)(ws + alloc(cE * 2));
  u16* b1    = (u16*)(ws + alloc(2 * cE * 2));
  u16* b2    = (u16*)(ws + alloc(cE * 2));
  u16* WeT   = (u16*)(ws + alloc((size_t)384 * 192 * 2));
  u16* WqkvT = (u16*)(ws + alloc((size_t)1152 * 384 * 2));
  u16* WoT   = (u16*)(ws + alloc((size_t)384 * 384 * 2));
  u16* WcT   = (u16*)(ws + alloc((size_t)256 * 384 * 2));   // rows padded 192->256
  u16* W1T   = (u16*)(ws + alloc((size_t)768 * 384 * 2));
  u16* W2T   = (u16*)(ws + alloc((size_t)384 * 768 * 2));
  (void)ws_size; (void)in_sizes; (void)out_size;

  detect_all_kernel<<<1, 256, 0, stream>>>((const u32*)d_in[0], (const u32*)mask, flag);

  {
    PrepArgs pa;
    const int csrci[11] = {0, 3, 4, 5, 7, 9, 11, 12, 13, 15, 17};
    u16* cdsts[11] = {tokc, be, g1, bt1, bqkv, bo, bc, g2, bt2, b1, b2};
    const int cns[11] = {cM * cD, cE, cE, cE, c3E, cE, cD, cE, cE, 2 * cE, cE};
    for (int i = 0; i < 11; ++i) { pa.csrc[i] = d_in[csrci[i]]; pa.cdst[i] = cdsts[i]; pa.cn[i] = cns[i]; }
    const int tsrci[6] = {2, 6, 8, 10, 14, 16};
    u16* tdsts[6] = {WeT, WqkvT, WoT, WcT, W1T, W2T};
    const int tKs[6] = {192, 384, 384, 384, 384, 768};
    const int tNs[6] = {384, 1152, 384, 192, 768, 384};
    for (int i = 0; i < 6; ++i) { pa.tsrc[i] = d_in[tsrci[i]]; pa.tdst[i] = tdsts[i]; pa.tK[i] = tKs[i]; pa.tN[i] = tNs[i]; }
    pa.mask = mask; pa.bm = bmask;
    prep_kernel<<<dim3(96, 18), 256, 0, stream>>>(pa, flag);
  }

  knn_kernel<<<cM / 4, 256, 0, stream>>>(bmask, knn);

  const int GB = cM / 32;  // 256 blocks
  fused_ln_qkv<<<GB, 512, 0, stream>>>(tokc, WeT, be, g1, bt1, WqkvT, bqkv, QB);
  attn_kernel<<<cM / 4, 256, 0, stream>>>(QB, knn, S2);
  fused_cd<<<GB, 512, 0, stream>>>(S2, WoT, bo, mask, flag, WcT, bc, tokc,
                                   WeT, be, g2, bt2, W1T, b1, W2T, b2, d_out);
}

// Round 14
// 139.835 us; speedup vs baseline: 1.4202x; 1.0791x over previous
//
#include <hip/hip_runtime.h>
#include <stdint.h>

// ============================================================================
// DSVABlockLarge — round 14: B operands in REGISTERS via fragment-packed
// weights (fixes round-9's uncoalesced-load failure).
//  * prep packs each weight into MFMA B-fragment layout: each (16col x 32k)
//    fragment = 1KB contiguous block in lane order -> B-frag load is ONE
//    coalesced global_load_dwordx4 (16B/lane). No LDS for B at all.
//  * B double-buffered in 48 VGPRs, static indices; compiler-managed waits.
//  * LDS only: A tiles (gload16, swizzled) + intermediates (X1/Tb/H).
//  * attn/knn/detect unchanged from round 13.
// ============================================================================

using u16 = unsigned short;
using u32 = unsigned int;
using u64 = unsigned long long;

typedef short short8 __attribute__((ext_vector_type(8)));
typedef float f32x4 __attribute__((ext_vector_type(4)));

#define DEV static __device__ __forceinline__

constexpr int cV = 4096, cD = 192;
constexpr int cE = 384;
constexpr int cKN = 16, cTK = 8;
constexpr int cM = 2 * cV;   // 8192 rows (B*V)
constexpr int c3E = 1152;

DEV float bf2f(u16 v) { return __uint_as_float(((u32)v) << 16); }
DEV float bflo(u32 v) { return __uint_as_float(v << 16); }
DEV float bfhi(u32 v) { return __uint_as_float(v & 0xFFFF0000u); }
DEV u16 f2bf(float f) {
  u32 u = __float_as_uint(f);
  u = (u + 0x7FFFu + ((u >> 16) & 1u)) >> 16;
  return (u16)u;
}
DEV int mget(const void* mp, int flag, int i) {
  if (flag == 0) return ((const int*)mp)[i] != 0;
  if (flag == 1) return ((const float*)mp)[i] != 0.0f;
  if (flag == 2) return ((const u16*)mp)[i] != 0;
  return ((const unsigned char*)mp)[i] != 0;
}
DEV float gelu_tanh(float x) {
  float t = tanhf(0.7978845608028654f * (x + 0.044715f * x * x * x));
  return 0.5f * x * (1.0f + t);
}
DEV u32 f2ord(float f) {
  u32 u = __float_as_uint(f);
  return (u & 0x80000000u) ? ~u : (u | 0x80000000u);
}
DEV float ord2f(u32 o) {
  u32 bits = (o & 0x80000000u) ? (o & 0x7FFFFFFFu) : ~o;
  return __uint_as_float(bits);
}
DEV int bf_plausible(u32 h) {
  if (h == 0u || h == 0x8000u) return 1;
  u32 e = (h >> 7) & 0xFFu;
  return (e >= 100u && e <= 140u) ? 1 : 0;
}

using as1p = const unsigned int __attribute__((address_space(1)))*;
using as3p = unsigned int __attribute__((address_space(3)))*;
DEV void gload16(const void* g, void* l) {
  __builtin_amdgcn_global_load_lds((as1p)g, (as3p)l, 16, 0, 0);
}
DEV f32x4 mfma16x16x32_bf16(short8 a, short8 b, f32x4 c) {
  asm volatile("v_mfma_f32_16x16x32_bf16 %0, %1, %2, %0" : "+v"(c) : "v"(a), "v"(b));
  return c;
}
DEV int swz(int row, int byteoff) { return byteoff ^ ((row & 7) << 4); }
DEV int ldswz(int r, int c) { return r * 64 + (c ^ ((r & 7) * 8)); }
#define SBPIN() __builtin_amdgcn_sched_barrier(0)

// B fragment block: v[n][ks] = fragment (16 cols=n, 32 k=ks) in lane order.
struct BF { short8 v[3][2]; };
// fbase = WF + colblk0*nKB*512 ; frag (n, kb+ks) at (n*nKB + kb + ks)*512.
DEV void loadBF(BF& b, const u16* __restrict__ fbase, int nKB, int kb, int lane) {
  #pragma unroll
  for (int n = 0; n < 3; ++n)
    #pragma unroll
    for (int ks = 0; ks < 2; ++ks)
      b.v[n][ks] = *(const short8*)(fbase + ((size_t)n * nKB + kb + ks) * 512 + lane * 8);
}

// Register-B K-loop, 1(M:32 rows)x8(N:48 cols/wave).
template <int T, typename AF>
DEV void rstage_1x8(const u16* __restrict__ fbase, int nKB, int kb0,
                    int lane, int l15, int l4,
                    f32x4 (&acc)[2][3], AF&& aread) {
  BF bp[2];
  loadBF(bp[0], fbase, nKB, kb0, lane);
  #pragma unroll
  for (int t = 0; t < T; ++t) {
    if (t + 1 < T) loadBF(bp[(t + 1) & 1], fbase, nKB, kb0 + 2 * (t + 1), lane);
    #pragma unroll
    for (int ks = 0; ks < 2; ++ks) {
      short8 a0 = aread(0, t, ks);
      short8 a1 = aread(1, t, ks);
      #pragma unroll
      for (int n = 0; n < 3; ++n) {
        acc[0][n] = mfma16x16x32_bf16(a0, bp[t & 1].v[n][ks], acc[0][n]);
        acc[1][n] = mfma16x16x32_bf16(a1, bp[t & 1].v[n][ks], acc[1][n]);
      }
    }
  }
}

// Register-B K-loop, 2(M)x4(N): wave owns 16 rows x 48 cols.
template <int T, typename AF>
DEV void rstage_2x4(const u16* __restrict__ fbase, int nKB, int kb0,
                    int lane, int l15, int l4,
                    f32x4 (&acc)[3], AF&& aread) {
  BF bp[2];
  loadBF(bp[0], fbase, nKB, kb0, lane);
  #pragma unroll
  for (int t = 0; t < T; ++t) {
    if (t + 1 < T) loadBF(bp[(t + 1) & 1], fbase, nKB, kb0 + 2 * (t + 1), lane);
    #pragma unroll
    for (int ks = 0; ks < 2; ++ks) {
      short8 a = aread(t, ks);
      #pragma unroll
      for (int n = 0; n < 3; ++n)
        acc[n] = mfma16x16x32_bf16(a, bp[t & 1].v[n][ks], acc[n]);
    }
  }
}

// ---------------------------------------------------------------------------
__global__ void detect_all_kernel(const u32* __restrict__ tok,
                                  const u32* __restrict__ m,
                                  int* __restrict__ flag) {
  __shared__ int cnt, sa, sb, sc;
  if (threadIdx.x == 0) { cnt = 0; sa = 0; sb = 0; sc = 0; }
  __syncthreads();
  int c = 0;
  for (int i = threadIdx.x; i < 4096; i += 256) {
    u32 d = tok[i];
    c += bf_plausible(d & 0xFFFFu) & bf_plausible(d >> 16);
  }
  atomicAdd(&cnt, c);
  int a = 0, b = 0, cc = 0;
  for (int i = threadIdx.x; i < 2048; i += 256) {
    u32 d = m[i];
    if (!(d == 0u || d == 1u)) a = 1;
    if (!(d == 0u || d == 0x3F800000u)) b = 1;
    if (!(d == 0u || d == 0x00003F80u || d == 0x3F800000u || d == 0x3F803F80u)) cc = 1;
  }
  if (a) atomicOr(&sa, 1);
  if (b) atomicOr(&sb, 1);
  if (cc) atomicOr(&sc, 1);
  __syncthreads();
  if (threadIdx.x == 0) {
    flag[1] = (cnt > 3400) ? 1 : 0;
    flag[0] = (sa == 0) ? 0 : ((sb == 0) ? 1 : ((sc == 0) ? 2 : 3));
  }
}

// ---------------------------------------------------------------------------
// Prep: jobs 0..10 convert-to-bf16; 11..16 pack weights to fragment layout;
// 17 bitmask.
struct PrepArgs {
  const void* csrc[11]; u16* cdst[11]; int cn[11];
  const void* tsrc[6]; u16* tdst[6]; int tK[6]; int tN[6];
  const void* mask; u64* bm;
};
__global__ __launch_bounds__(256) void prep_kernel(PrepArgs a, const int* __restrict__ flag) {
  const int job = blockIdx.y;
  const int dt = flag[1];
  if (job < 11) {
    const int n = a.cn[job];
    u16* d = a.cdst[job];
    if (dt) {
      const u16* s = (const u16*)a.csrc[job];
      for (int i = blockIdx.x * 256 + threadIdx.x; i < n; i += gridDim.x * 256) d[i] = s[i];
    } else {
      const float* s = (const float*)a.csrc[job];
      for (int i = blockIdx.x * 256 + threadIdx.x; i < n; i += gridDim.x * 256) d[i] = f2bf(s[i]);
    }
  } else if (job < 17) {
    const int t = job - 11;
    const int K = a.tK[t], N = a.tN[t];
    const int nKB = K >> 5;
    const int total = K * N;
    u16* d = a.tdst[t];
    for (int i = blockIdx.x * 256 + threadIdx.x; i < total; i += gridDim.x * 256) {
      const int frag = i >> 9;
      const int r = i & 511;
      const int lane = r >> 3, e = r & 7;
      const int l4 = lane >> 4, l15 = lane & 15;
      const int colblk = frag / nKB;
      const int kblk = frag - colblk * nKB;
      const int n = colblk * 16 + l15;
      const int k = kblk * 32 + l4 * 8 + e;
      u16 vv;
      if (dt) vv = ((const u16*)a.tsrc[t])[(size_t)k * N + n];
      else vv = f2bf(((const float*)a.tsrc[t])[(size_t)k * N + n]);
      d[i] = vv;
    }
  } else {
    const int gw = (blockIdx.x * 256 + threadIdx.x) >> 6;
    const int lane = threadIdx.x & 63;
    if (gw < 128) {
      const int fl = flag[0];
      u64 bal = __ballot(mget(a.mask, fl, gw * 64 + lane) != 0);
      if (lane == 0) a.bm[gw] = bal;
    }
  }
}

// ---------------------------------------------------------------------------
// KNN v2 (unchanged).
__global__ __launch_bounds__(256) void knn_kernel(const u64* __restrict__ bitmask,
                                                  int* __restrict__ knn_out) {
  const int tid = threadIdx.x;
  const int wid = tid >> 6, lane = tid & 63;
  const int q0 = blockIdx.x * 4;
  const int b = q0 >> 12;
  const int q = q0 + wid;
  const int v = q & 4095;
  __shared__ u64 smask[64];
  __shared__ int hist4[4][64];
  __shared__ int listT[4][64];
  __shared__ int out16s[4][16];
  __shared__ int meta[4][3];
  __shared__ int cntA[4], cntT[4];
  if (tid < 64) smask[tid] = bitmask[b * 64 + tid];
  for (int i = tid; i < 4 * 64; i += 256) ((int*)hist4)[i] = 0;
  if (lane == 0) { cntA[wid] = 0; cntT[wid] = 0; }
  __syncthreads();
  const int iv = v >> 8, jv = (v >> 4) & 15, kv = v & 15;
  #pragma unroll
  for (int t = 0; t < 12; ++t) {
    int o = t * 64 + lane;
    if (o < 729) {
      int oi = o / 81, rm = o - oi * 81;
      int oj = rm / 9, ok = rm - oj * 9;
      int i = iv + oi - 4, j = jv + oj - 4, k = kv + ok - 4;
      if (((i | j | k) & ~15) == 0) {
        int u = (i << 8) | (j << 4) | k;
        if ((smask[u >> 6] >> (u & 63)) & 1ull) {
          int di = oi - 4, dj = oj - 4, dk = ok - 4;
          atomicAdd(&hist4[wid][di * di + dj * dj + dk * dk], 1);
        }
      }
    }
  }
  __syncthreads();
  if (lane == 0) {
    int cum = 0, T = -1, below = 0;
    for (int d = 0; d <= 48; ++d) {
      int h = hist4[wid][d];
      if (h > 0 && cum + h >= cKN) { T = d; below = cum; break; }
      cum += h;
    }
    if (T > 24) T = -1;
    meta[wid][0] = T; meta[wid][1] = below; meta[wid][2] = (T < 0) ? 1 : 0;
  }
  __syncthreads();
  const int T = meta[wid][0], below = meta[wid][1], fb = meta[wid][2];
  #pragma unroll
  for (int t = 0; t < 12; ++t) {
    int o = t * 64 + lane;
    if (o < 729) {
      int oi = o / 81, rm = o - oi * 81;
      int oj = rm / 9, ok = rm - oj * 9;
      int i = iv + oi - 4, j = jv + oj - 4, k = kv + ok - 4;
      if (((i | j | k) & ~15) == 0) {
        int u = (i << 8) | (j << 4) | k;
        if ((smask[u >> 6] >> (u & 63)) & 1ull) {
          int di = oi - 4, dj = oj - 4, dk = ok - 4;
          int d2 = di * di + dj * dj + dk * dk;
          if (d2 < T) { int p = atomicAdd(&cntA[wid], 1); out16s[wid][p] = u; }
          else if (d2 == T) { int p = atomicAdd(&cntT[wid], 1); if (p < 64) listT[wid][p] = u; }
        }
      }
    }
  }
  __syncthreads();
  if (!fb) {
    if (lane == 0) {
      int need = cKN - below;
      int nT = cntT[wid] < 64 ? cntT[wid] : 64;
      for (int r = 0; r < need; ++r) {
        int bi = 0, bu = 0x7FFFFFFF;
        for (int i2 = 0; i2 < nT; ++i2) { int x = listT[wid][i2]; if (x < bu) { bu = x; bi = i2; } }
        out16s[wid][below + r] = bu;
        listT[wid][bi] = 0x7FFFFFFF;
      }
    }
  } else {
    u64 rem = smask[lane];
    const int myi = lane >> 2;
    const int di2 = (iv - myi) * (iv - myi);
    for (int r = 0; r < cKN; ++r) {
      u64 tmp = rem;
      u32 best = 0xFFFFFFFFu;
      while (tmp) {
        int bp = __builtin_ctzll(tmp);
        tmp &= tmp - 1;
        int u = (lane << 6) | bp;
        int dj = jv - ((u >> 4) & 15), dk = kv - (u & 15);
        u32 key = (u32)(((di2 + dj * dj + dk * dk) << 12) | u);
        if (key < best) best = key;
      }
      u32 pk = (best == 0xFFFFFFFFu) ? 0xFFFFFFFFu : ((best << 6) | (u32)lane);
      #pragma unroll
      for (int off = 1; off < 64; off <<= 1) {
        u32 o2 = __shfl_xor(pk, off);
        if (o2 < pk) pk = o2;
      }
      int u = (int)((pk >> 6) & 4095u);
      int wl = (int)(pk & 63u);
      if (lane == wl) rem &= ~(1ull << (u & 63));
      if (lane == 0) out16s[wid][r] = u;
    }
  }
  __syncthreads();
  if (lane < cKN) knn_out[q * cKN + lane] = out16s[wid][lane];
}

// ---------------------------------------------------------------------------
// F_A: X1 = LN(tok@We+be; g1,bt1) ; QB = X1@Wqkv + bqkv.  Register-B.
__global__ __launch_bounds__(512) void fused_ln_qkv(
    const u16* __restrict__ tokc, const u16* __restrict__ WeF,
    const u16* __restrict__ be, const u16* __restrict__ g1, const u16* __restrict__ bt1,
    const u16* __restrict__ WqkvF, const u16* __restrict__ bqkv,
    u16* __restrict__ QB) {
  __shared__ alignas(16) u16 Afull[3 * 2048];   // 12KB tok (swz)
  __shared__ alignas(16) char X1[32 * 768];     // 24KB swz
  __shared__ float st[32][8][2];
  const int tid = threadIdx.x;
  const int lane = tid & 63, wn = tid >> 6;
  const int l15 = lane & 15, l4 = lane >> 4;
  const int sr = lane >> 3;
  const int scs = (((lane & 7) ^ sr) << 3);
  const int row0 = blockIdx.x * 32;

  for (int g = wn; g < 12; g += 8)
    gload16(tokc + (size_t)(row0 + (g & 3) * 8 + sr) * 192 + (g >> 2) * 64 + scs,
            (char*)Afull + g * 1024);
  SBPIN();
  __syncthreads();

  // stage 1: tok @ We (K=192: nKB=6, T=3; colblk0 = wn*3)
  f32x4 acc[2][3];
  #pragma unroll
  for (int m = 0; m < 2; ++m)
    #pragma unroll
    for (int n = 0; n < 3; ++n) acc[m][n] = f32x4{0.f, 0.f, 0.f, 0.f};
  rstage_1x8<3>(WeF + (size_t)(wn * 3) * 6 * 512, 6, 0, lane, l15, l4, acc,
                [&](int m, int t, int ks) {
                  return *(const short8*)&Afull[t * 2048 + ldswz(m * 16 + l15, ks * 32 + l4 * 8)];
                });
  float s[2][4], sq[2][4];
  #pragma unroll
  for (int m = 0; m < 2; ++m)
    #pragma unroll
    for (int j = 0; j < 4; ++j) { s[m][j] = 0.f; sq[m][j] = 0.f; }
  #pragma unroll
  for (int n = 0; n < 3; ++n) {
    const float bi = bf2f(be[wn * 48 + n * 16 + l15]);
    #pragma unroll
    for (int m = 0; m < 2; ++m)
      #pragma unroll
      for (int j = 0; j < 4; ++j) {
        acc[m][n][j] += bi;
        s[m][j] += acc[m][n][j]; sq[m][j] += acc[m][n][j] * acc[m][n][j];
      }
  }
  #pragma unroll
  for (int off = 1; off < 16; off <<= 1)
    #pragma unroll
    for (int m = 0; m < 2; ++m)
      #pragma unroll
      for (int j = 0; j < 4; ++j) { s[m][j] += __shfl_xor(s[m][j], off); sq[m][j] += __shfl_xor(sq[m][j], off); }
  if (l15 == 0) {
    #pragma unroll
    for (int m = 0; m < 2; ++m)
      #pragma unroll
      for (int j = 0; j < 4; ++j) {
        const int rl = m * 16 + l4 * 4 + j;
        st[rl][wn][0] = s[m][j]; st[rl][wn][1] = sq[m][j];
      }
  }
  __syncthreads();
  #pragma unroll
  for (int m = 0; m < 2; ++m)
    #pragma unroll
    for (int j = 0; j < 4; ++j) {
      const int rl = m * 16 + l4 * 4 + j;
      float ts = 0.f, tq = 0.f;
      #pragma unroll
      for (int wv = 0; wv < 8; ++wv) { ts += st[rl][wv][0]; tq += st[rl][wv][1]; }
      const float mean = ts * (1.0f / 384.0f);
      const float var = tq * (1.0f / 384.0f) - mean * mean;
      const float rstd = rsqrtf(var + 1e-5f);
      #pragma unroll
      for (int n = 0; n < 3; ++n) {
        const int col = wn * 48 + n * 16 + l15;
        const float v = (acc[m][n][j] - mean) * rstd * bf2f(g1[col]) + bf2f(bt1[col]);
        *(u16*)(X1 + swz(rl, rl * 768 + col * 2)) = f2bf(v);
      }
    }
  __syncthreads();

  // stage 2: QB = X1 @ Wqkv (K=384: nKB=12, T=6; colblk0 = chunk*24 + wn*3)
  for (int chunk = 0; chunk < 3; ++chunk) {
    f32x4 a2[2][3];
    #pragma unroll
    for (int m = 0; m < 2; ++m)
      #pragma unroll
      for (int n = 0; n < 3; ++n) a2[m][n] = f32x4{0.f, 0.f, 0.f, 0.f};
    rstage_1x8<6>(WqkvF + (size_t)(chunk * 24 + wn * 3) * 12 * 512, 12, 0, lane, l15, l4, a2,
                  [&](int m, int t, int ks) {
                    const int rl = m * 16 + l15;
                    return *(const short8*)(X1 + swz(rl, rl * 768 + (t * 64 + ks * 32 + l4 * 8) * 2));
                  });
    #pragma unroll
    for (int n = 0; n < 3; ++n) {
      const int col = chunk * 384 + wn * 48 + n * 16 + l15;
      const float bi = bf2f(bqkv[col]);
      #pragma unroll
      for (int m = 0; m < 2; ++m)
        #pragma unroll
        for (int j = 0; j < 4; ++j)
          QB[(size_t)(row0 + m * 16 + l4 * 4 + j) * c3E + col] = f2bf(a2[m][n][j] + bi);
    }
  }
}

// ---------------------------------------------------------------------------
// F_CD: T=(S2@Wo+bo)*mask ; xm=(T@Wc+bc)/2+tok (REGS) ; S1=LN(xm@We+be) ;
//       H=gelu(S1@W1+b1) ; F=H@W2+b2 ; out=(F@Wc+bc)/2+xm.  Register-B.
__global__ __launch_bounds__(512) void fused_cd(
    const u16* __restrict__ S2, const u16* __restrict__ WoF, const u16* __restrict__ bo,
    const void* __restrict__ mask, const int* __restrict__ flag,
    const u16* __restrict__ WcF, const u16* __restrict__ bc, const u16* __restrict__ tokc,
    const u16* __restrict__ WeF, const u16* __restrict__ be,
    const u16* __restrict__ g2, const u16* __restrict__ bt2,
    const u16* __restrict__ W1F, const u16* __restrict__ b1,
    const u16* __restrict__ W2F, const u16* __restrict__ b2,
    void* __restrict__ outv) {
  __shared__ alignas(16) u16 Afull[6 * 2048];   // 24KB: S2 tiles; later H
  __shared__ alignas(16) char Tb[32 * 768];     // 24KB: T -> X2 -> S1
  __shared__ float st[32][8][2];
  char* HbA = (char*)Afull;
  const int tid = threadIdx.x;
  const int lane = tid & 63, wn = tid >> 6;
  const int wr = wn >> 2, wc = wn & 3;
  const int l15 = lane & 15, l4 = lane >> 4;
  const int sr = lane >> 3;
  const int scs = (((lane & 7) ^ sr) << 3);
  const int row0 = blockIdx.x * 32;
  const int fl = flag[0];

  for (int g = wn; g < 24; g += 8)
    gload16(S2 + (size_t)(row0 + (g & 3) * 8 + sr) * cE + (g >> 2) * 64 + scs,
            (char*)Afull + g * 1024);
  SBPIN();
  __syncthreads();

  // stage 1: T = (S2 @ Wo + bo) * fmask (nKB=12, T=6, 1x8)
  {
    f32x4 acc[2][3];
    #pragma unroll
    for (int m = 0; m < 2; ++m)
      #pragma unroll
      for (int n = 0; n < 3; ++n) acc[m][n] = f32x4{0.f, 0.f, 0.f, 0.f};
    rstage_1x8<6>(WoF + (size_t)(wn * 3) * 12 * 512, 12, 0, lane, l15, l4, acc,
                  [&](int m, int t, int ks) {
                    return *(const short8*)&Afull[t * 2048 + ldswz(m * 16 + l15, ks * 32 + l4 * 8)];
                  });
    #pragma unroll
    for (int m = 0; m < 2; ++m)
      #pragma unroll
      for (int j = 0; j < 4; ++j) {
        const int rl = m * 16 + l4 * 4 + j;
        const float fm = mget(mask, fl, row0 + rl) ? 1.0f : 0.0f;
        #pragma unroll
        for (int n = 0; n < 3; ++n) {
          const int col = wn * 48 + n * 16 + l15;
          const float v = (acc[m][n][j] + bf2f(bo[col])) * fm;
          *(u16*)(Tb + swz(rl, rl * 768 + col * 2)) = f2bf(v);
        }
      }
  }
  __syncthreads();

  // stage 2: xm = (T @ Wc + bc)*0.5 + tok  — registers (2x4; Wc nKB=12)
  f32x4 xm[3];
  #pragma unroll
  for (int n = 0; n < 3; ++n) xm[n] = f32x4{0.f, 0.f, 0.f, 0.f};
  rstage_2x4<6>(WcF + (size_t)(wc * 3) * 12 * 512, 12, 0, lane, l15, l4, xm,
                [&](int t, int ks) {
                  const int rl = wr * 16 + l15;
                  return *(const short8*)(Tb + swz(rl, rl * 768 + (t * 64 + ks * 32 + l4 * 8) * 2));
                });
  __syncthreads();   // all Tb(T) readers done
  #pragma unroll
  for (int n = 0; n < 3; ++n) {
    const int col = wc * 48 + n * 16 + l15;
    const float bi = bf2f(bc[col]);
    #pragma unroll
    for (int j = 0; j < 4; ++j) {
      const int rl = wr * 16 + l4 * 4 + j;
      xm[n][j] = (xm[n][j] + bi) * 0.5f + bf2f(tokc[(size_t)(row0 + rl) * cD + col]);
      *(u16*)(Tb + swz(rl, rl * 384 + col * 2)) = f2bf(xm[n][j]);   // X2
    }
  }
  __syncthreads();

  // stage 3: S1 = LN(X2 @ We + be; g2, bt2) -> Tb (We nKB=6, T=3, 1x8)
  {
    f32x4 a3[2][3];
    #pragma unroll
    for (int m = 0; m < 2; ++m)
      #pragma unroll
      for (int n = 0; n < 3; ++n) a3[m][n] = f32x4{0.f, 0.f, 0.f, 0.f};
    rstage_1x8<3>(WeF + (size_t)(wn * 3) * 6 * 512, 6, 0, lane, l15, l4, a3,
                  [&](int m, int t, int ks) {
                    const int rl = m * 16 + l15;
                    return *(const short8*)(Tb + swz(rl, rl * 384 + (t * 64 + ks * 32 + l4 * 8) * 2));
                  });
    float s[2][4], sq[2][4];
    #pragma unroll
    for (int m = 0; m < 2; ++m)
      #pragma unroll
      for (int j = 0; j < 4; ++j) { s[m][j] = 0.f; sq[m][j] = 0.f; }
    #pragma unroll
    for (int n = 0; n < 3; ++n) {
      const float bi = bf2f(be[wn * 48 + n * 16 + l15]);
      #pragma unroll
      for (int m = 0; m < 2; ++m)
        #pragma unroll
        for (int j = 0; j < 4; ++j) {
          a3[m][n][j] += bi;
          s[m][j] += a3[m][n][j]; sq[m][j] += a3[m][n][j] * a3[m][n][j];
        }
    }
    #pragma unroll
    for (int off = 1; off < 16; off <<= 1)
      #pragma unroll
      for (int m = 0; m < 2; ++m)
        #pragma unroll
        for (int j = 0; j < 4; ++j) { s[m][j] += __shfl_xor(s[m][j], off); sq[m][j] += __shfl_xor(sq[m][j], off); }
    if (l15 == 0) {
      #pragma unroll
      for (int m = 0; m < 2; ++m)
        #pragma unroll
        for (int j = 0; j < 4; ++j) {
          const int rl = m * 16 + l4 * 4 + j;
          st[rl][wn][0] = s[m][j]; st[rl][wn][1] = sq[m][j];
        }
    }
    __syncthreads();   // X2 reads done + st visible
    #pragma unroll
    for (int m = 0; m < 2; ++m)
      #pragma unroll
      for (int j = 0; j < 4; ++j) {
        const int rl = m * 16 + l4 * 4 + j;
        float ts = 0.f, tq = 0.f;
        #pragma unroll
        for (int wv = 0; wv < 8; ++wv) { ts += st[rl][wv][0]; tq += st[rl][wv][1]; }
        const float mean = ts * (1.0f / 384.0f);
        const float var = tq * (1.0f / 384.0f) - mean * mean;
        const float rstd = rsqrtf(var + 1e-5f);
        #pragma unroll
        for (int n = 0; n < 3; ++n) {
          const int col = wn * 48 + n * 16 + l15;
          const float v = (a3[m][n][j] - mean) * rstd * bf2f(g2[col]) + bf2f(bt2[col]);
          *(u16*)(Tb + swz(rl, rl * 768 + col * 2)) = f2bf(v);   // S1
        }
      }
  }
  __syncthreads();

  // ---- FFN: A = S1 in Tb, H buffer = Afull ----
  f32x4 accF[2][3];
  #pragma unroll
  for (int m = 0; m < 2; ++m)
    #pragma unroll
    for (int n = 0; n < 3; ++n) accF[m][n] = f32x4{0.f, 0.f, 0.f, 0.f};

  for (int half = 0; half < 2; ++half) {
    // s1: H = gelu(S1 @ W1[half] + b1[half]) (W1 nKB=12; colblk0=half*24+wn*3)
    {
      f32x4 a1[2][3];
      #pragma unroll
      for (int m = 0; m < 2; ++m)
        #pragma unroll
        for (int n = 0; n < 3; ++n) a1[m][n] = f32x4{0.f, 0.f, 0.f, 0.f};
      rstage_1x8<6>(W1F + (size_t)(half * 24 + wn * 3) * 12 * 512, 12, 0, lane, l15, l4, a1,
                    [&](int m, int t, int ks) {
                      const int rl = m * 16 + l15;
                      return *(const short8*)(Tb + swz(rl, rl * 768 + (t * 64 + ks * 32 + l4 * 8) * 2));
                    });
      #pragma unroll
      for (int n = 0; n < 3; ++n) {
        const int col = wn * 48 + n * 16 + l15;
        const float bi = bf2f(b1[half * 384 + col]);
        #pragma unroll
        for (int m = 0; m < 2; ++m)
          #pragma unroll
          for (int j = 0; j < 4; ++j) {
            const int rl = m * 16 + l4 * 4 + j;
            *(u16*)(HbA + swz(rl, rl * 768 + col * 2)) = f2bf(gelu_tanh(a1[m][n][j] + bi));
          }
      }
    }
    __syncthreads();
    // s2: accF += H @ W2[:, :] k-range half (W2 nKB=24; kb0 = half*12)
    rstage_1x8<6>(W2F + (size_t)(wn * 3) * 24 * 512, 24, half * 12, lane, l15, l4, accF,
                  [&](int m, int t, int ks) {
                    const int rl = m * 16 + l15;
                    return *(const short8*)(HbA + swz(rl, rl * 768 + (t * 64 + ks * 32 + l4 * 8) * 2));
                  });
    __syncthreads();
  }
  // F = accF + b2 -> HbA
  #pragma unroll
  for (int n = 0; n < 3; ++n) {
    const int col = wn * 48 + n * 16 + l15;
    const float bi = bf2f(b2[col]);
    #pragma unroll
    for (int m = 0; m < 2; ++m)
      #pragma unroll
      for (int j = 0; j < 4; ++j) {
        const int rl = m * 16 + l4 * 4 + j;
        *(u16*)(HbA + swz(rl, rl * 768 + col * 2)) = f2bf(accF[m][n][j] + bi);
      }
  }
  __syncthreads();
  // s3: out = (F @ Wc + bc)*0.5 + xm  (2x4, Wc nKB=12)
  f32x4 a3[3];
  #pragma unroll
  for (int n = 0; n < 3; ++n) a3[n] = f32x4{0.f, 0.f, 0.f, 0.f};
  rstage_2x4<6>(WcF + (size_t)(wc * 3) * 12 * 512, 12, 0, lane, l15, l4, a3,
                [&](int t, int ks) {
                  const int rl = wr * 16 + l15;
                  return *(const short8*)(HbA + swz(rl, rl * 768 + (t * 64 + ks * 32 + l4 * 8) * 2));
                });
  u16* o16 = (u16*)outv;
  float* o32 = (float*)outv;
  const int dtf = flag[1];
  #pragma unroll
  for (int n = 0; n < 3; ++n) {
    const int col = wc * 48 + n * 16 + l15;
    const float bi = bf2f(bc[col]);
    #pragma unroll
    for (int j = 0; j < 4; ++j) {
      const int rl = wr * 16 + l4 * 4 + j;
      const size_t oi = (size_t)(row0 + rl) * cD + col;
      const float r = (a3[n][j] + bi) * 0.5f + xm[n][j];
      if (dtf) o16[oi] = f2bf(r);
      else o32[oi] = r;
    }
  }
}

// ---------------------------------------------------------------------------
// attn v3 (unchanged).
__global__ __launch_bounds__(256) void attn_kernel(const u16* __restrict__ qkv,
                                                   const int* __restrict__ knn,
                                                   u16* __restrict__ o_out) {
  const int wid = threadIdx.x >> 6;
  const int lane = threadIdx.x & 63;
  const int bq = blockIdx.x * 4 + wid;
  const int b = bq >> 12;
  __shared__ float w4[4][8][8];
  __shared__ int vid4[4][8][8];
  __shared__ int nb4[4][16];
  float (*w)[8] = w4[wid];
  int (*vid)[8] = vid4[wid];
  int* nb = nb4[wid];
  if (lane < 16) nb[lane] = knn[bq * cKN + lane];
  const int h = lane >> 3;
  const int j = lane & 7;
  const uint2* qp = (const uint2*)(qkv + (size_t)bq * c3E + h * 48);
  const int r0 = nb[j], r1 = nb[j + 8];
  const uint2* k0p = (const uint2*)(qkv + ((size_t)(b * cV + r0)) * c3E + cE + h * 48);
  const uint2* k1p = (const uint2*)(qkv + ((size_t)(b * cV + r1)) * c3E + cE + h * 48);
  float s0 = 0.f, s1 = 0.f;
  #pragma unroll
  for (int t = 0; t < 12; ++t) {
    uint2 qv = qp[t];
    uint2 k0 = k0p[t];
    uint2 k1 = k1p[t];
    s0 += bflo(qv.x) * bflo(k0.x) + bfhi(qv.x) * bfhi(k0.x)
        + bflo(qv.y) * bflo(k0.y) + bfhi(qv.y) * bfhi(k0.y);
    s1 += bflo(qv.x) * bflo(k1.x) + bfhi(qv.x) * bfhi(k1.x)
        + bflo(qv.y) * bflo(k1.y) + bfhi(qv.y) * bfhi(k1.y);
  }
  const float inv = 0.14433756729740643f;  // 1/sqrt(48)
  u64 key0 = (((u64)f2ord(s0 * inv)) << 4) | (u64)(15 - j);
  u64 key1 = (((u64)f2ord(s1 * inv)) << 4) | (u64)(15 - (j + 8));
  float m0 = 0.f, Z = 0.f, myw = 0.f;
  int myv = 0;
  #pragma unroll
  for (int r = 0; r < cTK; ++r) {
    u64 best = key0 > key1 ? key0 : key1;
    u64 o1 = __shfl_xor(best, 1); if (o1 > best) best = o1;
    u64 o2 = __shfl_xor(best, 2); if (o2 > best) best = o2;
    u64 o4 = __shfl_xor(best, 4); if (o4 > best) best = o4;
    if (key0 == best) key0 = 0;
    if (key1 == best) key1 = 0;
    float sv = ord2f((u32)(best >> 4));
    int nsel = 15 - (int)(best & 15ull);
    if (r == 0) m0 = sv;
    float e = expf(sv - m0);
    Z += e;
    if (j == r) { myw = e; myv = nsel; }
  }
  w[h][j] = myw / Z;
  vid[h][j] = nb[myv];
  const u16* vbase = qkv + (size_t)(b * cV) * c3E + 2 * cE;
  #pragma unroll
  for (int rep = 0; rep < 6; ++rep) {
    int e = rep * 64 + lane;
    int h2 = e / 48;
    float acc = 0.f;
    #pragma unroll
    for (int t = 0; t < cTK; ++t)
      acc += w[h2][t] * bf2f(vbase[(size_t)vid[h2][t] * c3E + e]);
    o_out[(size_t)bq * cE + e] = f2bf(acc);
  }
}

// ---------------------------------------------------------------------------
extern "C" void kernel_launch(void* const* d_in, const int* in_sizes, int n_in,
                              void* d_out, int out_size, void* d_ws, size_t ws_size,
                              hipStream_t stream) {
  if (n_in < 18) return;
  const void* mask = d_in[1];

  char* ws = (char*)d_ws;
  size_t off = 0;
  auto alloc = [&](size_t bytes) { size_t o = off; off += (bytes + 255) & ~(size_t)255; return o; };
  int* flag  = (int*)(ws + alloc(256));
  u64* bmask = (u64*)(ws + alloc(128 * 8));
  int* knn   = (int*)(ws + alloc((size_t)cM * cKN * 4));
  u16* S2    = (u16*)(ws + alloc((size_t)cM * cE * 2));
  u16* QB    = (u16*)(ws + alloc((size_t)cM * c3E * 2));
  u16* tokc  = (u16*)(ws + alloc((size_t)cM * cD * 2));
  u16* be    = (u16*)(ws + alloc(cE * 2));
  u16* g1    = (u16*)(ws + alloc(cE * 2));
  u16* bt1   = (u16*)(ws + alloc(cE * 2));
  u16* bqkv  = (u16*)(ws + alloc(c3E * 2));
  u16* bo    = (u16*)(ws + alloc(cE * 2));
  u16* bc    = (u16*)(ws + alloc(cD * 2));
  u16* g2    = (u16*)(ws + alloc(cE * 2));
  u16* bt2   = (u16*)(ws + alloc(cE * 2));
  u16* b1    = (u16*)(ws + alloc(2 * cE * 2));
  u16* b2    = (u16*)(ws + alloc(cE * 2));
  u16* WeF   = (u16*)(ws + alloc((size_t)192 * 384 * 2));
  u16* WqkvF = (u16*)(ws + alloc((size_t)384 * 1152 * 2));
  u16* WoF   = (u16*)(ws + alloc((size_t)384 * 384 * 2));
  u16* WcF   = (u16*)(ws + alloc((size_t)384 * 192 * 2));
  u16* W1F   = (u16*)(ws + alloc((size_t)384 * 768 * 2));
  u16* W2F   = (u16*)(ws + alloc((size_t)768 * 384 * 2));
  (void)ws_size; (void)in_sizes; (void)out_size;

  detect_all_kernel<<<1, 256, 0, stream>>>((const u32*)d_in[0], (const u32*)mask, flag);

  {
    PrepArgs pa;
    const int csrci[11] = {0, 3, 4, 5, 7, 9, 11, 12, 13, 15, 17};
    u16* cdsts[11] = {tokc, be, g1, bt1, bqkv, bo, bc, g2, bt2, b1, b2};
    const int cns[11] = {cM * cD, cE, cE, cE, c3E, cE, cD, cE, cE, 2 * cE, cE};
    for (int i = 0; i < 11; ++i) { pa.csrc[i] = d_in[csrci[i]]; pa.cdst[i] = cdsts[i]; pa.cn[i] = cns[i]; }
    const int tsrci[6] = {2, 6, 8, 10, 14, 16};
    u16* tdsts[6] = {WeF, WqkvF, WoF, WcF, W1F, W2F};
    const int tKs[6] = {192, 384, 384, 384, 384, 768};
    const int tNs[6] = {384, 1152, 384, 192, 768, 384};
    for (int i = 0; i < 6; ++i) { pa.tsrc[i] = d_in[tsrci[i]]; pa.tdst[i] = tdsts[i]; pa.tK[i] = tKs[i]; pa.tN[i] = tNs[i]; }
    pa.mask = mask; pa.bm = bmask;
    prep_kernel<<<dim3(96, 18), 256, 0, stream>>>(pa, flag);
  }

  knn_kernel<<<cM / 4, 256, 0, stream>>>(bmask, knn);

  const int GB = cM / 32;  // 256 blocks
  fused_ln_qkv<<<GB, 512, 0, stream>>>(tokc, WeF, be, g1, bt1, WqkvF, bqkv, QB);
  attn_kernel<<<cM / 4, 256, 0, stream>>>(QB, knn, S2);
  fused_cd<<<GB, 512, 0, stream>>>(S2, WoF, bo, mask, flag, WcF, bc, tokc,
                                   WeF, be, g2, bt2, W1F, b1, W2F, b2, d_out);
}